// Round 6
// baseline (328.163 us; speedup 1.0000x reference)
//
#include <hip/hip_runtime.h>
#include <math.h>

// TopDownHTMM: C=32, 4-ary tree depth 7, N=21845, M=256. Output: scalar fp32.
// Two kernels:
//   k_pre   (33 x 256): softmax tables into W + zero sync counters.
//   k_fused (256 x 1024, cooperative for co-residency): per-subtree
//     down 5-7 + up 7-5 (LDS-resident), then last-finishing block does the
//     top-tree work (down 0-3, up 4-1, eps 0-3) while others prefetch;
//     flag-release; all blocks run eps 4-7 from LDS; deterministic reduce.
//
// Subtree r in [85,341): local m in [0,85), local depth d, global id
// g = 4^d * r + m; parent=(m-1)>>2, pos=(m-1)&3 hold locally.

#define GRID 256

enum : int {
  W_TB4  = 0,              // [256][32] level-4 t_beta rows (index r-85)
  W_EPSM = 8192,           // [85][32] mid eps rows
  W_AST  = W_EPSM + 2720,  // [e][j][i] = smA[i][j][e]      (4096)
  W_AS   = W_AST + 4096,   // [e][i][j] = smA[i][j][e]      (4096)
  W_ALT  = W_AS + 4096,    // [e][j][i] = log smA[i][j][e]  (4096)
  W_SPI  = W_ALT + 4096,   // smPi (32)
  W_LPI  = W_SPI + 32,     // log smPi (32)
  W_SBT  = W_LPI + 32,     // smB^T [s][i] (8192)
  W_LBT  = W_SBT + 8192,   // log smB^T [s][i] (8192)
  W_PART = W_LBT + 8192,   // 257 lh partials
  W_SYNC = W_PART + 260,   // 3 ints: ticket1, flag, ticket2
};

__device__ inline float hsum32(float v) {
#pragma unroll
  for (int m = 16; m >= 1; m >>= 1) v += __shfl_xor(v, m, 32);
  return v;
}

// global row index for local node m of subtree r
__device__ inline int gmap(int r, int m) {
  return (m == 0) ? r : (m < 5 ? 4 * r + m : (m < 21 ? 16 * r + m : 64 * r + m));
}

// ---------------- K1: softmax precompute + sync-counter zero ----------------
__global__ void k_pre(const float* __restrict__ A, const float* __restrict__ Bm,
                      const float* __restrict__ Pi, float* __restrict__ W) {
  __shared__ float sh[256];
  int tid = threadIdx.x;
  int b = blockIdx.x;
  if (b < 32) {
    int r = b, s = tid;
    float x = Bm[r * 256 + s];
    sh[tid] = x; __syncthreads();
    for (int off = 128; off >= 1; off >>= 1) {
      if (tid < off) sh[tid] = fmaxf(sh[tid], sh[tid + off]);
      __syncthreads();
    }
    float m = sh[0]; __syncthreads();
    float e = expf(x - m);
    sh[tid] = e; __syncthreads();
    for (int off = 128; off >= 1; off >>= 1) {
      if (tid < off) sh[tid] += sh[tid + off];
      __syncthreads();
    }
    float sum = sh[0];
    W[W_SBT + s * 32 + r] = e / sum;
    W[W_LBT + s * 32 + r] = (x - m) - logf(sum);
  } else {
    if (tid < 128) {
      int e = tid >> 5, j = tid & 31;
      float m = -1e30f;
      for (int i = 0; i < 32; i++) m = fmaxf(m, A[(i * 32 + j) * 4 + e]);
      float s = 0.f;
      for (int i = 0; i < 32; i++) s += expf(A[(i * 32 + j) * 4 + e] - m);
      float ls = logf(s);
      for (int i = 0; i < 32; i++) {
        float a = A[(i * 32 + j) * 4 + e];
        float sm = expf(a - m) / s;
        W[W_AST + e * 1024 + j * 32 + i] = sm;
        W[W_AS  + e * 1024 + i * 32 + j] = sm;
        W[W_ALT + e * 1024 + j * 32 + i] = (a - m) - ls;
      }
    } else if (tid == 128) {
      float m = -1e30f;
      for (int i = 0; i < 32; i++) m = fmaxf(m, Pi[i]);
      float s = 0.f;
      for (int i = 0; i < 32; i++) s += expf(Pi[i] - m);
      float ls = logf(s);
      for (int i = 0; i < 32; i++) {
        W[W_SPI + i] = expf(Pi[i] - m) / s;
        W[W_LPI + i] = (Pi[i] - m) - ls;
      }
    } else if (tid == 129) {
      int* Wi = (int*)(W + W_SYNC);
      Wi[0] = 0; Wi[1] = 0; Wi[2] = 0;
    }
  }
}

// ---------------- K2: fully fused tree sweep --------------------------------
__global__ __launch_bounds__(1024) void k_fused(const int* __restrict__ labels,
                                                float* __restrict__ W,
                                                float* __restrict__ out) {
  __shared__ float sAT[4096], sA[4096], sLT[4096];
  __shared__ float sp[2720], sb[2720], stb[2720];
  __shared__ float uni[10880];   // slb (rows 0..84) / mid arrays (last block)
  __shared__ float spe[32];
  __shared__ float sred[16];
  __shared__ int sLast;
  float* slb   = uni;            // 85x32 B-table rows (SBT then LBT)
  float* msp   = uni;            // mid arrays (only the last block uses these,
  float* msb   = uni + 2720;     //  and only before it refills slb)
  float* mstb  = uni + 5440;
  float* mseps = uni + 8160;

  const int tid = threadIdx.x, bid = blockIdx.x;
  const int grp = tid >> 5, lane = tid & 31;  // 32 groups of 32 lanes
  const int r = 85 + bid;
  int* Wi = (int*)(W + W_SYNC);
  const int LOFF[5] = {0, 1, 5, 21, 85};

  // tables (48 KB) + SBT label-row prefetch
  { float4* d; const float4* g;
    d = (float4*)sAT; g = (const float4*)(W + W_AST); d[tid] = g[tid];
    d = (float4*)sA;  g = (const float4*)(W + W_AS);  d[tid] = g[tid];
    d = (float4*)sLT; g = (const float4*)(W + W_ALT); d[tid] = g[tid]; }
  for (int m = grp; m < 85; m += 32)
    slb[m * 32 + lane] = W[W_SBT + labels[gmap(r, m)] * 32 + lane];
  float p = W[W_SPI + lane];  // path prior, register-resident, per group
  __syncthreads();

  // path: root -> a1 -> a2 -> a3 -> r (redundant per group, no barriers)
  const int a3 = (r - 1) >> 2, a2 = (a3 - 1) >> 2, a1 = (a2 - 1) >> 2;
  float p3 = 0.f;
  {
    int es[4] = {(a1 - 1) & 3, (a2 - 1) & 3, (a3 - 1) & 3, (r - 1) & 3};
#pragma unroll
    for (int s = 0; s < 4; s++) {
      float acc = 0.f;
#pragma unroll
      for (int j = 0; j < 32; j++)
        acc += sAT[es[s] * 1024 + j * 32 + lane] * __shfl(p, j, 32);
      if (s == 2) p3 = acc;   // prior at parent(r)
      p = acc;
    }
  }
  if (tid < 32) { sp[tid] = p; sb[tid] = p * slb[tid]; }
  __syncthreads();

  // down local levels 1..3 (global 5..7)
  for (int d = 1; d <= 3; d++) {
    int st = LOFF[d], cnt = LOFF[d + 1] - st;
    for (int base = 0; base < cnt; base += 32) {
      int ix = base + grp;
      if (ix < cnt) {
        int m = st + ix;
        int pam = (m - 1) >> 2, e = (m - 1) & 3;
        float acc = 0.f;
#pragma unroll
        for (int j = 0; j < 32; j++)
          acc += sAT[e * 1024 + j * 32 + lane] * sp[pam * 32 + j];
        sp[m * 32 + lane] = acc;
        float bv = acc * slb[m * 32 + lane];
        if (d == 3) { float s = hsum32(bv); bv /= s; }  // leaves normalized
        sb[m * 32 + lane] = bv;
      }
    }
    __syncthreads();
  }

  // up: parents at local levels 2,1,0; t_beta kept in LDS
  for (int d = 2; d >= 0; d--) {
    int st = LOFF[d], cnt = LOFF[d + 1] - st;
    for (int base = 0; base < cnt; base += 32) {
      int ix = base + grp;
      if (ix < cnt) {
        int pn = st + ix;
        float ppj = sp[pn * 32 + lane];
        float prod = 1.f;
#pragma unroll
        for (int c = 0; c < 4; c++) {
          int mch = 4 * pn + 1 + c;
          float acc = 0.f;
#pragma unroll
          for (int i = 0; i < 32; i++)
            acc += sA[c * 1024 + i * 32 + lane] * sb[mch * 32 + i];
          float buv = acc / ppj;
          stb[mch * 32 + lane] = buv;
          prod *= buv;
        }
        float bnew = sb[pn * 32 + lane] * prod;
        float s = hsum32(bnew);
        sb[pn * 32 + lane] = bnew / s;
      }
    }
    __syncthreads();
  }
  // local-root t_beta (final beta, parent prior from register p3) + export
  if (tid < 32) {
    int e = (r - 1) & 3;
    float acc = 0.f;
#pragma unroll
    for (int i = 0; i < 32; i++) acc += sA[e * 1024 + i * 32 + tid] * sb[i];
    float tb = acc / p3;
    stb[tid] = tb;
    W[W_TB4 + bid * 32 + tid] = tb;
  }
  // ratio = beta_final / prior, overwrites sp (prior dead)
  for (int m = grp; m < 85; m += 32) {
    int k = m * 32 + lane;
    sp[k] = sb[k] / sp[k];
  }
  __syncthreads();
  __threadfence();
  if (tid == 0) {
    int prev = __hip_atomic_fetch_add(&Wi[0], 1, __ATOMIC_ACQ_REL,
                                      __HIP_MEMORY_SCOPE_AGENT);
    sLast = (prev == GRID - 1) ? 1 : 0;
  }
  __syncthreads();
  const bool isLast = (sLast != 0);

  if (!isLast) {
    // prefetch LBT label rows (overlaps the mid block's work), then wait
    for (int m = grp; m < 85; m += 32)
      slb[m * 32 + lane] = W[W_LBT + labels[gmap(r, m)] * 32 + lane];
    if (tid == 0) {
      while (__hip_atomic_load(&Wi[1], __ATOMIC_ACQUIRE,
                               __HIP_MEMORY_SCOPE_AGENT) == 0)
        __builtin_amdgcn_s_sleep(2);
    }
    __syncthreads();
    __threadfence();
    if (tid < 32) spe[tid] = W[W_EPSM + ((r - 1) >> 2) * 32 + tid];
    __syncthreads();
  } else {
    // ---- mid-tree work: down 0-3, up 4-1, eps 0-3 ----
    if (tid < 32) {
      float pr = W[W_SPI + tid];
      msp[tid] = pr;
      msb[tid] = pr * W[W_SBT + labels[0] * 32 + tid];
    }
    __syncthreads();
    for (int l = 1; l <= 3; l++) {
      int st = LOFF[l], cnt = LOFF[l + 1] - st;
      for (int base = 0; base < cnt; base += 32) {
        int ix = base + grp;
        if (ix < cnt) {
          int n = st + ix;
          int pa = (n - 1) >> 2, e = (n - 1) & 3;
          float acc = 0.f;
#pragma unroll
          for (int j = 0; j < 32; j++)
            acc += sAT[e * 1024 + j * 32 + lane] * msp[pa * 32 + j];
          msp[n * 32 + lane] = acc;
          msb[n * 32 + lane] = acc * W[W_SBT + labels[n] * 32 + lane];
        }
      }
      __syncthreads();
    }
    const int PST[4] = {21, 5, 1, 0}, PCNT[4] = {64, 16, 4, 1};
    for (int s = 0; s < 4; s++) {
      int st = PST[s], cnt = PCNT[s];
      for (int base = 0; base < cnt; base += 32) {
        int ix = base + grp;
        if (ix < cnt) {
          int pn = st + ix;
          float prod = 1.f;
#pragma unroll
          for (int c = 0; c < 4; c++) {
            int n = 4 * pn + 1 + c;
            float buv;
            if (s == 0) {
              buv = W[W_TB4 + (n - 85) * 32 + lane];  // level-4 t_beta
            } else {
              float acc = 0.f;
#pragma unroll
              for (int i = 0; i < 32; i++)
                acc += sA[c * 1024 + i * 32 + lane] * msb[n * 32 + i];
              buv = acc / msp[pn * 32 + lane];
              mstb[n * 32 + lane] = buv;
            }
            prod *= buv;
          }
          float bnew = msb[pn * 32 + lane] * prod;
          float ss = hsum32(bnew);
          msb[pn * 32 + lane] = bnew / ss;
        }
      }
      __syncthreads();
    }
    float mlh = 0.f;
    if (tid < 32) {  // eps[root] = beta[root]; root Pi + B terms
      float v = msb[tid];
      mseps[tid] = v;
      mlh += v * (W[W_LPI + tid] + W[W_LBT + labels[0] * 32 + tid]);
    }
    __syncthreads();
    const int EST[3] = {1, 5, 21}, ECNT[3] = {4, 16, 64};
    for (int s = 0; s < 3; s++) {
      int st = EST[s], cnt = ECNT[s];
      for (int base = 0; base < cnt; base += 32) {
        int ix = base + grp;
        if (ix < cnt) {
          int n = st + ix;
          int pa = (n - 1) >> 2, e = (n - 1) & 3;
          float ratio = msb[n * 32 + lane] / msp[n * 32 + lane];
          float qv = mseps[pa * 32 + lane] / mstb[n * 32 + lane];
          float num = 0.f, alh = 0.f;
#pragma unroll
          for (int j = 0; j < 32; j++) {
            float qq = __shfl(qv, j, 32);
            float te = ratio * sAT[e * 1024 + j * 32 + lane] * qq;
            num += te;
            alh += te * sLT[e * 1024 + j * 32 + lane];
          }
          float den = hsum32(num);
          float epsi = num / den;
          mseps[n * 32 + lane] = epsi;
          mlh += alh + epsi * W[W_LBT + labels[n] * 32 + lane];
        }
      }
      __syncthreads();
    }
    if (tid < 680) {  // export eps rows 0..84
      int m = tid >> 3, q = tid & 7;
      *(float4*)&W[W_EPSM + m * 32 + q * 4] = *(float4*)&mseps[m * 32 + q * 4];
    }
#pragma unroll
    for (int m2 = 32; m2 >= 1; m2 >>= 1) mlh += __shfl_xor(mlh, m2, 64);
    if ((tid & 63) == 0) sred[tid >> 6] = mlh;
    __syncthreads();
    if (tid == 0) {
      float t = 0.f;
#pragma unroll
      for (int w = 0; w < 16; w++) t += sred[w];
      W[W_PART + 256] = t;
    }
    __syncthreads();
    __threadfence();
    if (tid == 0)
      __hip_atomic_store(&Wi[1], 1, __ATOMIC_RELEASE, __HIP_MEMORY_SCOPE_AGENT);
    // refill slb with LBT rows (overwrites msp region only) + spe from LDS
    for (int m = grp; m < 85; m += 32)
      slb[m * 32 + lane] = W[W_LBT + labels[gmap(r, m)] * 32 + lane];
    if (tid < 32) spe[tid] = mseps[((r - 1) >> 2) * 32 + tid];
    __syncthreads();
  }

  // ---- eps 4-7 (all blocks, all-LDS) + fused likelihood ----
  float lh = 0.f;
  if (grp == 0) {  // level-4 root r
    int e = (r - 1) & 3;
    float ratio = sp[lane];
    float qv = spe[lane] / stb[lane];
    float num = 0.f, alh = 0.f;
#pragma unroll
    for (int j = 0; j < 32; j++) {
      float qq = __shfl(qv, j, 32);
      float te = ratio * sAT[e * 1024 + j * 32 + lane] * qq;
      num += te;
      alh += te * sLT[e * 1024 + j * 32 + lane];
    }
    float den = hsum32(num);
    float epsi = num / den;
    sb[lane] = epsi;  // sb now stores eps
    lh += alh + epsi * slb[lane];
  }
  __syncthreads();
  for (int d = 1; d <= 3; d++) {
    int st = LOFF[d], cnt = LOFF[d + 1] - st;
    for (int base = 0; base < cnt; base += 32) {
      int ix = base + grp;
      if (ix < cnt) {
        int m = st + ix;
        int pa = (m - 1) >> 2, e = (m - 1) & 3;
        float ratio = sp[m * 32 + lane];
        float qv = sb[pa * 32 + lane] / stb[m * 32 + lane];
        float num = 0.f, alh = 0.f;
#pragma unroll
        for (int j = 0; j < 32; j++) {
          float qq = __shfl(qv, j, 32);
          float te = ratio * sAT[e * 1024 + j * 32 + lane] * qq;
          num += te;
          alh += te * sLT[e * 1024 + j * 32 + lane];
        }
        float den = hsum32(num);
        float epsi = num / den;
        sb[m * 32 + lane] = epsi;
        lh += alh + epsi * slb[m * 32 + lane];
      }
    }
    __syncthreads();
  }

  // block partial -> deterministic final sum by last-finishing block
#pragma unroll
  for (int m2 = 32; m2 >= 1; m2 >>= 1) lh += __shfl_xor(lh, m2, 64);
  if ((tid & 63) == 0) sred[tid >> 6] = lh;
  __syncthreads();
  if (tid == 0) {
    float t = 0.f;
#pragma unroll
    for (int w = 0; w < 16; w++) t += sred[w];
    W[W_PART + bid] = t;
  }
  __threadfence();
  if (tid == 0) {
    int prev = __hip_atomic_fetch_add(&Wi[2], 1, __ATOMIC_ACQ_REL,
                                      __HIP_MEMORY_SCOPE_AGENT);
    sLast = (prev == GRID - 1) ? 1 : 0;
  }
  __syncthreads();
  if (sLast) {
    __threadfence();
    if (tid < 64) {
      float a = 0.f;
      for (int k = tid; k < 257; k += 64) a += W[W_PART + k];
#pragma unroll
      for (int m2 = 32; m2 >= 1; m2 >>= 1) a += __shfl_xor(a, m2, 64);
      if (tid == 0) out[0] = a;
    }
  }
}

extern "C" void kernel_launch(void* const* d_in, const int* in_sizes, int n_in,
                              void* d_out, int out_size, void* d_ws, size_t ws_size,
                              hipStream_t stream) {
  const float* A  = (const float*)d_in[0];
  const float* Bm = (const float*)d_in[1];
  const float* Pi = (const float*)d_in[2];
  const int* labels = (const int*)d_in[5];
  float* W = (float*)d_ws;
  float* out = (float*)d_out;

  k_pre<<<33, 256, 0, stream>>>(A, Bm, Pi, W);

  void* args[] = {(void*)&labels, (void*)&W, (void*)&out};
  hipLaunchCooperativeKernel((const void*)k_fused, dim3(GRID), dim3(1024),
                             args, 0u, stream);
}

// Round 7
// 70.333 us; speedup vs baseline: 4.6659x; 4.6659x over previous
//
#include <hip/hip_runtime.h>
#include <math.h>

// TopDownHTMM: C=32, 4-ary tree depth 7, N=21845, M=256. Output: scalar fp32.
// 3-kernel pipeline (kernel boundary = cheap device barrier; NO in-kernel
// agent-scope sync — round-6 lesson: polling = per-XCD L2 invalidation storm):
//   k_sub (256x1024): build tables in-LDS, path prior, down 5-7, up 7-5,
//                     export level-4 t_beta + per-subtree t_beta/ratio stash.
//   k_mid (1x1024):   build tables, down 0-3, up 4-1 (level-4 from TB4),
//                     eps 0-3 + lh, export eps rows 0..84.
//   k_eps (256x1024): build packed table, eps 4-7 + lh (stash in LDS).
// Likelihood accumulated with atomicAdd into out[0] (zeroed by k_sub).
//
// Subtree r in [85,341): local m in [0,85), depth d, global g = 4^d*r + m;
// parent=(m-1)>>2, pos=(m-1)&3 hold locally.

#define NF (21845 * 32)

enum : int {
  W_TBETA = 0,           // [N][32] rows 85..21844
  W_RATIO = NF,          // [N][32] rows 85..21844 (beta_final/prior)
  W_TB4   = 2 * NF,      // [256][32] level-4 t_beta (index r-85)
  W_EPSM  = 2 * NF + 8192,  // [85][32] eps rows 0..84
};

__device__ inline float hsum32(float v) {
#pragma unroll
  for (int m = 16; m >= 1; m >>= 1) v += __shfl_xor(v, m, 32);
  return v;
}
__device__ inline float hmax32(float v) {
#pragma unroll
  for (int m = 16; m >= 1; m >>= 1) v = fmaxf(v, __shfl_xor(v, m, 32));
  return v;
}
// global row index for local node m of subtree r
__device__ inline int gmap(int r, int m) {
  return (m == 0) ? r : (m < 5 ? 4 * r + m : (m < 21 ? 16 * r + m : 64 * r + m));
}

// ---------------- K1: subtrees (tables + path + down 5-7 + up 7-5) ----------
__global__ __launch_bounds__(1024) void k_sub(const float* __restrict__ A,
                                              const float* __restrict__ Bm,
                                              const float* __restrict__ Pi,
                                              const int* __restrict__ labels,
                                              float* __restrict__ W,
                                              float* __restrict__ out) {
  __shared__ float sAT[4096];              // [e][j][i] = smA[i][j][e]
  __shared__ float sA[4096];               // [e][i][j] = smA[i][j][e]
  __shared__ float sp[2720], sb[2720], stb[2720], slb[2720];
  __shared__ float sBm[32], sBi[32], sPi[32];
  const int tid = threadIdx.x, bid = blockIdx.x;
  const int grp = tid >> 5, lane = tid & 31;
  const int r = 85 + bid;

  // B row stats: group g -> row g (max + 1/sum)
  {
    float xs[8], mx = -1e30f;
#pragma unroll
    for (int k = 0; k < 8; k++) { xs[k] = Bm[grp * 256 + k * 32 + lane]; mx = fmaxf(mx, xs[k]); }
    mx = hmax32(mx);
    float s = 0.f;
#pragma unroll
    for (int k = 0; k < 8; k++) s += expf(xs[k] - mx);
    s = hsum32(s);
    if (lane == 0) { sBm[grp] = mx; sBi[grp] = 1.f / s; }
  }
  // A softmax: group handles 4 (e,j) columns; lane = i
#pragma unroll
  for (int k = 0; k < 4; k++) {
    int c = grp * 4 + k, e = c >> 5, j = c & 31;
    float a = A[(lane * 32 + j) * 4 + e];
    float mx = hmax32(a);
    float ex = expf(a - mx);
    float s = hsum32(ex);
    float sm = ex / s;
    sAT[e * 1024 + j * 32 + lane] = sm;
    sA [e * 1024 + lane * 32 + j] = sm;
  }
  if (grp == 0) {  // smPi
    float x = Pi[lane];
    float mx = hmax32(x);
    float ex = expf(x - mx);
    sPi[lane] = ex / hsum32(ex);
  }
  if (bid == 0 && tid == 0) out[0] = 0.f;
  __syncthreads();

  // smB label rows for this subtree (gather from raw B)
  for (int m = grp; m < 85; m += 32) {
    float x = Bm[lane * 256 + labels[gmap(r, m)]];
    slb[m * 32 + lane] = expf(x - sBm[lane]) * sBi[lane];
  }
  // path prior root->a1->a2->a3->r (register + shfl, group-redundant)
  const int a3 = (r - 1) >> 2, a2 = (a3 - 1) >> 2, a1 = (a2 - 1) >> 2;
  float p = sPi[lane], p3 = 0.f;
  {
    int es[4] = {(a1 - 1) & 3, (a2 - 1) & 3, (a3 - 1) & 3, (r - 1) & 3};
#pragma unroll
    for (int s = 0; s < 4; s++) {
      float acc = 0.f;
#pragma unroll
      for (int j = 0; j < 32; j++)
        acc += sAT[es[s] * 1024 + j * 32 + lane] * __shfl(p, j, 32);
      if (s == 2) p3 = acc;
      p = acc;
    }
  }
  if (tid < 32) { sp[tid] = p; sb[tid] = p * slb[tid]; }  // grp0 wrote slb row 0
  __syncthreads();

  const int LOFF[5] = {0, 1, 5, 21, 85};
  // down local levels 1..3 (global 5..7); parent vector via float4 broadcast
  for (int d = 1; d <= 3; d++) {
    int st = LOFF[d], cnt = LOFF[d + 1] - st;
    for (int base = 0; base < cnt; base += 32) {
      int ix = base + grp;
      if (ix < cnt) {
        int m = st + ix, pam = (m - 1) >> 2, e = (m - 1) & 3;
        const float4* pv = (const float4*)&sp[pam * 32];
        float acc = 0.f;
#pragma unroll
        for (int j4 = 0; j4 < 8; j4++) {
          float4 v = pv[j4];
          const float* t = &sAT[e * 1024 + j4 * 128 + lane];
          acc += t[0] * v.x + t[32] * v.y + t[64] * v.z + t[96] * v.w;
        }
        sp[m * 32 + lane] = acc;
        float bv = acc * slb[m * 32 + lane];
        if (d == 3) bv /= hsum32(bv);  // leaves normalized
        sb[m * 32 + lane] = bv;
      }
    }
    __syncthreads();
  }
  // up: parents at local levels 2,1,0; t_beta in LDS
  for (int d = 2; d >= 0; d--) {
    int st = LOFF[d], cnt = LOFF[d + 1] - st;
    for (int base = 0; base < cnt; base += 32) {
      int ix = base + grp;
      if (ix < cnt) {
        int pn = st + ix;
        float ppj = sp[pn * 32 + lane];
        float prod = 1.f;
#pragma unroll
        for (int c = 0; c < 4; c++) {
          int mc = 4 * pn + 1 + c;
          const float4* bv4 = (const float4*)&sb[mc * 32];
          float acc = 0.f;
#pragma unroll
          for (int i4 = 0; i4 < 8; i4++) {
            float4 v = bv4[i4];
            const float* t = &sA[c * 1024 + i4 * 128 + lane];
            acc += t[0] * v.x + t[32] * v.y + t[64] * v.z + t[96] * v.w;
          }
          float buv = acc / ppj;
          stb[mc * 32 + lane] = buv;
          prod *= buv;
        }
        float bn = sb[pn * 32 + lane] * prod;
        bn /= hsum32(bn);
        sb[pn * 32 + lane] = bn;
      }
    }
    __syncthreads();
  }
  // local-root t_beta (final beta, parent prior p3) + TB4 export
  if (tid < 32) {
    int e = (r - 1) & 3;
    const float4* bv4 = (const float4*)&sb[0];
    float acc = 0.f;
#pragma unroll
    for (int i4 = 0; i4 < 8; i4++) {
      float4 v = bv4[i4];
      const float* t = &sA[e * 1024 + i4 * 128 + tid];
      acc += t[0] * v.x + t[32] * v.y + t[64] * v.z + t[96] * v.w;
    }
    float tb = acc / p3;
    stb[tid] = tb;
    W[W_TB4 + bid * 32 + tid] = tb;
  }
  __syncthreads();
  // coalesced stash: t_beta + ratio rows for all 85 local nodes
  if (tid < 680) {
    int m = tid >> 3, q = tid & 7, g = gmap(r, m);
    *(float4*)&W[W_TBETA + g * 32 + q * 4] = *(float4*)&stb[m * 32 + q * 4];
    float4 bb = *(float4*)&sb[m * 32 + q * 4], pp = *(float4*)&sp[m * 32 + q * 4];
    float4 rr; rr.x = bb.x / pp.x; rr.y = bb.y / pp.y; rr.z = bb.z / pp.z; rr.w = bb.w / pp.w;
    *(float4*)&W[W_RATIO + g * 32 + q * 4] = rr;
  }
}

// ---------------- K2: top tree (down 0-3, up 4-1, eps 0-3, lh) --------------
__global__ __launch_bounds__(1024) void k_mid(const float* __restrict__ A,
                                              const float* __restrict__ Bm,
                                              const float* __restrict__ Pi,
                                              const int* __restrict__ labels,
                                              float* __restrict__ W,
                                              float* __restrict__ out) {
  __shared__ float sAT[4096], sA[4096], sLT[4096];
  __shared__ float stb4[8192];  // level-4 t_beta
  __shared__ float msp[2720], msb[2720], mstb[2720], mseps[2720];
  __shared__ float slbS[2720], slbL[2720];
  __shared__ float sBm[32], sBi[32], sBls[32], sPi[32], sLpi[32];
  __shared__ float sred[16];
  const int tid = threadIdx.x;
  const int grp = tid >> 5, lane = tid & 31;

  {  // B row stats (max, 1/sum, log sum)
    float xs[8], mx = -1e30f;
#pragma unroll
    for (int k = 0; k < 8; k++) { xs[k] = Bm[grp * 256 + k * 32 + lane]; mx = fmaxf(mx, xs[k]); }
    mx = hmax32(mx);
    float s = 0.f;
#pragma unroll
    for (int k = 0; k < 8; k++) s += expf(xs[k] - mx);
    s = hsum32(s);
    if (lane == 0) { sBm[grp] = mx; sBi[grp] = 1.f / s; sBls[grp] = logf(s); }
  }
#pragma unroll
  for (int k = 0; k < 4; k++) {  // A softmax + log table
    int c = grp * 4 + k, e = c >> 5, j = c & 31;
    float a = A[(lane * 32 + j) * 4 + e];
    float mx = hmax32(a);
    float ex = expf(a - mx);
    float s = hsum32(ex);
    float ls = logf(s);
    sAT[e * 1024 + j * 32 + lane] = ex / s;
    sA [e * 1024 + lane * 32 + j] = ex / s;
    sLT[e * 1024 + j * 32 + lane] = (a - mx) - ls;
  }
  if (grp == 0) {  // smPi + log
    float x = Pi[lane];
    float mx = hmax32(x);
    float ex = expf(x - mx);
    float s = hsum32(ex);
    sPi[lane] = ex / s;
    sLpi[lane] = (x - mx) - logf(s);
  }
  {  // stage TB4 (32 KB)
    float4* d = (float4*)stb4; const float4* g = (const float4*)(W + W_TB4);
    d[tid] = g[tid]; d[tid + 1024] = g[tid + 1024];
  }
  __syncthreads();
  for (int m = grp; m < 85; m += 32) {  // B label rows (sm + log)
    float x = Bm[lane * 256 + labels[m]];
    slbS[m * 32 + lane] = expf(x - sBm[lane]) * sBi[lane];
    slbL[m * 32 + lane] = (x - sBm[lane]) - sBls[lane];
  }
  if (tid < 32) { msp[tid] = sPi[tid]; msb[tid] = sPi[tid] * slbS[tid]; }
  __syncthreads();

  const int LOFF[5] = {0, 1, 5, 21, 85};
  for (int d = 1; d <= 3; d++) {  // down 1..3
    int st = LOFF[d], cnt = LOFF[d + 1] - st;
    for (int base = 0; base < cnt; base += 32) {
      int ix = base + grp;
      if (ix < cnt) {
        int n = st + ix, pa = (n - 1) >> 2, e = (n - 1) & 3;
        const float4* pv = (const float4*)&msp[pa * 32];
        float acc = 0.f;
#pragma unroll
        for (int j4 = 0; j4 < 8; j4++) {
          float4 v = pv[j4];
          const float* t = &sAT[e * 1024 + j4 * 128 + lane];
          acc += t[0] * v.x + t[32] * v.y + t[64] * v.z + t[96] * v.w;
        }
        msp[n * 32 + lane] = acc;
        msb[n * 32 + lane] = acc * slbS[n * 32 + lane];
      }
    }
    __syncthreads();
  }
  const int PST[4] = {21, 5, 1, 0}, PCNT[4] = {64, 16, 4, 1};
  for (int s = 0; s < 4; s++) {  // up: parents 3,2,1,0
    int st = PST[s], cnt = PCNT[s];
    for (int base = 0; base < cnt; base += 32) {
      int ix = base + grp;
      if (ix < cnt) {
        int pn = st + ix;
        float prod = 1.f;
#pragma unroll
        for (int c = 0; c < 4; c++) {
          int n = 4 * pn + 1 + c;
          float buv;
          if (s == 0) {
            buv = stb4[(n - 85) * 32 + lane];
          } else {
            const float4* bv4 = (const float4*)&msb[n * 32];
            float acc = 0.f;
#pragma unroll
            for (int i4 = 0; i4 < 8; i4++) {
              float4 v = bv4[i4];
              const float* t = &sA[c * 1024 + i4 * 128 + lane];
              acc += t[0] * v.x + t[32] * v.y + t[64] * v.z + t[96] * v.w;
            }
            buv = acc / msp[pn * 32 + lane];
            mstb[n * 32 + lane] = buv;
          }
          prod *= buv;
        }
        float bn = msb[pn * 32 + lane] * prod;
        bn /= hsum32(bn);
        msb[pn * 32 + lane] = bn;
      }
    }
    __syncthreads();
  }
  float lh = 0.f;
  if (tid < 32) {  // eps[root]=beta[root]; Pi_lh + root B_lh
    float v = msb[tid];
    mseps[tid] = v;
    lh += v * (sLpi[tid] + slbL[tid]);
  }
  __syncthreads();
  const int EST[3] = {1, 5, 21}, ECNT[3] = {4, 16, 64};
  for (int s = 0; s < 3; s++) {  // eps levels 1..3
    int st = EST[s], cnt = ECNT[s];
    for (int base = 0; base < cnt; base += 32) {
      int ix = base + grp;
      if (ix < cnt) {
        int n = st + ix, pa = (n - 1) >> 2, e = (n - 1) & 3;
        float ratio = msb[n * 32 + lane] / msp[n * 32 + lane];
        float qv = mseps[pa * 32 + lane] / mstb[n * 32 + lane];
        float num = 0.f, alh = 0.f;
#pragma unroll
        for (int j = 0; j < 32; j++) {
          float qq = __shfl(qv, j, 32);
          float te = ratio * sAT[e * 1024 + j * 32 + lane] * qq;
          num += te;
          alh += te * sLT[e * 1024 + j * 32 + lane];
        }
        float den = hsum32(num);
        float epsi = num / den;
        mseps[n * 32 + lane] = epsi;
        lh += alh + epsi * slbL[n * 32 + lane];
      }
    }
    __syncthreads();
  }
  if (tid < 680) {  // export eps rows 0..84
    int m = tid >> 3, q = tid & 7;
    *(float4*)&W[W_EPSM + m * 32 + q * 4] = *(float4*)&mseps[m * 32 + q * 4];
  }
#pragma unroll
  for (int m2 = 32; m2 >= 1; m2 >>= 1) lh += __shfl_xor(lh, m2, 64);
  if ((tid & 63) == 0) sred[tid >> 6] = lh;
  __syncthreads();
  if (tid == 0) {
    float t = 0.f;
#pragma unroll
    for (int w = 0; w < 16; w++) t += sred[w];
    atomicAdd(out, t);
  }
}

// ---------------- K3: per-subtree eps 4-7 + fused lh ------------------------
__global__ __launch_bounds__(1024) void k_eps(const float* __restrict__ A,
                                              const float* __restrict__ Bm,
                                              const int* __restrict__ labels,
                                              float* __restrict__ W,
                                              float* __restrict__ out) {
  __shared__ float2 sC[4096];  // [e][j][i] = {smA, smA*log smA}
  __shared__ float stb[2720], srt[2720], seps[2720], slbL[2720];
  __shared__ float sq[1024];
  __shared__ float sBm[32], sBls[32], spe[32];
  __shared__ float sred[16];
  const int tid = threadIdx.x, bid = blockIdx.x;
  const int grp = tid >> 5, lane = tid & 31;
  const int r = 85 + bid;

  {  // B row stats (max + log sum)
    float xs[8], mx = -1e30f;
#pragma unroll
    for (int k = 0; k < 8; k++) { xs[k] = Bm[grp * 256 + k * 32 + lane]; mx = fmaxf(mx, xs[k]); }
    mx = hmax32(mx);
    float s = 0.f;
#pragma unroll
    for (int k = 0; k < 8; k++) s += expf(xs[k] - mx);
    s = hsum32(s);
    if (lane == 0) { sBm[grp] = mx; sBls[grp] = logf(s); }
  }
#pragma unroll
  for (int k = 0; k < 4; k++) {  // packed A table
    int c = grp * 4 + k, e = c >> 5, j = c & 31;
    float a = A[(lane * 32 + j) * 4 + e];
    float mx = hmax32(a);
    float ex = expf(a - mx);
    float s = hsum32(ex);
    float sm = ex / s;
    float lg = (a - mx) - logf(s);
    float2 t; t.x = sm; t.y = sm * lg;
    sC[e * 1024 + j * 32 + lane] = t;
  }
  // stash prefetch (coalesced float4)
  if (tid < 680) {
    int m = tid >> 3, q = tid & 7, g = gmap(r, m);
    *(float4*)&stb[m * 32 + q * 4] = *(const float4*)&W[W_TBETA + g * 32 + q * 4];
    *(float4*)&srt[m * 32 + q * 4] = *(const float4*)&W[W_RATIO + g * 32 + q * 4];
  }
  if (tid >= 992) spe[tid - 992] = W[W_EPSM + ((r - 1) >> 2) * 32 + (tid - 992)];
  __syncthreads();
  for (int m = grp; m < 85; m += 32) {  // log-B label rows
    float x = Bm[lane * 256 + labels[gmap(r, m)]];
    slbL[m * 32 + lane] = (x - sBm[lane]) - sBls[lane];
  }
  __syncthreads();

  float lh = 0.f;
  if (grp == 0) {  // eps at level-4 root r
    int e = (r - 1) & 3;
    float ratio = srt[lane];
    sq[lane] = spe[lane] / stb[lane];
    float an = 0.f, aa = 0.f;
    const float4* q4 = (const float4*)&sq[0];
#pragma unroll
    for (int j4 = 0; j4 < 8; j4++) {
      float4 qv = q4[j4];
      const float2* t = &sC[e * 1024 + j4 * 128 + lane];
      an += t[0].x * qv.x + t[32].x * qv.y + t[64].x * qv.z + t[96].x * qv.w;
      aa += t[0].y * qv.x + t[32].y * qv.y + t[64].y * qv.z + t[96].y * qv.w;
    }
    float num = ratio * an;
    float den = hsum32(num);
    float epsi = num / den;
    seps[lane] = epsi;
    lh += ratio * aa + epsi * slbL[lane];
  }
  __syncthreads();
  const int LOFF[5] = {0, 1, 5, 21, 85};
  for (int d = 1; d <= 3; d++) {
    int st = LOFF[d], cnt = LOFF[d + 1] - st;
    for (int base = 0; base < cnt; base += 32) {
      int ix = base + grp;
      if (ix < cnt) {
        int m = st + ix, pa = (m - 1) >> 2, e = (m - 1) & 3;
        float ratio = srt[m * 32 + lane];
        sq[grp * 32 + lane] = seps[pa * 32 + lane] / stb[m * 32 + lane];
        float an = 0.f, aa = 0.f;
        const float4* q4 = (const float4*)&sq[grp * 32];
#pragma unroll
        for (int j4 = 0; j4 < 8; j4++) {
          float4 qv = q4[j4];
          const float2* t = &sC[e * 1024 + j4 * 128 + lane];
          an += t[0].x * qv.x + t[32].x * qv.y + t[64].x * qv.z + t[96].x * qv.w;
          aa += t[0].y * qv.x + t[32].y * qv.y + t[64].y * qv.z + t[96].y * qv.w;
        }
        float num = ratio * an;
        float den = hsum32(num);
        float epsi = num / den;
        seps[m * 32 + lane] = epsi;
        lh += ratio * aa + epsi * slbL[m * 32 + lane];
      }
    }
    __syncthreads();
  }
#pragma unroll
  for (int m2 = 32; m2 >= 1; m2 >>= 1) lh += __shfl_xor(lh, m2, 64);
  if ((tid & 63) == 0) sred[tid >> 6] = lh;
  __syncthreads();
  if (tid == 0) {
    float t = 0.f;
#pragma unroll
    for (int w = 0; w < 16; w++) t += sred[w];
    atomicAdd(out, t);
  }
}

extern "C" void kernel_launch(void* const* d_in, const int* in_sizes, int n_in,
                              void* d_out, int out_size, void* d_ws, size_t ws_size,
                              hipStream_t stream) {
  const float* A  = (const float*)d_in[0];
  const float* Bm = (const float*)d_in[1];
  const float* Pi = (const float*)d_in[2];
  const int* labels = (const int*)d_in[5];
  float* W = (float*)d_ws;
  float* out = (float*)d_out;

  k_sub<<<256, 1024, 0, stream>>>(A, Bm, Pi, labels, W, out);
  k_mid<<<1, 1024, 0, stream>>>(A, Bm, Pi, labels, W, out);
  k_eps<<<256, 1024, 0, stream>>>(A, Bm, labels, W, out);
}

// Round 8
// 66.114 us; speedup vs baseline: 4.9636x; 1.0638x over previous
//
#include <hip/hip_runtime.h>
#include <math.h>

// TopDownHTMM: C=32, 4-ary tree depth 7, N=21845, M=256. Output: scalar fp32.
// 3-kernel pipeline:
//   k_pre  (33x256):   softmax tables (incl. packed (sm, sm*log) C-table) -> W.
//   k_sub  (256x1024): per-subtree path prior + down 5-7 + up 7-5;
//                      exports TB4 + t_beta/ratio stash.
//   k_eps2 (256x1024): per-block REDUNDANT top-tree (down 0-3, up 4-1 from TB4)
//                      + own 3-node ancestor eps chain; block 0 additionally
//                      does full top-eps + top lh; then subtree eps 4-7 + lh.
// Likelihood: atomicAdd into out[0] (zeroed by k_pre). No in-kernel cross-block
// sync (round-6 lesson: polling = L2 invalidation storm).
//
// Subtree r in [85,341): local m in [0,85), depth d, global g = 4^d*r + m;
// parent=(m-1)>>2, pos=(m-1)&3 hold locally.

#define NF (21845 * 32)

enum : int {
  W_TBETA = 0,              // [N][32] rows 85..21844 (+ row r per subtree)
  W_RATIO = NF,             // [N][32] (beta_final/prior)
  W_TB4   = 2 * NF,         // [256][32] level-4 t_beta (index r-85)
  W_AST   = 2 * NF + 8192,  // [e][j][i] = smA[i][j][e]          (4096)
  W_AS    = W_AST + 4096,   // [e][i][j] = smA[i][j][e]          (4096)
  W_SC    = W_AS + 4096,    // packed [e][j][i] = {sm, sm*log}   (8192)
  W_SPI   = W_SC + 8192,    // smPi (32)
  W_LPI   = W_SPI + 32,     // log smPi (32)
  W_SBT   = W_LPI + 32,     // smB^T [s][i] (8192)
  W_LBT   = W_SBT + 8192,   // log smB^T [s][i] (8192)
};

__device__ inline float hsum32(float v) {
#pragma unroll
  for (int m = 16; m >= 1; m >>= 1) v += __shfl_xor(v, m, 32);
  return v;
}

// global row index for local node m of subtree r
__device__ inline int gmap(int r, int m) {
  return (m == 0) ? r : (m < 5 ? 4 * r + m : (m < 21 ? 16 * r + m : 64 * r + m));
}

// 32x32 matvec, 4 independent fma chains. T = table base (row-major over j,
// lane = output idx), vec = 32-float broadcast operand.
__device__ inline float mv4(const float* __restrict__ T, const float* __restrict__ vec,
                            int lane) {
  const float4* v4 = (const float4*)vec;
  float a0 = 0.f, a1 = 0.f, a2 = 0.f, a3 = 0.f;
#pragma unroll
  for (int j4 = 0; j4 < 8; j4++) {
    float4 v = v4[j4];
    const float* t = &T[j4 * 128 + lane];
    a0 += t[0] * v.x; a1 += t[32] * v.y; a2 += t[64] * v.z; a3 += t[96] * v.w;
  }
  return (a0 + a1) + (a2 + a3);
}

// packed version: returns num (sm·q) and alh (sm·log·q) parts
__device__ inline void mv4p(const float2* __restrict__ T, const float* __restrict__ vec,
                            int lane, float& an, float& aa) {
  const float4* v4 = (const float4*)vec;
  float n0 = 0.f, n1 = 0.f, n2 = 0.f, n3 = 0.f;
  float l0 = 0.f, l1 = 0.f, l2 = 0.f, l3 = 0.f;
#pragma unroll
  for (int j4 = 0; j4 < 8; j4++) {
    float4 v = v4[j4];
    const float2* t = &T[j4 * 128 + lane];
    float2 x0 = t[0], x1 = t[32], x2 = t[64], x3 = t[96];
    n0 += x0.x * v.x; n1 += x1.x * v.y; n2 += x2.x * v.z; n3 += x3.x * v.w;
    l0 += x0.y * v.x; l1 += x1.y * v.y; l2 += x2.y * v.z; l3 += x3.y * v.w;
  }
  an = (n0 + n1) + (n2 + n3);
  aa = (l0 + l1) + (l2 + l3);
}

// ---------------- K1: softmax precompute (coalesced writes) -----------------
__global__ void k_pre(const float* __restrict__ A, const float* __restrict__ Bm,
                      const float* __restrict__ Pi, float* __restrict__ W,
                      float* __restrict__ out) {
  __shared__ float sh[256];
  int tid = threadIdx.x;
  int b = blockIdx.x;
  if (b < 32) {
    int r = b, s = tid;
    float x = Bm[r * 256 + s];
    sh[tid] = x; __syncthreads();
    for (int off = 128; off >= 1; off >>= 1) {
      if (tid < off) sh[tid] = fmaxf(sh[tid], sh[tid + off]);
      __syncthreads();
    }
    float m = sh[0]; __syncthreads();
    float e = expf(x - m);
    sh[tid] = e; __syncthreads();
    for (int off = 128; off >= 1; off >>= 1) {
      if (tid < off) sh[tid] += sh[tid + off];
      __syncthreads();
    }
    float sum = sh[0];
    W[W_SBT + s * 32 + r] = e / sum;
    W[W_LBT + s * 32 + r] = (x - m) - logf(sum);
  } else {
    if (tid < 128) {  // one (e,j) column of A, softmax over i
      int e = tid >> 5, j = tid & 31;
      float m = -1e30f;
      for (int i = 0; i < 32; i++) m = fmaxf(m, A[(i * 32 + j) * 4 + e]);
      float s = 0.f;
      for (int i = 0; i < 32; i++) s += expf(A[(i * 32 + j) * 4 + e] - m);
      float ls = logf(s);
      for (int i = 0; i < 32; i++) {
        float a = A[(i * 32 + j) * 4 + e];
        float sm = expf(a - m) / s;
        float lg = (a - m) - ls;
        W[W_AST + e * 1024 + j * 32 + i] = sm;
        W[W_AS  + e * 1024 + i * 32 + j] = sm;
        W[W_SC + 2 * (e * 1024 + j * 32 + i)] = sm;
        W[W_SC + 2 * (e * 1024 + j * 32 + i) + 1] = sm * lg;
      }
    } else if (tid == 128) {  // smPi
      float m = -1e30f;
      for (int i = 0; i < 32; i++) m = fmaxf(m, Pi[i]);
      float s = 0.f;
      for (int i = 0; i < 32; i++) s += expf(Pi[i] - m);
      float ls = logf(s);
      for (int i = 0; i < 32; i++) {
        W[W_SPI + i] = expf(Pi[i] - m) / s;
        W[W_LPI + i] = (Pi[i] - m) - ls;
      }
    } else if (tid == 129) {
      out[0] = 0.f;
    }
  }
}

// ---------------- K2: per-subtree down 5-7 + up 7-5 -------------------------
__global__ __launch_bounds__(1024) void k_sub(const int* __restrict__ labels,
                                              float* __restrict__ W) {
  __shared__ float sAT[4096], sA[4096];
  __shared__ float sp[2720], sb[2720], stb[2720], slb[2720];
  const int tid = threadIdx.x, bid = blockIdx.x;
  const int grp = tid >> 5, lane = tid & 31;
  const int r = 85 + bid;

  // early global issues: B label rows (regs) + tables (f4)
  float slbreg[3]; int mI[3]; int scnt = 0;
  for (int m = grp; m < 85; m += 32) {
    mI[scnt] = m;
    slbreg[scnt++] = W[W_SBT + labels[gmap(r, m)] * 32 + lane];
  }
  float pPi = W[W_SPI + lane];
  { ((float4*)sAT)[tid] = ((const float4*)(W + W_AST))[tid];
    ((float4*)sA)[tid]  = ((const float4*)(W + W_AS))[tid]; }
  for (int k = 0; k < scnt; k++) slb[mI[k] * 32 + lane] = slbreg[k];
  __syncthreads();

  // path prior root->a1->a2->a3->r (register + shfl, group-redundant)
  const int a3 = (r - 1) >> 2, a2 = (a3 - 1) >> 2, a1 = (a2 - 1) >> 2;
  float p = pPi, p3 = 0.f;
  {
    int es[4] = {(a1 - 1) & 3, (a2 - 1) & 3, (a3 - 1) & 3, (r - 1) & 3};
#pragma unroll
    for (int s = 0; s < 4; s++) {
      float acc = 0.f;
#pragma unroll
      for (int j = 0; j < 32; j++)
        acc += sAT[es[s] * 1024 + j * 32 + lane] * __shfl(p, j, 32);
      if (s == 2) p3 = acc;
      p = acc;
    }
  }
  if (tid < 32) { sp[tid] = p; sb[tid] = p * slb[tid]; }
  __syncthreads();

  const int LOFF[5] = {0, 1, 5, 21, 85};
  // down local 1..3 (global 5..7)
  for (int d = 1; d <= 3; d++) {
    int st = LOFF[d], cnt = LOFF[d + 1] - st;
    for (int base = 0; base < cnt; base += 32) {
      int ix = base + grp;
      if (ix < cnt) {
        int m = st + ix, pam = (m - 1) >> 2, e = (m - 1) & 3;
        float acc = mv4(&sAT[e * 1024], &sp[pam * 32], lane);
        sp[m * 32 + lane] = acc;
        float bv = acc * slb[m * 32 + lane];
        if (d == 3) bv /= hsum32(bv);  // leaves normalized
        sb[m * 32 + lane] = bv;
      }
    }
    __syncthreads();
  }
  // up: parents at local 2,1,0 — 4-child interleaved ILP
  for (int d = 2; d >= 0; d--) {
    int st = LOFF[d], cnt = LOFF[d + 1] - st;
    for (int base = 0; base < cnt; base += 32) {
      int ix = base + grp;
      if (ix < cnt) {
        int pn = st + ix;
        float ppj = sp[pn * 32 + lane];
        float ac[4] = {0.f, 0.f, 0.f, 0.f};
#pragma unroll
        for (int j4 = 0; j4 < 8; j4++) {
#pragma unroll
          for (int c = 0; c < 4; c++) {
            float4 v = ((const float4*)&sb[(4 * pn + 1 + c) * 32])[j4];
            const float* t = &sA[c * 1024 + j4 * 128 + lane];
            ac[c] += t[0] * v.x + t[32] * v.y + t[64] * v.z + t[96] * v.w;
          }
        }
        float prod = 1.f;
#pragma unroll
        for (int c = 0; c < 4; c++) {
          float buv = ac[c] / ppj;
          stb[(4 * pn + 1 + c) * 32 + lane] = buv;
          prod *= buv;
        }
        float bn = sb[pn * 32 + lane] * prod;
        bn /= hsum32(bn);
        sb[pn * 32 + lane] = bn;
      }
    }
    __syncthreads();
  }
  // local-root t_beta (final local beta, parent prior p3) + TB4 export
  if (tid < 32) {
    int e = (r - 1) & 3;
    float acc = mv4(&sA[e * 1024], &sb[0], tid);
    float tb = acc / p3;
    stb[tid] = tb;
    W[W_TB4 + bid * 32 + tid] = tb;
  }
  __syncthreads();
  // coalesced stash: t_beta + ratio for all 85 local rows
  if (tid < 680) {
    int m = tid >> 3, q = tid & 7, g = gmap(r, m);
    *(float4*)&W[W_TBETA + g * 32 + q * 4] = *(float4*)&stb[m * 32 + q * 4];
    float4 bb = *(float4*)&sb[m * 32 + q * 4], pp = *(float4*)&sp[m * 32 + q * 4];
    float4 rr;
    rr.x = bb.x / pp.x; rr.y = bb.y / pp.y; rr.z = bb.z / pp.z; rr.w = bb.w / pp.w;
    *(float4*)&W[W_RATIO + g * 32 + q * 4] = rr;
  }
}

// ---------------- K3: redundant top tree + eps (all levels 1-7) + lh --------
__global__ __launch_bounds__(1024) void k_eps2(const int* __restrict__ labels,
                                               float* __restrict__ W,
                                               float* __restrict__ out) {
  __shared__ float sAT[4096], sA[4096];
  __shared__ float R[8192];     // phase A: stb4 (level-4 t_beta); phase B: sC
  __shared__ float U[13600];    // top: msp,msb,mstb,mslb,mseps | sub: stb,srt,seps,slbL
  __shared__ float sq[1024];
  __shared__ float sPi[32], sLpi[32];
  __shared__ float sred[16];
  float* msp   = U;            float* msb  = U + 2720;
  float* mstb  = U + 5440;     float* mslb = U + 8160;
  float* mseps = U + 10880;
  float* stb = U;              float* srt  = U + 2720;   // subtree-phase aliases
  float* seps = U + 5440;      float* slbL = U + 8160;

  const int tid = threadIdx.x, bid = blockIdx.x;
  const int grp = tid >> 5, lane = tid & 31;
  const int r = 85 + bid;
  const int LOFF[5] = {0, 1, 5, 21, 85};

  // ---- early global issues into registers ----
  float4 sC0 = ((const float4*)(W + W_SC))[tid];
  float4 sC1 = ((const float4*)(W + W_SC))[tid + 1024];
  float4 stT, stR;
  const int sm_ = tid >> 3, sq_ = tid & 7;
  if (tid < 680) {
    int g = gmap(r, sm_);
    stT = *(const float4*)&W[W_TBETA + g * 32 + sq_ * 4];
    stR = *(const float4*)&W[W_RATIO + g * 32 + sq_ * 4];
  }
  float subL[3], topS[3], topL[3]; int mI[3]; int scnt = 0;
  for (int m = grp; m < 85; m += 32) {
    mI[scnt] = m;
    subL[scnt] = W[W_LBT + labels[gmap(r, m)] * 32 + lane];  // subtree log-B rows
    topS[scnt] = W[W_SBT + labels[m] * 32 + lane];           // top B rows
    topL[scnt] = W[W_LBT + labels[m] * 32 + lane];
    scnt++;
  }
  // tables + TB4
  { ((float4*)sAT)[tid] = ((const float4*)(W + W_AST))[tid];
    ((float4*)sA)[tid]  = ((const float4*)(W + W_AS))[tid];
    ((float4*)R)[tid]        = ((const float4*)(W + W_TB4))[tid];
    ((float4*)R)[tid + 1024] = ((const float4*)(W + W_TB4))[tid + 1024]; }
  if (grp == 0) { sPi[lane] = W[W_SPI + lane]; sLpi[lane] = W[W_LPI + lane]; }
  for (int k = 0; k < scnt; k++) mslb[mI[k] * 32 + lane] = topS[k];
  if (grp == 0) { msp[lane] = sPi[lane]; }
  __syncthreads();
  if (grp == 0) msb[lane] = msp[lane] * mslb[lane];
  __syncthreads();

  // ---- top-down levels 1..3 ----
  for (int l = 1; l <= 3; l++) {
    int st = LOFF[l], cnt = LOFF[l + 1] - st;
    for (int base = 0; base < cnt; base += 32) {
      int ix = base + grp;
      if (ix < cnt) {
        int n = st + ix, pa = (n - 1) >> 2, e = (n - 1) & 3;
        float acc = mv4(&sAT[e * 1024], &msp[pa * 32], lane);
        msp[n * 32 + lane] = acc;
        msb[n * 32 + lane] = acc * mslb[n * 32 + lane];
      }
    }
    __syncthreads();
  }
  // ---- top-up: parents level 3 (from TB4), then 2,1,0 ----
  {
    // s=0: 64 level-3 parents, t_beta of children = R(stb4) rows
    for (int base = 0; base < 64; base += 32) {
      int ix = base + grp;
      if (ix < 64) {
        int pn = 21 + ix;
        float prod = 1.f;
#pragma unroll
        for (int c = 0; c < 4; c++) {
          int n = 4 * pn + 1 + c;
          prod *= R[(n - 85) * 32 + lane];
        }
        float bn = msb[pn * 32 + lane] * prod;
        bn /= hsum32(bn);
        msb[pn * 32 + lane] = bn;
      }
    }
    __syncthreads();
    const int PST[3] = {5, 1, 0}, PCNT[3] = {16, 4, 1};
    for (int s = 0; s < 3; s++) {
      int st = PST[s], cnt = PCNT[s];
      int ix = grp;
      if (ix < cnt) {
        int pn = st + ix;
        float ppj = msp[pn * 32 + lane];
        float ac[4] = {0.f, 0.f, 0.f, 0.f};
#pragma unroll
        for (int j4 = 0; j4 < 8; j4++) {
#pragma unroll
          for (int c = 0; c < 4; c++) {
            float4 v = ((const float4*)&msb[(4 * pn + 1 + c) * 32])[j4];
            const float* t = &sA[c * 1024 + j4 * 128 + lane];
            ac[c] += t[0] * v.x + t[32] * v.y + t[64] * v.z + t[96] * v.w;
          }
        }
        float prod = 1.f;
#pragma unroll
        for (int c = 0; c < 4; c++) {
          float buv = ac[c] / ppj;
          mstb[(4 * pn + 1 + c) * 32 + lane] = buv;
          prod *= buv;
        }
        float bn = msb[pn * 32 + lane] * prod;
        bn /= hsum32(bn);
        msb[pn * 32 + lane] = bn;
      }
      __syncthreads();
    }
  }
  // ---- switch R -> sC; mslb -> log rows ----
  ((float4*)R)[tid] = sC0;
  ((float4*)R)[tid + 1024] = sC1;
  for (int k = 0; k < scnt; k++) mslb[mI[k] * 32 + lane] = topL[k];
  __syncthreads();
  const float2* sC = (const float2*)R;

  // ---- own ancestor eps chain: root -> a1 -> a2 -> a3 (group-redundant) ----
  const int a3 = (r - 1) >> 2, a2 = (a3 - 1) >> 2, a1 = (a2 - 1) >> 2;
  float peps = msb[lane];  // eps[root] = final root beta
  {
    int pathN[3] = {a1, a2, a3};
#pragma unroll
    for (int s = 0; s < 3; s++) {
      int n = pathN[s], e = (n - 1) & 3;
      sq[grp * 32 + lane] = peps / mstb[n * 32 + lane];
      float an, aa;
      mv4p(&sC[e * 1024], &sq[grp * 32], lane, an, aa);
      float ratio = msb[n * 32 + lane] / msp[n * 32 + lane];
      float num = ratio * an;
      float den = hsum32(num);
      peps = num / den;
    }
  }

  float lh = 0.f;
  if (bid == 0) {  // full top-eps + top lh (levels 0..3)
    if (grp == 0) {
      float v = msb[lane];
      mseps[lane] = v;
      lh += v * (sLpi[lane] + mslb[lane]);  // Pi_lh + root B_lh
    }
    __syncthreads();
    const int EST[3] = {1, 5, 21}, ECNT[3] = {4, 16, 64};
    for (int s = 0; s < 3; s++) {
      int st = EST[s], cnt = ECNT[s];
      for (int base = 0; base < cnt; base += 32) {
        int ix = base + grp;
        if (ix < cnt) {
          int n = st + ix, pa = (n - 1) >> 2, e = (n - 1) & 3;
          float ratio = msb[n * 32 + lane] / msp[n * 32 + lane];
          sq[grp * 32 + lane] = mseps[pa * 32 + lane] / mstb[n * 32 + lane];
          float an, aa;
          mv4p(&sC[e * 1024], &sq[grp * 32], lane, an, aa);
          float num = ratio * an;
          float den = hsum32(num);
          float epsi = num / den;
          mseps[n * 32 + lane] = epsi;
          lh += ratio * aa + epsi * mslb[n * 32 + lane];
        }
      }
      __syncthreads();
    }
  }
  __syncthreads();  // all blocks: top arrays dead; repurpose U

  // ---- subtree phase: write early-loaded stash + log-B rows ----
  if (tid < 680) {
    *(float4*)&stb[sm_ * 32 + sq_ * 4] = stT;
    *(float4*)&srt[sm_ * 32 + sq_ * 4] = stR;
  }
  for (int k = 0; k < scnt; k++) slbL[mI[k] * 32 + lane] = subL[k];
  __syncthreads();

  // eps at level-4 root r
  if (grp == 0) {
    int e = (r - 1) & 3;
    float ratio = srt[lane];
    sq[lane] = peps / stb[lane];
    float an, aa;
    mv4p(&sC[e * 1024], &sq[0], lane, an, aa);
    float num = ratio * an;
    float den = hsum32(num);
    float epsi = num / den;
    seps[lane] = epsi;
    lh += ratio * aa + epsi * slbL[lane];
  }
  __syncthreads();
  // subtree eps levels 1..3 (global 5..7)
  for (int d = 1; d <= 3; d++) {
    int st = LOFF[d], cnt = LOFF[d + 1] - st;
    for (int base = 0; base < cnt; base += 32) {
      int ix = base + grp;
      if (ix < cnt) {
        int m = st + ix, pa = (m - 1) >> 2, e = (m - 1) & 3;
        float ratio = srt[m * 32 + lane];
        sq[grp * 32 + lane] = seps[pa * 32 + lane] / stb[m * 32 + lane];
        float an, aa;
        mv4p(&sC[e * 1024], &sq[grp * 32], lane, an, aa);
        float num = ratio * an;
        float den = hsum32(num);
        float epsi = num / den;
        seps[m * 32 + lane] = epsi;
        lh += ratio * aa + epsi * slbL[m * 32 + lane];
      }
    }
    __syncthreads();
  }

  // ---- block partial -> atomicAdd ----
#pragma unroll
  for (int m2 = 32; m2 >= 1; m2 >>= 1) lh += __shfl_xor(lh, m2, 64);
  if ((tid & 63) == 0) sred[tid >> 6] = lh;
  __syncthreads();
  if (tid == 0) {
    float t = 0.f;
#pragma unroll
    for (int w = 0; w < 16; w++) t += sred[w];
    atomicAdd(out, t);
  }
}

extern "C" void kernel_launch(void* const* d_in, const int* in_sizes, int n_in,
                              void* d_out, int out_size, void* d_ws, size_t ws_size,
                              hipStream_t stream) {
  const float* A  = (const float*)d_in[0];
  const float* Bm = (const float*)d_in[1];
  const float* Pi = (const float*)d_in[2];
  const int* labels = (const int*)d_in[5];
  float* W = (float*)d_ws;
  float* out = (float*)d_out;

  k_pre<<<33, 256, 0, stream>>>(A, Bm, Pi, W, out);
  k_sub<<<256, 1024, 0, stream>>>(labels, W);
  k_eps2<<<256, 1024, 0, stream>>>(labels, W, out);
}

// Round 9
// 65.524 us; speedup vs baseline: 5.0083x; 1.0090x over previous
//
#include <hip/hip_runtime.h>
#include <math.h>

// TopDownHTMM: C=32, 4-ary tree depth 7, N=21845, M=256. Output: scalar fp32.
// TWO kernels (per-kernel fixed cost ~5us dominates; no in-kernel cross-block
// sync — round-6 lesson):
//   k_sub2 (256x1024): in-block softmax tables from raw A/B/Pi, path prior,
//                      down 5-7, up 7-5; exports TB4 + t_beta/ratio stash.
//   k_eps3 (256x1024): in-block tables, redundant top-tree (down 0-3, up 4-1
//                      from TB4), own ancestor eps chain; block 0 adds full
//                      top-eps + top lh; subtree eps 4-7 + lh; atomicAdd.
//
// Subtree r in [85,341): local m in [0,85), depth d, global g = 4^d*r + m;
// parent=(m-1)>>2, pos=(m-1)&3 hold locally.
//
// In-block table build (fixes round-7's regression):
//   stage: coalesced float4 read of raw A -> padded LDS S[(j*4+e)*33 + i]
//          (write ~4-way conflict, one pass; column reads conflict-free)
//   stats: 128 threads: max/sum/log per (e,j) column
//   emit:  lane-consecutive float4 stores of sAT [e][j][i], sA [e][i][j],
//          and packed sC {sm, sm*log} — all conflict-free.

#define NF (21845 * 32)

enum : int {
  W_TBETA = 0,          // [N][32] rows 85..21844 (+ row r per subtree)
  W_RATIO = NF,         // [N][32] (beta_final/prior)
  W_TB4   = 2 * NF,     // [256][32] level-4 t_beta (index r-85)
};

__device__ inline float hsum32(float v) {
#pragma unroll
  for (int m = 16; m >= 1; m >>= 1) v += __shfl_xor(v, m, 32);
  return v;
}
__device__ inline float hmax32(float v) {
#pragma unroll
  for (int m = 16; m >= 1; m >>= 1) v = fmaxf(v, __shfl_xor(v, m, 32));
  return v;
}
// global row index for local node m of subtree r
__device__ inline int gmap(int r, int m) {
  return (m == 0) ? r : (m < 5 ? 4 * r + m : (m < 21 ? 16 * r + m : 64 * r + m));
}

// 32x32 matvec, 4 independent fma chains; T row-major over j, lane = out idx.
__device__ inline float mv4(const float* __restrict__ T, const float* __restrict__ vec,
                            int lane) {
  const float4* v4 = (const float4*)vec;
  float a0 = 0.f, a1 = 0.f, a2 = 0.f, a3 = 0.f;
#pragma unroll
  for (int j4 = 0; j4 < 8; j4++) {
    float4 v = v4[j4];
    const float* t = &T[j4 * 128 + lane];
    a0 += t[0] * v.x; a1 += t[32] * v.y; a2 += t[64] * v.z; a3 += t[96] * v.w;
  }
  return (a0 + a1) + (a2 + a3);
}

// packed version: num (sm*q) and alh (sm*log*q)
__device__ inline void mv4p(const float2* __restrict__ T, const float* __restrict__ vec,
                            int lane, float& an, float& aa) {
  const float4* v4 = (const float4*)vec;
  float n0 = 0.f, n1 = 0.f, n2 = 0.f, n3 = 0.f;
  float l0 = 0.f, l1 = 0.f, l2 = 0.f, l3 = 0.f;
#pragma unroll
  for (int j4 = 0; j4 < 8; j4++) {
    float4 v = v4[j4];
    const float2* t = &T[j4 * 128 + lane];
    float2 x0 = t[0], x1 = t[32], x2 = t[64], x3 = t[96];
    n0 += x0.x * v.x; n1 += x1.x * v.y; n2 += x2.x * v.z; n3 += x3.x * v.w;
    l0 += x0.y * v.x; l1 += x1.y * v.y; l2 += x2.y * v.z; l3 += x3.y * v.w;
  }
  an = (n0 + n1) + (n2 + n3);
  aa = (l0 + l1) + (l2 + l3);
}

// ---------------- K1: per-subtree down 5-7 + up 7-5 (in-block tables) -------
__global__ __launch_bounds__(1024) void k_sub2(const float* __restrict__ A,
                                               const float* __restrict__ Bm,
                                               const float* __restrict__ Pi,
                                               const int* __restrict__ labels,
                                               float* __restrict__ W,
                                               float* __restrict__ out) {
  __shared__ float sAT[4096], sA[4096];
  __shared__ float SH[10880];            // sp|sb|stb|slb; staging S aliases front
  __shared__ float smx[128], sinv[128];
  __shared__ float sBmx[32], sBinv[32];
  float* sp  = SH;          float* sb  = SH + 2720;
  float* stb = SH + 5440;   float* slb = SH + 8160;
  float* S   = SH;                       // 128*33 = 4224 floats, dead after build

  const int tid = threadIdx.x, bid = blockIdx.x;
  const int grp = tid >> 5, lane = tid & 31;
  const int r = 85 + bid;
  if (bid == 0 && tid == 0) out[0] = 0.f;

  // ---- B row stats (row = grp): max + 1/sum ----
  {
    float xs[8], mx = -1e30f;
#pragma unroll
    for (int k = 0; k < 8; k++) { xs[k] = Bm[grp * 256 + k * 32 + lane]; mx = fmaxf(mx, xs[k]); }
    mx = hmax32(mx);
    float s = 0.f;
#pragma unroll
    for (int k = 0; k < 8; k++) s += expf(xs[k] - mx);
    s = hsum32(s);
    if (lane == 0) { sBmx[grp] = mx; sBinv[grp] = 1.f / s; }
  }
  // ---- stage raw A coalesced -> padded S[(j*4+e)*33 + i] ----
  {
    float4 raw = ((const float4*)A)[tid];   // (i = tid>>5, j = tid&31, e=0..3)
    int i = tid >> 5, j = tid & 31;
    S[(j * 4 + 0) * 33 + i] = raw.x;
    S[(j * 4 + 1) * 33 + i] = raw.y;
    S[(j * 4 + 2) * 33 + i] = raw.z;
    S[(j * 4 + 3) * 33 + i] = raw.w;
  }
  __syncthreads();
  if (tid < 128) {  // column stats (c = j*4+e)
    int c = tid;
    float mx = -1e30f;
    for (int i = 0; i < 32; i++) mx = fmaxf(mx, S[c * 33 + i]);
    float s = 0.f;
    for (int i = 0; i < 32; i++) s += expf(S[c * 33 + i] - mx);
    smx[c] = mx; sinv[c] = 1.f / s;
  }
  __syncthreads();
  // ---- emit sAT [e][j][i] (float4, conflict-free) ----
  {
    int v = 4 * tid, e = v >> 10, j = (v >> 5) & 31, i0 = v & 31, c = j * 4 + e;
    float mx = smx[c], iv = sinv[c];
    float4 o;
    o.x = expf(S[c * 33 + i0 + 0] - mx) * iv;
    o.y = expf(S[c * 33 + i0 + 1] - mx) * iv;
    o.z = expf(S[c * 33 + i0 + 2] - mx) * iv;
    o.w = expf(S[c * 33 + i0 + 3] - mx) * iv;
    ((float4*)sAT)[tid] = o;
  }
  // ---- emit sA [e][i][j] (float4, conflict-free) ----
  {
    int v = 4 * tid, e = v >> 10, i = (v >> 5) & 31, j0 = v & 31;
    float4 o;
    { int c = (j0 + 0) * 4 + e; o.x = expf(S[c * 33 + i] - smx[c]) * sinv[c]; }
    { int c = (j0 + 1) * 4 + e; o.y = expf(S[c * 33 + i] - smx[c]) * sinv[c]; }
    { int c = (j0 + 2) * 4 + e; o.z = expf(S[c * 33 + i] - smx[c]) * sinv[c]; }
    { int c = (j0 + 3) * 4 + e; o.w = expf(S[c * 33 + i] - smx[c]) * sinv[c]; }
    ((float4*)sA)[tid] = o;
  }
  __syncthreads();  // S dead; sp/sb usable

  // ---- smB label rows ----
  for (int m = grp; m < 85; m += 32) {
    float x = Bm[lane * 256 + labels[gmap(r, m)]];
    slb[m * 32 + lane] = expf(x - sBmx[lane]) * sBinv[lane];
  }
  // ---- smPi (register, group-redundant) + path prior ----
  float pPi;
  {
    float x = Pi[lane];
    float mx = hmax32(x);
    float ex = expf(x - mx);
    pPi = ex / hsum32(ex);
  }
  const int a3 = (r - 1) >> 2, a2 = (a3 - 1) >> 2, a1 = (a2 - 1) >> 2;
  float p = pPi, p3 = 0.f;
  {
    int es[4] = {(a1 - 1) & 3, (a2 - 1) & 3, (a3 - 1) & 3, (r - 1) & 3};
#pragma unroll
    for (int s = 0; s < 4; s++) {
      float acc = 0.f;
#pragma unroll
      for (int j = 0; j < 32; j++)
        acc += sAT[es[s] * 1024 + j * 32 + lane] * __shfl(p, j, 32);
      if (s == 2) p3 = acc;
      p = acc;
    }
  }
  if (tid < 32) { sp[tid] = p; sb[tid] = p * slb[tid]; }
  __syncthreads();

  const int LOFF[5] = {0, 1, 5, 21, 85};
  // down local 1..3 (global 5..7)
  for (int d = 1; d <= 3; d++) {
    int st = LOFF[d], cnt = LOFF[d + 1] - st;
    for (int base = 0; base < cnt; base += 32) {
      int ix = base + grp;
      if (ix < cnt) {
        int m = st + ix, pam = (m - 1) >> 2, e = (m - 1) & 3;
        float acc = mv4(&sAT[e * 1024], &sp[pam * 32], lane);
        sp[m * 32 + lane] = acc;
        float bv = acc * slb[m * 32 + lane];
        if (d == 3) bv /= hsum32(bv);  // leaves normalized
        sb[m * 32 + lane] = bv;
      }
    }
    __syncthreads();
  }
  // up: parents at local 2,1,0 — 4-child interleaved ILP
  for (int d = 2; d >= 0; d--) {
    int st = LOFF[d], cnt = LOFF[d + 1] - st;
    for (int base = 0; base < cnt; base += 32) {
      int ix = base + grp;
      if (ix < cnt) {
        int pn = st + ix;
        float ppj = sp[pn * 32 + lane];
        float ac[4] = {0.f, 0.f, 0.f, 0.f};
#pragma unroll
        for (int j4 = 0; j4 < 8; j4++) {
#pragma unroll
          for (int c = 0; c < 4; c++) {
            float4 v = ((const float4*)&sb[(4 * pn + 1 + c) * 32])[j4];
            const float* t = &sA[c * 1024 + j4 * 128 + lane];
            ac[c] += t[0] * v.x + t[32] * v.y + t[64] * v.z + t[96] * v.w;
          }
        }
        float prod = 1.f;
#pragma unroll
        for (int c = 0; c < 4; c++) {
          float buv = ac[c] / ppj;
          stb[(4 * pn + 1 + c) * 32 + lane] = buv;
          prod *= buv;
        }
        float bn = sb[pn * 32 + lane] * prod;
        bn /= hsum32(bn);
        sb[pn * 32 + lane] = bn;
      }
    }
    __syncthreads();
  }
  // local-root t_beta + TB4 export
  if (tid < 32) {
    int e = (r - 1) & 3;
    float acc = mv4(&sA[e * 1024], &sb[0], tid);
    float tb = acc / p3;
    stb[tid] = tb;
    W[W_TB4 + bid * 32 + tid] = tb;
  }
  __syncthreads();
  // coalesced stash: t_beta + ratio for all 85 local rows
  if (tid < 680) {
    int m = tid >> 3, q = tid & 7, g = gmap(r, m);
    *(float4*)&W[W_TBETA + g * 32 + q * 4] = *(float4*)&stb[m * 32 + q * 4];
    float4 bb = *(float4*)&sb[m * 32 + q * 4], pp = *(float4*)&sp[m * 32 + q * 4];
    float4 rr;
    rr.x = bb.x / pp.x; rr.y = bb.y / pp.y; rr.z = bb.z / pp.z; rr.w = bb.w / pp.w;
    *(float4*)&W[W_RATIO + g * 32 + q * 4] = rr;
  }
}

// ---------------- K2: redundant top tree + eps (levels 1-7) + lh ------------
__global__ __launch_bounds__(1024) void k_eps3(const float* __restrict__ A,
                                               const float* __restrict__ Bm,
                                               const float* __restrict__ Pi,
                                               const int* __restrict__ labels,
                                               float* __restrict__ W,
                                               float* __restrict__ out) {
  __shared__ float sAT[4096], sA[4096];
  __shared__ float R[8192];     // phase A: TB4; phase B: packed sC
  __shared__ float U[13600];    // top: msp,msb,mstb,mslb,mseps | sub aliases
  __shared__ float sq[1024];
  __shared__ float smx[128], sinv[128], sls[128];
  __shared__ float sBmx[32], sBinv[32], sBls[32];
  __shared__ float sred[16];
  float* msp   = U;            float* msb  = U + 2720;
  float* mstb  = U + 5440;     float* mslb = U + 8160;
  float* mseps = U + 10880;
  float* stb = U;              float* srt  = U + 2720;
  float* seps = U + 5440;      float* slbL = U + 8160;
  float* S = U;                // staging 4224 floats, dead after build

  const int tid = threadIdx.x, bid = blockIdx.x;
  const int grp = tid >> 5, lane = tid & 31;
  const int r = 85 + bid;
  const int LOFF[5] = {0, 1, 5, 21, 85};

  // ---- early global issues ----
  float4 stT, stR;
  const int sm_ = tid >> 3, sq_ = tid & 7;
  if (tid < 680) {
    int g = gmap(r, sm_);
    stT = *(const float4*)&W[W_TBETA + g * 32 + sq_ * 4];
    stR = *(const float4*)&W[W_RATIO + g * 32 + sq_ * 4];
  }
  { ((float4*)R)[tid]        = ((const float4*)(W + W_TB4))[tid];       // TB4
    ((float4*)R)[tid + 1024] = ((const float4*)(W + W_TB4))[tid + 1024]; }

  // ---- B row stats (max, 1/sum, log sum) ----
  {
    float xs[8], mx = -1e30f;
#pragma unroll
    for (int k = 0; k < 8; k++) { xs[k] = Bm[grp * 256 + k * 32 + lane]; mx = fmaxf(mx, xs[k]); }
    mx = hmax32(mx);
    float s = 0.f;
#pragma unroll
    for (int k = 0; k < 8; k++) s += expf(xs[k] - mx);
    s = hsum32(s);
    if (lane == 0) { sBmx[grp] = mx; sBinv[grp] = 1.f / s; sBls[grp] = logf(s); }
  }
  // ---- stage raw A ----
  {
    float4 raw = ((const float4*)A)[tid];
    int i = tid >> 5, j = tid & 31;
    S[(j * 4 + 0) * 33 + i] = raw.x;
    S[(j * 4 + 1) * 33 + i] = raw.y;
    S[(j * 4 + 2) * 33 + i] = raw.z;
    S[(j * 4 + 3) * 33 + i] = raw.w;
  }
  __syncthreads();
  if (tid < 128) {
    int c = tid;
    float mx = -1e30f;
    for (int i = 0; i < 32; i++) mx = fmaxf(mx, S[c * 33 + i]);
    float s = 0.f;
    for (int i = 0; i < 32; i++) s += expf(S[c * 33 + i] - mx);
    smx[c] = mx; sinv[c] = 1.f / s; sls[c] = logf(s);
  }
  __syncthreads();
  float4 sC0, sC1;  // packed {sm, sm*lg} for v=4t..4t+3, kept in regs until top done
  {
    int v = 4 * tid, e = v >> 10, j = (v >> 5) & 31, i0 = v & 31, c = j * 4 + e;
    float mx = smx[c], iv = sinv[c], ls = sls[c];
    float x0 = S[c * 33 + i0 + 0], x1 = S[c * 33 + i0 + 1];
    float x2 = S[c * 33 + i0 + 2], x3 = S[c * 33 + i0 + 3];
    float s0 = expf(x0 - mx) * iv, s1 = expf(x1 - mx) * iv;
    float s2 = expf(x2 - mx) * iv, s3 = expf(x3 - mx) * iv;
    float4 o; o.x = s0; o.y = s1; o.z = s2; o.w = s3;
    ((float4*)sAT)[tid] = o;
    sC0.x = s0; sC0.y = s0 * ((x0 - mx) - ls);
    sC0.z = s1; sC0.w = s1 * ((x1 - mx) - ls);
    sC1.x = s2; sC1.y = s2 * ((x2 - mx) - ls);
    sC1.z = s3; sC1.w = s3 * ((x3 - mx) - ls);
  }
  {
    int v = 4 * tid, e = v >> 10, i = (v >> 5) & 31, j0 = v & 31;
    float4 o;
    { int c = (j0 + 0) * 4 + e; o.x = expf(S[c * 33 + i] - smx[c]) * sinv[c]; }
    { int c = (j0 + 1) * 4 + e; o.y = expf(S[c * 33 + i] - smx[c]) * sinv[c]; }
    { int c = (j0 + 2) * 4 + e; o.z = expf(S[c * 33 + i] - smx[c]) * sinv[c]; }
    { int c = (j0 + 3) * 4 + e; o.w = expf(S[c * 33 + i] - smx[c]) * sinv[c]; }
    ((float4*)sA)[tid] = o;
  }
  __syncthreads();  // S dead; U usable

  // ---- label gathers (raw B + row stats): top sm/log, subtree log ----
  float subL[3], topS[3], topL[3]; int mI[3]; int scnt = 0;
  for (int m = grp; m < 85; m += 32) {
    float xt = Bm[lane * 256 + labels[m]];
    float xs = Bm[lane * 256 + labels[gmap(r, m)]];
    mI[scnt] = m;
    topS[scnt] = expf(xt - sBmx[lane]) * sBinv[lane];
    topL[scnt] = (xt - sBmx[lane]) - sBls[lane];
    subL[scnt] = (xs - sBmx[lane]) - sBls[lane];
    scnt++;
  }
  for (int k = 0; k < scnt; k++) mslb[mI[k] * 32 + lane] = topS[k];
  // smPi + logPi (registers, group 0 suffices)
  float pPi, lPi;
  {
    float x = Pi[lane];
    float mx = hmax32(x);
    float ex = expf(x - mx);
    float s = hsum32(ex);
    pPi = ex / s;
    lPi = (x - mx) - logf(s);
  }
  if (grp == 0) msp[lane] = pPi;
  __syncthreads();
  if (grp == 0) msb[lane] = msp[lane] * mslb[lane];
  __syncthreads();

  // ---- top-down levels 1..3 ----
  for (int l = 1; l <= 3; l++) {
    int st = LOFF[l], cnt = LOFF[l + 1] - st;
    for (int base = 0; base < cnt; base += 32) {
      int ix = base + grp;
      if (ix < cnt) {
        int n = st + ix, pa = (n - 1) >> 2, e = (n - 1) & 3;
        float acc = mv4(&sAT[e * 1024], &msp[pa * 32], lane);
        msp[n * 32 + lane] = acc;
        msb[n * 32 + lane] = acc * mslb[n * 32 + lane];
      }
    }
    __syncthreads();
  }
  // ---- top-up: level-3 parents from TB4 (R), then 2,1,0 ----
  {
    for (int base = 0; base < 64; base += 32) {
      int ix = base + grp;
      if (ix < 64) {
        int pn = 21 + ix;
        float prod = 1.f;
#pragma unroll
        for (int c = 0; c < 4; c++) {
          int n = 4 * pn + 1 + c;
          prod *= R[(n - 85) * 32 + lane];
        }
        float bn = msb[pn * 32 + lane] * prod;
        bn /= hsum32(bn);
        msb[pn * 32 + lane] = bn;
      }
    }
    __syncthreads();
    const int PST[3] = {5, 1, 0}, PCNT[3] = {16, 4, 1};
    for (int s = 0; s < 3; s++) {
      int st = PST[s], cnt = PCNT[s];
      int ix = grp;
      if (ix < cnt) {
        int pn = st + ix;
        float ppj = msp[pn * 32 + lane];
        float ac[4] = {0.f, 0.f, 0.f, 0.f};
#pragma unroll
        for (int j4 = 0; j4 < 8; j4++) {
#pragma unroll
          for (int c = 0; c < 4; c++) {
            float4 v = ((const float4*)&msb[(4 * pn + 1 + c) * 32])[j4];
            const float* t = &sA[c * 1024 + j4 * 128 + lane];
            ac[c] += t[0] * v.x + t[32] * v.y + t[64] * v.z + t[96] * v.w;
          }
        }
        float prod = 1.f;
#pragma unroll
        for (int c = 0; c < 4; c++) {
          float buv = ac[c] / ppj;
          mstb[(4 * pn + 1 + c) * 32 + lane] = buv;
          prod *= buv;
        }
        float bn = msb[pn * 32 + lane] * prod;
        bn /= hsum32(bn);
        msb[pn * 32 + lane] = bn;
      }
      __syncthreads();
    }
  }
  // ---- switch R -> sC; mslb -> log rows ----
  ((float4*)R)[tid] = sC0;
  ((float4*)R)[tid + 1024] = sC1;
  for (int k = 0; k < scnt; k++) mslb[mI[k] * 32 + lane] = topL[k];
  __syncthreads();
  const float2* sC = (const float2*)R;

  // ---- own ancestor eps chain: root -> a1 -> a2 -> a3 (group-redundant) ----
  const int a3 = (r - 1) >> 2, a2 = (a3 - 1) >> 2, a1 = (a2 - 1) >> 2;
  float peps = msb[lane];  // eps[root] = final root beta
  {
    int pathN[3] = {a1, a2, a3};
#pragma unroll
    for (int s = 0; s < 3; s++) {
      int n = pathN[s], e = (n - 1) & 3;
      sq[grp * 32 + lane] = peps / mstb[n * 32 + lane];
      float an, aa;
      mv4p(&sC[e * 1024], &sq[grp * 32], lane, an, aa);
      float ratio = msb[n * 32 + lane] / msp[n * 32 + lane];
      float num = ratio * an;
      float den = hsum32(num);
      peps = num / den;
    }
  }

  float lh = 0.f;
  if (bid == 0) {  // full top-eps + top lh (levels 0..3)
    if (grp == 0) {
      float v = msb[lane];
      mseps[lane] = v;
      lh += v * (lPi + mslb[lane]);  // Pi_lh + root B_lh
    }
    __syncthreads();
    const int EST[3] = {1, 5, 21}, ECNT[3] = {4, 16, 64};
    for (int s = 0; s < 3; s++) {
      int st = EST[s], cnt = ECNT[s];
      for (int base = 0; base < cnt; base += 32) {
        int ix = base + grp;
        if (ix < cnt) {
          int n = st + ix, pa = (n - 1) >> 2, e = (n - 1) & 3;
          float ratio = msb[n * 32 + lane] / msp[n * 32 + lane];
          sq[grp * 32 + lane] = mseps[pa * 32 + lane] / mstb[n * 32 + lane];
          float an, aa;
          mv4p(&sC[e * 1024], &sq[grp * 32], lane, an, aa);
          float num = ratio * an;
          float den = hsum32(num);
          float epsi = num / den;
          mseps[n * 32 + lane] = epsi;
          lh += ratio * aa + epsi * mslb[n * 32 + lane];
        }
      }
      __syncthreads();
    }
  }
  __syncthreads();  // top arrays dead; repurpose U

  // ---- subtree phase: write early-loaded stash + log-B rows ----
  if (tid < 680) {
    *(float4*)&stb[sm_ * 32 + sq_ * 4] = stT;
    *(float4*)&srt[sm_ * 32 + sq_ * 4] = stR;
  }
  for (int k = 0; k < scnt; k++) slbL[mI[k] * 32 + lane] = subL[k];
  __syncthreads();

  // eps at level-4 root r
  if (grp == 0) {
    int e = (r - 1) & 3;
    float ratio = srt[lane];
    sq[lane] = peps / stb[lane];
    float an, aa;
    mv4p(&sC[e * 1024], &sq[0], lane, an, aa);
    float num = ratio * an;
    float den = hsum32(num);
    float epsi = num / den;
    seps[lane] = epsi;
    lh += ratio * aa + epsi * slbL[lane];
  }
  __syncthreads();
  // subtree eps levels 1..3 (global 5..7)
  for (int d = 1; d <= 3; d++) {
    int st = LOFF[d], cnt = LOFF[d + 1] - st;
    for (int base = 0; base < cnt; base += 32) {
      int ix = base + grp;
      if (ix < cnt) {
        int m = st + ix, pa = (m - 1) >> 2, e = (m - 1) & 3;
        float ratio = srt[m * 32 + lane];
        sq[grp * 32 + lane] = seps[pa * 32 + lane] / stb[m * 32 + lane];
        float an, aa;
        mv4p(&sC[e * 1024], &sq[grp * 32], lane, an, aa);
        float num = ratio * an;
        float den = hsum32(num);
        float epsi = num / den;
        seps[m * 32 + lane] = epsi;
        lh += ratio * aa + epsi * slbL[m * 32 + lane];
      }
    }
    __syncthreads();
  }

  // ---- block partial -> atomicAdd ----
#pragma unroll
  for (int m2 = 32; m2 >= 1; m2 >>= 1) lh += __shfl_xor(lh, m2, 64);
  if ((tid & 63) == 0) sred[tid >> 6] = lh;
  __syncthreads();
  if (tid == 0) {
    float t = 0.f;
#pragma unroll
    for (int w = 0; w < 16; w++) t += sred[w];
    atomicAdd(out, t);
  }
}

extern "C" void kernel_launch(void* const* d_in, const int* in_sizes, int n_in,
                              void* d_out, int out_size, void* d_ws, size_t ws_size,
                              hipStream_t stream) {
  const float* A  = (const float*)d_in[0];
  const float* Bm = (const float*)d_in[1];
  const float* Pi = (const float*)d_in[2];
  const int* labels = (const int*)d_in[5];
  float* W = (float*)d_ws;
  float* out = (float*)d_out;

  k_sub2<<<256, 1024, 0, stream>>>(A, Bm, Pi, labels, W, out);
  k_eps3<<<256, 1024, 0, stream>>>(A, Bm, Pi, labels, W, out);
}

// Round 10
// 65.386 us; speedup vs baseline: 5.0189x; 1.0021x over previous
//
#include <hip/hip_runtime.h>
#include <math.h>

// TopDownHTMM: C=32, 4-ary tree depth 7, N=21845, M=256. Output: scalar fp32.
// TWO kernels, both 1024 threads with __launch_bounds__(1024, 4):
//   126 KB LDS -> exactly 1 block/CU = 4 waves/SIMD -> VGPR cap 128 (not 64).
//   Round-9 postmortem: default launch_bounds capped VGPR at 64 and spilled
//   ~34 B/thread to scratch (8.6 MB WRITE_SIZE in k_eps3, 41 us exec).
//
//   k_sub2 (256x1024): in-block softmax tables from raw A/B/Pi, path prior,
//                      down 5-7, up 7-5; exports TB4 + t_beta/ratio stash.
//   k_eps3 (256x1024): in-block tables, redundant top-tree (down 0-3, up 4-1
//                      from TB4), own ancestor eps chain; block 0 adds full
//                      top-eps + top lh; subtree eps 4-7 + lh; atomicAdd.
//
// Subtree r in [85,341): local m in [0,85), depth d, global g = 4^d*r + m;
// parent=(m-1)>>2, pos=(m-1)&3 hold locally.

#define NF (21845 * 32)

enum : int {
  W_TBETA = 0,          // [N][32] rows 85..21844 (+ row r per subtree)
  W_RATIO = NF,         // [N][32] (beta_final/prior)
  W_TB4   = 2 * NF,     // [256][32] level-4 t_beta (index r-85)
};

__device__ inline float hsum32(float v) {
#pragma unroll
  for (int m = 16; m >= 1; m >>= 1) v += __shfl_xor(v, m, 32);
  return v;
}
__device__ inline float hmax32(float v) {
#pragma unroll
  for (int m = 16; m >= 1; m >>= 1) v = fmaxf(v, __shfl_xor(v, m, 32));
  return v;
}
// global row index for local node m of subtree r
__device__ inline int gmap(int r, int m) {
  return (m == 0) ? r : (m < 5 ? 4 * r + m : (m < 21 ? 16 * r + m : 64 * r + m));
}

// 32x32 matvec, 4 independent fma chains; T row-major over j, lane = out idx.
__device__ inline float mv4(const float* __restrict__ T, const float* __restrict__ vec,
                            int lane) {
  const float4* v4 = (const float4*)vec;
  float a0 = 0.f, a1 = 0.f, a2 = 0.f, a3 = 0.f;
#pragma unroll
  for (int j4 = 0; j4 < 8; j4++) {
    float4 v = v4[j4];
    const float* t = &T[j4 * 128 + lane];
    a0 += t[0] * v.x; a1 += t[32] * v.y; a2 += t[64] * v.z; a3 += t[96] * v.w;
  }
  return (a0 + a1) + (a2 + a3);
}

// packed version: num (sm*q) and alh (sm*log*q)
__device__ inline void mv4p(const float2* __restrict__ T, const float* __restrict__ vec,
                            int lane, float& an, float& aa) {
  const float4* v4 = (const float4*)vec;
  float n0 = 0.f, n1 = 0.f, n2 = 0.f, n3 = 0.f;
  float l0 = 0.f, l1 = 0.f, l2 = 0.f, l3 = 0.f;
#pragma unroll
  for (int j4 = 0; j4 < 8; j4++) {
    float4 v = v4[j4];
    const float2* t = &T[j4 * 128 + lane];
    float2 x0 = t[0], x1 = t[32], x2 = t[64], x3 = t[96];
    n0 += x0.x * v.x; n1 += x1.x * v.y; n2 += x2.x * v.z; n3 += x3.x * v.w;
    l0 += x0.y * v.x; l1 += x1.y * v.y; l2 += x2.y * v.z; l3 += x3.y * v.w;
  }
  an = (n0 + n1) + (n2 + n3);
  aa = (l0 + l1) + (l2 + l3);
}

// ---------------- K1: per-subtree down 5-7 + up 7-5 (in-block tables) -------
__global__ __launch_bounds__(1024, 4) void k_sub2(const float* __restrict__ A,
                                                  const float* __restrict__ Bm,
                                                  const float* __restrict__ Pi,
                                                  const int* __restrict__ labels,
                                                  float* __restrict__ W,
                                                  float* __restrict__ out) {
  __shared__ float sAT[4096], sA[4096];
  __shared__ float SH[10880];            // sp|sb|stb|slb; staging S aliases front
  __shared__ float smx[128], sinv[128];
  __shared__ float sBmx[32], sBinv[32];
  float* sp  = SH;          float* sb  = SH + 2720;
  float* stb = SH + 5440;   float* slb = SH + 8160;
  float* S   = SH;                       // 128*33 = 4224 floats, dead after build

  const int tid = threadIdx.x, bid = blockIdx.x;
  const int grp = tid >> 5, lane = tid & 31;
  const int r = 85 + bid;
  if (bid == 0 && tid == 0) out[0] = 0.f;

  // ---- B row stats (row = grp): max + 1/sum ----
  {
    float xs[8], mx = -1e30f;
#pragma unroll
    for (int k = 0; k < 8; k++) { xs[k] = Bm[grp * 256 + k * 32 + lane]; mx = fmaxf(mx, xs[k]); }
    mx = hmax32(mx);
    float s = 0.f;
#pragma unroll
    for (int k = 0; k < 8; k++) s += expf(xs[k] - mx);
    s = hsum32(s);
    if (lane == 0) { sBmx[grp] = mx; sBinv[grp] = 1.f / s; }
  }
  // ---- stage raw A coalesced -> padded S[(j*4+e)*33 + i] ----
  {
    float4 raw = ((const float4*)A)[tid];   // (i = tid>>5, j = tid&31, e=0..3)
    int i = tid >> 5, j = tid & 31;
    S[(j * 4 + 0) * 33 + i] = raw.x;
    S[(j * 4 + 1) * 33 + i] = raw.y;
    S[(j * 4 + 2) * 33 + i] = raw.z;
    S[(j * 4 + 3) * 33 + i] = raw.w;
  }
  __syncthreads();
  if (tid < 128) {  // column stats (c = j*4+e)
    int c = tid;
    float mx = -1e30f;
    for (int i = 0; i < 32; i++) mx = fmaxf(mx, S[c * 33 + i]);
    float s = 0.f;
    for (int i = 0; i < 32; i++) s += expf(S[c * 33 + i] - mx);
    smx[c] = mx; sinv[c] = 1.f / s;
  }
  __syncthreads();
  // ---- emit sAT [e][j][i] (float4, conflict-free) ----
  {
    int v = 4 * tid, e = v >> 10, j = (v >> 5) & 31, i0 = v & 31, c = j * 4 + e;
    float mx = smx[c], iv = sinv[c];
    float4 o;
    o.x = expf(S[c * 33 + i0 + 0] - mx) * iv;
    o.y = expf(S[c * 33 + i0 + 1] - mx) * iv;
    o.z = expf(S[c * 33 + i0 + 2] - mx) * iv;
    o.w = expf(S[c * 33 + i0 + 3] - mx) * iv;
    ((float4*)sAT)[tid] = o;
  }
  // ---- emit sA [e][i][j] (float4, conflict-free) ----
  {
    int v = 4 * tid, e = v >> 10, i = (v >> 5) & 31, j0 = v & 31;
    float4 o;
    { int c = (j0 + 0) * 4 + e; o.x = expf(S[c * 33 + i] - smx[c]) * sinv[c]; }
    { int c = (j0 + 1) * 4 + e; o.y = expf(S[c * 33 + i] - smx[c]) * sinv[c]; }
    { int c = (j0 + 2) * 4 + e; o.z = expf(S[c * 33 + i] - smx[c]) * sinv[c]; }
    { int c = (j0 + 3) * 4 + e; o.w = expf(S[c * 33 + i] - smx[c]) * sinv[c]; }
    ((float4*)sA)[tid] = o;
  }
  __syncthreads();  // S dead; sp/sb usable

  // ---- smB label rows ----
  for (int m = grp; m < 85; m += 32) {
    float x = Bm[lane * 256 + labels[gmap(r, m)]];
    slb[m * 32 + lane] = expf(x - sBmx[lane]) * sBinv[lane];
  }
  // ---- smPi (register, group-redundant) + path prior ----
  float pPi;
  {
    float x = Pi[lane];
    float mx = hmax32(x);
    float ex = expf(x - mx);
    pPi = ex / hsum32(ex);
  }
  const int a3 = (r - 1) >> 2, a2 = (a3 - 1) >> 2, a1 = (a2 - 1) >> 2;
  float p = pPi, p3 = 0.f;
  {
    int es[4] = {(a1 - 1) & 3, (a2 - 1) & 3, (a3 - 1) & 3, (r - 1) & 3};
#pragma unroll
    for (int s = 0; s < 4; s++) {
      float acc = 0.f;
#pragma unroll
      for (int j = 0; j < 32; j++)
        acc += sAT[es[s] * 1024 + j * 32 + lane] * __shfl(p, j, 32);
      if (s == 2) p3 = acc;
      p = acc;
    }
  }
  if (tid < 32) { sp[tid] = p; sb[tid] = p * slb[tid]; }
  __syncthreads();

  const int LOFF[5] = {0, 1, 5, 21, 85};
  // down local 1..3 (global 5..7)
  for (int d = 1; d <= 3; d++) {
    int st = LOFF[d], cnt = LOFF[d + 1] - st;
    for (int base = 0; base < cnt; base += 32) {
      int ix = base + grp;
      if (ix < cnt) {
        int m = st + ix, pam = (m - 1) >> 2, e = (m - 1) & 3;
        float acc = mv4(&sAT[e * 1024], &sp[pam * 32], lane);
        sp[m * 32 + lane] = acc;
        float bv = acc * slb[m * 32 + lane];
        if (d == 3) bv /= hsum32(bv);  // leaves normalized
        sb[m * 32 + lane] = bv;
      }
    }
    __syncthreads();
  }
  // up: parents at local 2,1,0 — 4-child interleaved ILP
  for (int d = 2; d >= 0; d--) {
    int st = LOFF[d], cnt = LOFF[d + 1] - st;
    for (int base = 0; base < cnt; base += 32) {
      int ix = base + grp;
      if (ix < cnt) {
        int pn = st + ix;
        float ppj = sp[pn * 32 + lane];
        float ac[4] = {0.f, 0.f, 0.f, 0.f};
#pragma unroll
        for (int j4 = 0; j4 < 8; j4++) {
#pragma unroll
          for (int c = 0; c < 4; c++) {
            float4 v = ((const float4*)&sb[(4 * pn + 1 + c) * 32])[j4];
            const float* t = &sA[c * 1024 + j4 * 128 + lane];
            ac[c] += t[0] * v.x + t[32] * v.y + t[64] * v.z + t[96] * v.w;
          }
        }
        float prod = 1.f;
#pragma unroll
        for (int c = 0; c < 4; c++) {
          float buv = ac[c] / ppj;
          stb[(4 * pn + 1 + c) * 32 + lane] = buv;
          prod *= buv;
        }
        float bn = sb[pn * 32 + lane] * prod;
        bn /= hsum32(bn);
        sb[pn * 32 + lane] = bn;
      }
    }
    __syncthreads();
  }
  // local-root t_beta + TB4 export
  if (tid < 32) {
    int e = (r - 1) & 3;
    float acc = mv4(&sA[e * 1024], &sb[0], tid);
    float tb = acc / p3;
    stb[tid] = tb;
    W[W_TB4 + bid * 32 + tid] = tb;
  }
  __syncthreads();
  // coalesced stash: t_beta + ratio for all 85 local rows
  if (tid < 680) {
    int m = tid >> 3, q = tid & 7, g = gmap(r, m);
    *(float4*)&W[W_TBETA + g * 32 + q * 4] = *(float4*)&stb[m * 32 + q * 4];
    float4 bb = *(float4*)&sb[m * 32 + q * 4], pp = *(float4*)&sp[m * 32 + q * 4];
    float4 rr;
    rr.x = bb.x / pp.x; rr.y = bb.y / pp.y; rr.z = bb.z / pp.z; rr.w = bb.w / pp.w;
    *(float4*)&W[W_RATIO + g * 32 + q * 4] = rr;
  }
}

// ---------------- K2: redundant top tree + eps (levels 1-7) + lh ------------
__global__ __launch_bounds__(1024, 4) void k_eps3(const float* __restrict__ A,
                                                  const float* __restrict__ Bm,
                                                  const float* __restrict__ Pi,
                                                  const int* __restrict__ labels,
                                                  float* __restrict__ W,
                                                  float* __restrict__ out) {
  __shared__ float sAT[4096], sA[4096];
  __shared__ float R[8192];     // phase A: TB4; phase B: packed sC
  __shared__ float U[13600];    // top: msp,msb,mstb,mslb,mseps | sub aliases
  __shared__ float sq[1024];
  __shared__ float smx[128], sinv[128], sls[128];
  __shared__ float sBmx[32], sBinv[32], sBls[32];
  __shared__ float sred[16];
  float* msp   = U;            float* msb  = U + 2720;
  float* mstb  = U + 5440;     float* mslb = U + 8160;
  float* mseps = U + 10880;
  float* stb = U;              float* srt  = U + 2720;
  float* seps = U + 5440;      float* slbL = U + 8160;
  float* S = U;                // staging 4224 floats, dead after build

  const int tid = threadIdx.x, bid = blockIdx.x;
  const int grp = tid >> 5, lane = tid & 31;
  const int r = 85 + bid;
  const int LOFF[5] = {0, 1, 5, 21, 85};

  // ---- early global issues ----
  float4 stT, stR;
  const int sm_ = tid >> 3, sq_ = tid & 7;
  if (tid < 680) {
    int g = gmap(r, sm_);
    stT = *(const float4*)&W[W_TBETA + g * 32 + sq_ * 4];
    stR = *(const float4*)&W[W_RATIO + g * 32 + sq_ * 4];
  }
  { ((float4*)R)[tid]        = ((const float4*)(W + W_TB4))[tid];       // TB4
    ((float4*)R)[tid + 1024] = ((const float4*)(W + W_TB4))[tid + 1024]; }

  // ---- B row stats (max, 1/sum, log sum) ----
  {
    float xs[8], mx = -1e30f;
#pragma unroll
    for (int k = 0; k < 8; k++) { xs[k] = Bm[grp * 256 + k * 32 + lane]; mx = fmaxf(mx, xs[k]); }
    mx = hmax32(mx);
    float s = 0.f;
#pragma unroll
    for (int k = 0; k < 8; k++) s += expf(xs[k] - mx);
    s = hsum32(s);
    if (lane == 0) { sBmx[grp] = mx; sBinv[grp] = 1.f / s; sBls[grp] = logf(s); }
  }
  // ---- stage raw A ----
  {
    float4 raw = ((const float4*)A)[tid];
    int i = tid >> 5, j = tid & 31;
    S[(j * 4 + 0) * 33 + i] = raw.x;
    S[(j * 4 + 1) * 33 + i] = raw.y;
    S[(j * 4 + 2) * 33 + i] = raw.z;
    S[(j * 4 + 3) * 33 + i] = raw.w;
  }
  __syncthreads();
  if (tid < 128) {
    int c = tid;
    float mx = -1e30f;
    for (int i = 0; i < 32; i++) mx = fmaxf(mx, S[c * 33 + i]);
    float s = 0.f;
    for (int i = 0; i < 32; i++) s += expf(S[c * 33 + i] - mx);
    smx[c] = mx; sinv[c] = 1.f / s; sls[c] = logf(s);
  }
  __syncthreads();
  float4 sC0, sC1;  // packed {sm, sm*lg} for v=4t..4t+3, kept in regs until top done
  {
    int v = 4 * tid, e = v >> 10, j = (v >> 5) & 31, i0 = v & 31, c = j * 4 + e;
    float mx = smx[c], iv = sinv[c], ls = sls[c];
    float x0 = S[c * 33 + i0 + 0], x1 = S[c * 33 + i0 + 1];
    float x2 = S[c * 33 + i0 + 2], x3 = S[c * 33 + i0 + 3];
    float s0 = expf(x0 - mx) * iv, s1 = expf(x1 - mx) * iv;
    float s2 = expf(x2 - mx) * iv, s3 = expf(x3 - mx) * iv;
    float4 o; o.x = s0; o.y = s1; o.z = s2; o.w = s3;
    ((float4*)sAT)[tid] = o;
    sC0.x = s0; sC0.y = s0 * ((x0 - mx) - ls);
    sC0.z = s1; sC0.w = s1 * ((x1 - mx) - ls);
    sC1.x = s2; sC1.y = s2 * ((x2 - mx) - ls);
    sC1.z = s3; sC1.w = s3 * ((x3 - mx) - ls);
  }
  {
    int v = 4 * tid, e = v >> 10, i = (v >> 5) & 31, j0 = v & 31;
    float4 o;
    { int c = (j0 + 0) * 4 + e; o.x = expf(S[c * 33 + i] - smx[c]) * sinv[c]; }
    { int c = (j0 + 1) * 4 + e; o.y = expf(S[c * 33 + i] - smx[c]) * sinv[c]; }
    { int c = (j0 + 2) * 4 + e; o.z = expf(S[c * 33 + i] - smx[c]) * sinv[c]; }
    { int c = (j0 + 3) * 4 + e; o.w = expf(S[c * 33 + i] - smx[c]) * sinv[c]; }
    ((float4*)sA)[tid] = o;
  }
  __syncthreads();  // S dead; U usable

  // ---- label gathers (raw B + row stats): top sm/log, subtree log ----
  float subL[3], topS[3], topL[3]; int mI[3]; int scnt = 0;
  for (int m = grp; m < 85; m += 32) {
    float xt = Bm[lane * 256 + labels[m]];
    float xs = Bm[lane * 256 + labels[gmap(r, m)]];
    mI[scnt] = m;
    topS[scnt] = expf(xt - sBmx[lane]) * sBinv[lane];
    topL[scnt] = (xt - sBmx[lane]) - sBls[lane];
    subL[scnt] = (xs - sBmx[lane]) - sBls[lane];
    scnt++;
  }
  for (int k = 0; k < scnt; k++) mslb[mI[k] * 32 + lane] = topS[k];
  // smPi + logPi (registers, group 0 suffices)
  float pPi, lPi;
  {
    float x = Pi[lane];
    float mx = hmax32(x);
    float ex = expf(x - mx);
    float s = hsum32(ex);
    pPi = ex / s;
    lPi = (x - mx) - logf(s);
  }
  if (grp == 0) msp[lane] = pPi;
  __syncthreads();
  if (grp == 0) msb[lane] = msp[lane] * mslb[lane];
  __syncthreads();

  // ---- top-down levels 1..3 ----
  for (int l = 1; l <= 3; l++) {
    int st = LOFF[l], cnt = LOFF[l + 1] - st;
    for (int base = 0; base < cnt; base += 32) {
      int ix = base + grp;
      if (ix < cnt) {
        int n = st + ix, pa = (n - 1) >> 2, e = (n - 1) & 3;
        float acc = mv4(&sAT[e * 1024], &msp[pa * 32], lane);
        msp[n * 32 + lane] = acc;
        msb[n * 32 + lane] = acc * mslb[n * 32 + lane];
      }
    }
    __syncthreads();
  }
  // ---- top-up: level-3 parents from TB4 (R), then 2,1,0 ----
  {
    for (int base = 0; base < 64; base += 32) {
      int ix = base + grp;
      if (ix < 64) {
        int pn = 21 + ix;
        float prod = 1.f;
#pragma unroll
        for (int c = 0; c < 4; c++) {
          int n = 4 * pn + 1 + c;
          prod *= R[(n - 85) * 32 + lane];
        }
        float bn = msb[pn * 32 + lane] * prod;
        bn /= hsum32(bn);
        msb[pn * 32 + lane] = bn;
      }
    }
    __syncthreads();
    const int PST[3] = {5, 1, 0}, PCNT[3] = {16, 4, 1};
    for (int s = 0; s < 3; s++) {
      int st = PST[s], cnt = PCNT[s];
      int ix = grp;
      if (ix < cnt) {
        int pn = st + ix;
        float ppj = msp[pn * 32 + lane];
        float ac[4] = {0.f, 0.f, 0.f, 0.f};
#pragma unroll
        for (int j4 = 0; j4 < 8; j4++) {
#pragma unroll
          for (int c = 0; c < 4; c++) {
            float4 v = ((const float4*)&msb[(4 * pn + 1 + c) * 32])[j4];
            const float* t = &sA[c * 1024 + j4 * 128 + lane];
            ac[c] += t[0] * v.x + t[32] * v.y + t[64] * v.z + t[96] * v.w;
          }
        }
        float prod = 1.f;
#pragma unroll
        for (int c = 0; c < 4; c++) {
          float buv = ac[c] / ppj;
          mstb[(4 * pn + 1 + c) * 32 + lane] = buv;
          prod *= buv;
        }
        float bn = msb[pn * 32 + lane] * prod;
        bn /= hsum32(bn);
        msb[pn * 32 + lane] = bn;
      }
      __syncthreads();
    }
  }
  // ---- switch R -> sC; mslb -> log rows ----
  ((float4*)R)[tid] = sC0;
  ((float4*)R)[tid + 1024] = sC1;
  for (int k = 0; k < scnt; k++) mslb[mI[k] * 32 + lane] = topL[k];
  __syncthreads();
  const float2* sC = (const float2*)R;

  // ---- own ancestor eps chain: root -> a1 -> a2 -> a3 (group-redundant) ----
  const int a3 = (r - 1) >> 2, a2 = (a3 - 1) >> 2, a1 = (a2 - 1) >> 2;
  float peps = msb[lane];  // eps[root] = final root beta
  {
    int pathN[3] = {a1, a2, a3};
#pragma unroll
    for (int s = 0; s < 3; s++) {
      int n = pathN[s], e = (n - 1) & 3;
      sq[grp * 32 + lane] = peps / mstb[n * 32 + lane];
      float an, aa;
      mv4p(&sC[e * 1024], &sq[grp * 32], lane, an, aa);
      float ratio = msb[n * 32 + lane] / msp[n * 32 + lane];
      float num = ratio * an;
      float den = hsum32(num);
      peps = num / den;
    }
  }

  float lh = 0.f;
  if (bid == 0) {  // full top-eps + top lh (levels 0..3)
    if (grp == 0) {
      float v = msb[lane];
      mseps[lane] = v;
      lh += v * (lPi + mslb[lane]);  // Pi_lh + root B_lh
    }
    __syncthreads();
    const int EST[3] = {1, 5, 21}, ECNT[3] = {4, 16, 64};
    for (int s = 0; s < 3; s++) {
      int st = EST[s], cnt = ECNT[s];
      for (int base = 0; base < cnt; base += 32) {
        int ix = base + grp;
        if (ix < cnt) {
          int n = st + ix, pa = (n - 1) >> 2, e = (n - 1) & 3;
          float ratio = msb[n * 32 + lane] / msp[n * 32 + lane];
          sq[grp * 32 + lane] = mseps[pa * 32 + lane] / mstb[n * 32 + lane];
          float an, aa;
          mv4p(&sC[e * 1024], &sq[grp * 32], lane, an, aa);
          float num = ratio * an;
          float den = hsum32(num);
          float epsi = num / den;
          mseps[n * 32 + lane] = epsi;
          lh += ratio * aa + epsi * mslb[n * 32 + lane];
        }
      }
      __syncthreads();
    }
  }
  __syncthreads();  // top arrays dead; repurpose U

  // ---- subtree phase: write early-loaded stash + log-B rows ----
  if (tid < 680) {
    *(float4*)&stb[sm_ * 32 + sq_ * 4] = stT;
    *(float4*)&srt[sm_ * 32 + sq_ * 4] = stR;
  }
  for (int k = 0; k < scnt; k++) slbL[mI[k] * 32 + lane] = subL[k];
  __syncthreads();

  // eps at level-4 root r
  if (grp == 0) {
    int e = (r - 1) & 3;
    float ratio = srt[lane];
    sq[lane] = peps / stb[lane];
    float an, aa;
    mv4p(&sC[e * 1024], &sq[0], lane, an, aa);
    float num = ratio * an;
    float den = hsum32(num);
    float epsi = num / den;
    seps[lane] = epsi;
    lh += ratio * aa + epsi * slbL[lane];
  }
  __syncthreads();
  // subtree eps levels 1..3 (global 5..7)
  for (int d = 1; d <= 3; d++) {
    int st = LOFF[d], cnt = LOFF[d + 1] - st;
    for (int base = 0; base < cnt; base += 32) {
      int ix = base + grp;
      if (ix < cnt) {
        int m = st + ix, pa = (m - 1) >> 2, e = (m - 1) & 3;
        float ratio = srt[m * 32 + lane];
        sq[grp * 32 + lane] = seps[pa * 32 + lane] / stb[m * 32 + lane];
        float an, aa;
        mv4p(&sC[e * 1024], &sq[grp * 32], lane, an, aa);
        float num = ratio * an;
        float den = hsum32(num);
        float epsi = num / den;
        seps[m * 32 + lane] = epsi;
        lh += ratio * aa + epsi * slbL[m * 32 + lane];
      }
    }
    __syncthreads();
  }

  // ---- block partial -> atomicAdd ----
#pragma unroll
  for (int m2 = 32; m2 >= 1; m2 >>= 1) lh += __shfl_xor(lh, m2, 64);
  if ((tid & 63) == 0) sred[tid >> 6] = lh;
  __syncthreads();
  if (tid == 0) {
    float t = 0.f;
#pragma unroll
    for (int w = 0; w < 16; w++) t += sred[w];
    atomicAdd(out, t);
  }
}

extern "C" void kernel_launch(void* const* d_in, const int* in_sizes, int n_in,
                              void* d_out, int out_size, void* d_ws, size_t ws_size,
                              hipStream_t stream) {
  const float* A  = (const float*)d_in[0];
  const float* Bm = (const float*)d_in[1];
  const float* Pi = (const float*)d_in[2];
  const int* labels = (const int*)d_in[5];
  float* W = (float*)d_ws;
  float* out = (float*)d_out;

  k_sub2<<<256, 1024, 0, stream>>>(A, Bm, Pi, labels, W, out);
  k_eps3<<<256, 1024, 0, stream>>>(A, Bm, Pi, labels, W, out);
}

// Round 11
// 64.903 us; speedup vs baseline: 5.0562x; 1.0074x over previous
//
#include <hip/hip_runtime.h>
#include <math.h>

// TopDownHTMM: C=32, 4-ary tree depth 7, N=21845, M=256. Output: scalar fp32.
// TWO kernels, 1024 threads, __launch_bounds__(1024, 4) (126KB LDS -> 1 blk/CU).
// Round-10 postmortem: k_eps3's 8.9MB WRITE_SIZE was scratch from
// RUNTIME-INDEXED local arrays (subL[3]/topS[3]/topL[3]/mI[3] + scnt loops) —
// rule #20: those can't be register-promoted at ANY VGPR budget. This round
// scalarizes them into named registers with compile-time indexing.
//
//   k_sub2 (256x1024): in-block softmax tables from raw A/B/Pi, path prior,
//                      down 5-7, up 7-5; exports TB4 + t_beta/ratio stash.
//   k_eps3 (256x1024): in-block tables, redundant top-tree (down 0-3, up 4-1
//                      from TB4), own ancestor eps chain; block 0 adds full
//                      top-eps + top lh; subtree eps 4-7 + lh; atomicAdd.
//
// Subtree r in [85,341): local m in [0,85), depth d, global g = 4^d*r + m;
// parent=(m-1)>>2, pos=(m-1)&3 hold locally.

#define NF (21845 * 32)

enum : int {
  W_TBETA = 0,          // [N][32] rows 85..21844 (+ row r per subtree)
  W_RATIO = NF,         // [N][32] (beta_final/prior)
  W_TB4   = 2 * NF,     // [256][32] level-4 t_beta (index r-85)
};

__device__ inline float hsum32(float v) {
#pragma unroll
  for (int m = 16; m >= 1; m >>= 1) v += __shfl_xor(v, m, 32);
  return v;
}
__device__ inline float hmax32(float v) {
#pragma unroll
  for (int m = 16; m >= 1; m >>= 1) v = fmaxf(v, __shfl_xor(v, m, 32));
  return v;
}
// global row index for local node m of subtree r
__device__ inline int gmap(int r, int m) {
  return (m == 0) ? r : (m < 5 ? 4 * r + m : (m < 21 ? 16 * r + m : 64 * r + m));
}

// 32x32 matvec, 4 independent fma chains; T row-major over j, lane = out idx.
__device__ inline float mv4(const float* __restrict__ T, const float* __restrict__ vec,
                            int lane) {
  const float4* v4 = (const float4*)vec;
  float a0 = 0.f, a1 = 0.f, a2 = 0.f, a3 = 0.f;
#pragma unroll
  for (int j4 = 0; j4 < 8; j4++) {
    float4 v = v4[j4];
    const float* t = &T[j4 * 128 + lane];
    a0 += t[0] * v.x; a1 += t[32] * v.y; a2 += t[64] * v.z; a3 += t[96] * v.w;
  }
  return (a0 + a1) + (a2 + a3);
}

// packed version: num (sm*q) and alh (sm*log*q)
__device__ inline void mv4p(const float2* __restrict__ T, const float* __restrict__ vec,
                            int lane, float& an, float& aa) {
  const float4* v4 = (const float4*)vec;
  float n0 = 0.f, n1 = 0.f, n2 = 0.f, n3 = 0.f;
  float l0 = 0.f, l1 = 0.f, l2 = 0.f, l3 = 0.f;
#pragma unroll
  for (int j4 = 0; j4 < 8; j4++) {
    float4 v = v4[j4];
    const float2* t = &T[j4 * 128 + lane];
    float2 x0 = t[0], x1 = t[32], x2 = t[64], x3 = t[96];
    n0 += x0.x * v.x; n1 += x1.x * v.y; n2 += x2.x * v.z; n3 += x3.x * v.w;
    l0 += x0.y * v.x; l1 += x1.y * v.y; l2 += x2.y * v.z; l3 += x3.y * v.w;
  }
  an = (n0 + n1) + (n2 + n3);
  aa = (l0 + l1) + (l2 + l3);
}

// ---------------- K1: per-subtree down 5-7 + up 7-5 (in-block tables) -------
__global__ __launch_bounds__(1024, 4) void k_sub2(const float* __restrict__ A,
                                                  const float* __restrict__ Bm,
                                                  const float* __restrict__ Pi,
                                                  const int* __restrict__ labels,
                                                  float* __restrict__ W,
                                                  float* __restrict__ out) {
  __shared__ float sAT[4096], sA[4096];
  __shared__ float SH[10880];            // sp|sb|stb|slb; staging S aliases front
  __shared__ float smx[128], sinv[128];
  __shared__ float sBmx[32], sBinv[32];
  float* sp  = SH;          float* sb  = SH + 2720;
  float* stb = SH + 5440;   float* slb = SH + 8160;
  float* S   = SH;                       // 128*33 = 4224 floats, dead after build

  const int tid = threadIdx.x, bid = blockIdx.x;
  const int grp = tid >> 5, lane = tid & 31;
  const int r = 85 + bid;
  if (bid == 0 && tid == 0) out[0] = 0.f;

  // ---- B row stats (row = grp): max + 1/sum ----
  {
    float xs[8], mx = -1e30f;
#pragma unroll
    for (int k = 0; k < 8; k++) { xs[k] = Bm[grp * 256 + k * 32 + lane]; mx = fmaxf(mx, xs[k]); }
    mx = hmax32(mx);
    float s = 0.f;
#pragma unroll
    for (int k = 0; k < 8; k++) s += expf(xs[k] - mx);
    s = hsum32(s);
    if (lane == 0) { sBmx[grp] = mx; sBinv[grp] = 1.f / s; }
  }
  // ---- stage raw A coalesced -> padded S[(j*4+e)*33 + i] ----
  {
    float4 raw = ((const float4*)A)[tid];   // (i = tid>>5, j = tid&31, e=0..3)
    int i = tid >> 5, j = tid & 31;
    S[(j * 4 + 0) * 33 + i] = raw.x;
    S[(j * 4 + 1) * 33 + i] = raw.y;
    S[(j * 4 + 2) * 33 + i] = raw.z;
    S[(j * 4 + 3) * 33 + i] = raw.w;
  }
  __syncthreads();
  if (tid < 128) {  // column stats (c = j*4+e)
    int c = tid;
    float mx = -1e30f;
    for (int i = 0; i < 32; i++) mx = fmaxf(mx, S[c * 33 + i]);
    float s = 0.f;
    for (int i = 0; i < 32; i++) s += expf(S[c * 33 + i] - mx);
    smx[c] = mx; sinv[c] = 1.f / s;
  }
  __syncthreads();
  // ---- emit sAT [e][j][i] (float4, conflict-free) ----
  {
    int v = 4 * tid, e = v >> 10, j = (v >> 5) & 31, i0 = v & 31, c = j * 4 + e;
    float mx = smx[c], iv = sinv[c];
    float4 o;
    o.x = expf(S[c * 33 + i0 + 0] - mx) * iv;
    o.y = expf(S[c * 33 + i0 + 1] - mx) * iv;
    o.z = expf(S[c * 33 + i0 + 2] - mx) * iv;
    o.w = expf(S[c * 33 + i0 + 3] - mx) * iv;
    ((float4*)sAT)[tid] = o;
  }
  // ---- emit sA [e][i][j] (float4, conflict-free) ----
  {
    int v = 4 * tid, e = v >> 10, i = (v >> 5) & 31, j0 = v & 31;
    float4 o;
    { int c = (j0 + 0) * 4 + e; o.x = expf(S[c * 33 + i] - smx[c]) * sinv[c]; }
    { int c = (j0 + 1) * 4 + e; o.y = expf(S[c * 33 + i] - smx[c]) * sinv[c]; }
    { int c = (j0 + 2) * 4 + e; o.z = expf(S[c * 33 + i] - smx[c]) * sinv[c]; }
    { int c = (j0 + 3) * 4 + e; o.w = expf(S[c * 33 + i] - smx[c]) * sinv[c]; }
    ((float4*)sA)[tid] = o;
  }
  __syncthreads();  // S dead; sp/sb usable

  // ---- smB label rows (static 3-slot, direct to LDS) ----
  {
    const int m0 = grp, m1 = grp + 32, m2 = grp + 64;
    float bmx = sBmx[lane], binv = sBinv[lane];
    float x0 = Bm[lane * 256 + labels[gmap(r, m0)]];
    float x1 = Bm[lane * 256 + labels[gmap(r, m1)]];
    slb[m0 * 32 + lane] = expf(x0 - bmx) * binv;
    slb[m1 * 32 + lane] = expf(x1 - bmx) * binv;
    if (m2 < 85) {
      float x2 = Bm[lane * 256 + labels[gmap(r, m2)]];
      slb[m2 * 32 + lane] = expf(x2 - bmx) * binv;
    }
  }
  // ---- smPi (register, group-redundant) + path prior ----
  float pPi;
  {
    float x = Pi[lane];
    float mx = hmax32(x);
    float ex = expf(x - mx);
    pPi = ex / hsum32(ex);
  }
  const int a3 = (r - 1) >> 2, a2 = (a3 - 1) >> 2, a1 = (a2 - 1) >> 2;
  float p = pPi, p3 = 0.f;
  {
    int es[4] = {(a1 - 1) & 3, (a2 - 1) & 3, (a3 - 1) & 3, (r - 1) & 3};
#pragma unroll
    for (int s = 0; s < 4; s++) {
      float acc = 0.f;
#pragma unroll
      for (int j = 0; j < 32; j++)
        acc += sAT[es[s] * 1024 + j * 32 + lane] * __shfl(p, j, 32);
      if (s == 2) p3 = acc;
      p = acc;
    }
  }
  if (tid < 32) { sp[tid] = p; sb[tid] = p * slb[tid]; }
  __syncthreads();

  const int LOFF[5] = {0, 1, 5, 21, 85};
  // down local 1..3 (global 5..7)
  for (int d = 1; d <= 3; d++) {
    int st = LOFF[d], cnt = LOFF[d + 1] - st;
    for (int base = 0; base < cnt; base += 32) {
      int ix = base + grp;
      if (ix < cnt) {
        int m = st + ix, pam = (m - 1) >> 2, e = (m - 1) & 3;
        float acc = mv4(&sAT[e * 1024], &sp[pam * 32], lane);
        sp[m * 32 + lane] = acc;
        float bv = acc * slb[m * 32 + lane];
        if (d == 3) bv /= hsum32(bv);  // leaves normalized
        sb[m * 32 + lane] = bv;
      }
    }
    __syncthreads();
  }
  // up: parents at local 2,1,0 — 4-child interleaved ILP
  for (int d = 2; d >= 0; d--) {
    int st = LOFF[d], cnt = LOFF[d + 1] - st;
    for (int base = 0; base < cnt; base += 32) {
      int ix = base + grp;
      if (ix < cnt) {
        int pn = st + ix;
        float ppj = sp[pn * 32 + lane];
        float ac[4] = {0.f, 0.f, 0.f, 0.f};
#pragma unroll
        for (int j4 = 0; j4 < 8; j4++) {
#pragma unroll
          for (int c = 0; c < 4; c++) {
            float4 v = ((const float4*)&sb[(4 * pn + 1 + c) * 32])[j4];
            const float* t = &sA[c * 1024 + j4 * 128 + lane];
            ac[c] += t[0] * v.x + t[32] * v.y + t[64] * v.z + t[96] * v.w;
          }
        }
        float prod = 1.f;
#pragma unroll
        for (int c = 0; c < 4; c++) {
          float buv = ac[c] / ppj;
          stb[(4 * pn + 1 + c) * 32 + lane] = buv;
          prod *= buv;
        }
        float bn = sb[pn * 32 + lane] * prod;
        bn /= hsum32(bn);
        sb[pn * 32 + lane] = bn;
      }
    }
    __syncthreads();
  }
  // local-root t_beta + TB4 export
  if (tid < 32) {
    int e = (r - 1) & 3;
    float acc = mv4(&sA[e * 1024], &sb[0], tid);
    float tb = acc / p3;
    stb[tid] = tb;
    W[W_TB4 + bid * 32 + tid] = tb;
  }
  __syncthreads();
  // coalesced stash: t_beta + ratio for all 85 local rows
  if (tid < 680) {
    int m = tid >> 3, q = tid & 7, g = gmap(r, m);
    *(float4*)&W[W_TBETA + g * 32 + q * 4] = *(float4*)&stb[m * 32 + q * 4];
    float4 bb = *(float4*)&sb[m * 32 + q * 4], pp = *(float4*)&sp[m * 32 + q * 4];
    float4 rr;
    rr.x = bb.x / pp.x; rr.y = bb.y / pp.y; rr.z = bb.z / pp.z; rr.w = bb.w / pp.w;
    *(float4*)&W[W_RATIO + g * 32 + q * 4] = rr;
  }
}

// ---------------- K2: redundant top tree + eps (levels 1-7) + lh ------------
__global__ __launch_bounds__(1024, 4) void k_eps3(const float* __restrict__ A,
                                                  const float* __restrict__ Bm,
                                                  const float* __restrict__ Pi,
                                                  const int* __restrict__ labels,
                                                  float* __restrict__ W,
                                                  float* __restrict__ out) {
  __shared__ float sAT[4096], sA[4096];
  __shared__ float R[8192];     // phase A: TB4; phase B: packed sC
  __shared__ float U[13600];    // top: msp,msb,mstb,mslb,mseps | sub aliases
  __shared__ float sq[1024];
  __shared__ float smx[128], sinv[128], sls[128];
  __shared__ float sBmx[32], sBinv[32], sBls[32];
  __shared__ float sred[16];
  float* msp   = U;            float* msb  = U + 2720;
  float* mstb  = U + 5440;     float* mslb = U + 8160;
  float* mseps = U + 10880;
  float* stb = U;              float* srt  = U + 2720;
  float* seps = U + 5440;      float* slbL = U + 8160;
  float* S = U;                // staging 4224 floats, dead after build

  const int tid = threadIdx.x, bid = blockIdx.x;
  const int grp = tid >> 5, lane = tid & 31;
  const int r = 85 + bid;
  const int LOFF[5] = {0, 1, 5, 21, 85};

  // ---- early global issues (static indexing only) ----
  float4 stT, stR;
  const int sm_ = tid >> 3, sq_ = tid & 7;
  if (tid < 680) {
    int g = gmap(r, sm_);
    stT = *(const float4*)&W[W_TBETA + g * 32 + sq_ * 4];
    stR = *(const float4*)&W[W_RATIO + g * 32 + sq_ * 4];
  }
  { ((float4*)R)[tid]        = ((const float4*)(W + W_TB4))[tid];       // TB4
    ((float4*)R)[tid + 1024] = ((const float4*)(W + W_TB4))[tid + 1024]; }

  // ---- B row stats (max, 1/sum, log sum) ----
  {
    float xs[8], mx = -1e30f;
#pragma unroll
    for (int k = 0; k < 8; k++) { xs[k] = Bm[grp * 256 + k * 32 + lane]; mx = fmaxf(mx, xs[k]); }
    mx = hmax32(mx);
    float s = 0.f;
#pragma unroll
    for (int k = 0; k < 8; k++) s += expf(xs[k] - mx);
    s = hsum32(s);
    if (lane == 0) { sBmx[grp] = mx; sBinv[grp] = 1.f / s; sBls[grp] = logf(s); }
  }
  // ---- stage raw A ----
  {
    float4 raw = ((const float4*)A)[tid];
    int i = tid >> 5, j = tid & 31;
    S[(j * 4 + 0) * 33 + i] = raw.x;
    S[(j * 4 + 1) * 33 + i] = raw.y;
    S[(j * 4 + 2) * 33 + i] = raw.z;
    S[(j * 4 + 3) * 33 + i] = raw.w;
  }
  __syncthreads();
  if (tid < 128) {
    int c = tid;
    float mx = -1e30f;
    for (int i = 0; i < 32; i++) mx = fmaxf(mx, S[c * 33 + i]);
    float s = 0.f;
    for (int i = 0; i < 32; i++) s += expf(S[c * 33 + i] - mx);
    smx[c] = mx; sinv[c] = 1.f / s; sls[c] = logf(s);
  }
  __syncthreads();
  float4 sC0, sC1;  // packed {sm, sm*lg}, kept in regs until top phase done
  {
    int v = 4 * tid, e = v >> 10, j = (v >> 5) & 31, i0 = v & 31, c = j * 4 + e;
    float mx = smx[c], iv = sinv[c], ls = sls[c];
    float x0 = S[c * 33 + i0 + 0], x1 = S[c * 33 + i0 + 1];
    float x2 = S[c * 33 + i0 + 2], x3 = S[c * 33 + i0 + 3];
    float s0 = expf(x0 - mx) * iv, s1 = expf(x1 - mx) * iv;
    float s2 = expf(x2 - mx) * iv, s3 = expf(x3 - mx) * iv;
    float4 o; o.x = s0; o.y = s1; o.z = s2; o.w = s3;
    ((float4*)sAT)[tid] = o;
    sC0.x = s0; sC0.y = s0 * ((x0 - mx) - ls);
    sC0.z = s1; sC0.w = s1 * ((x1 - mx) - ls);
    sC1.x = s2; sC1.y = s2 * ((x2 - mx) - ls);
    sC1.z = s3; sC1.w = s3 * ((x3 - mx) - ls);
  }
  {
    int v = 4 * tid, e = v >> 10, i = (v >> 5) & 31, j0 = v & 31;
    float4 o;
    { int c = (j0 + 0) * 4 + e; o.x = expf(S[c * 33 + i] - smx[c]) * sinv[c]; }
    { int c = (j0 + 1) * 4 + e; o.y = expf(S[c * 33 + i] - smx[c]) * sinv[c]; }
    { int c = (j0 + 2) * 4 + e; o.z = expf(S[c * 33 + i] - smx[c]) * sinv[c]; }
    { int c = (j0 + 3) * 4 + e; o.w = expf(S[c * 33 + i] - smx[c]) * sinv[c]; }
    ((float4*)sA)[tid] = o;
  }
  __syncthreads();  // S dead; U usable

  // ---- label gathers: STATIC 3-slot named registers (rule #20 fix) ----
  const int m0 = grp, m1 = grp + 32, m2 = grp + 64;
  const bool h2 = (m2 < 85);
  float topS0, topS1, topS2 = 0.f;
  float topL0, topL1, topL2 = 0.f;
  float subL0, subL1, subL2 = 0.f;
  {
    float bmx = sBmx[lane], binv = sBinv[lane], bls = sBls[lane];
    float xt0 = Bm[lane * 256 + labels[m0]];
    float xs0 = Bm[lane * 256 + labels[gmap(r, m0)]];
    float xt1 = Bm[lane * 256 + labels[m1]];
    float xs1 = Bm[lane * 256 + labels[gmap(r, m1)]];
    topS0 = expf(xt0 - bmx) * binv; topL0 = (xt0 - bmx) - bls; subL0 = (xs0 - bmx) - bls;
    topS1 = expf(xt1 - bmx) * binv; topL1 = (xt1 - bmx) - bls; subL1 = (xs1 - bmx) - bls;
    if (h2) {
      float xt2 = Bm[lane * 256 + labels[m2]];
      float xs2 = Bm[lane * 256 + labels[gmap(r, m2)]];
      topS2 = expf(xt2 - bmx) * binv; topL2 = (xt2 - bmx) - bls; subL2 = (xs2 - bmx) - bls;
    }
  }
  mslb[m0 * 32 + lane] = topS0;
  mslb[m1 * 32 + lane] = topS1;
  if (h2) mslb[m2 * 32 + lane] = topS2;
  // smPi + logPi (registers)
  float pPi, lPi;
  {
    float x = Pi[lane];
    float mx = hmax32(x);
    float ex = expf(x - mx);
    float s = hsum32(ex);
    pPi = ex / s;
    lPi = (x - mx) - logf(s);
  }
  if (grp == 0) msp[lane] = pPi;
  __syncthreads();
  if (grp == 0) msb[lane] = msp[lane] * mslb[lane];
  __syncthreads();

  // ---- top-down levels 1..3 ----
  for (int l = 1; l <= 3; l++) {
    int st = LOFF[l], cnt = LOFF[l + 1] - st;
    for (int base = 0; base < cnt; base += 32) {
      int ix = base + grp;
      if (ix < cnt) {
        int n = st + ix, pa = (n - 1) >> 2, e = (n - 1) & 3;
        float acc = mv4(&sAT[e * 1024], &msp[pa * 32], lane);
        msp[n * 32 + lane] = acc;
        msb[n * 32 + lane] = acc * mslb[n * 32 + lane];
      }
    }
    __syncthreads();
  }
  // ---- top-up: level-3 parents from TB4 (R), then 2,1,0 ----
  {
    for (int base = 0; base < 64; base += 32) {
      int ix = base + grp;
      if (ix < 64) {
        int pn = 21 + ix;
        float prod = 1.f;
#pragma unroll
        for (int c = 0; c < 4; c++) {
          int n = 4 * pn + 1 + c;
          prod *= R[(n - 85) * 32 + lane];
        }
        float bn = msb[pn * 32 + lane] * prod;
        bn /= hsum32(bn);
        msb[pn * 32 + lane] = bn;
      }
    }
    __syncthreads();
    const int PST[3] = {5, 1, 0}, PCNT[3] = {16, 4, 1};
    for (int s = 0; s < 3; s++) {
      int st = PST[s], cnt = PCNT[s];
      int ix = grp;
      if (ix < cnt) {
        int pn = st + ix;
        float ppj = msp[pn * 32 + lane];
        float ac[4] = {0.f, 0.f, 0.f, 0.f};
#pragma unroll
        for (int j4 = 0; j4 < 8; j4++) {
#pragma unroll
          for (int c = 0; c < 4; c++) {
            float4 v = ((const float4*)&msb[(4 * pn + 1 + c) * 32])[j4];
            const float* t = &sA[c * 1024 + j4 * 128 + lane];
            ac[c] += t[0] * v.x + t[32] * v.y + t[64] * v.z + t[96] * v.w;
          }
        }
        float prod = 1.f;
#pragma unroll
        for (int c = 0; c < 4; c++) {
          float buv = ac[c] / ppj;
          mstb[(4 * pn + 1 + c) * 32 + lane] = buv;
          prod *= buv;
        }
        float bn = msb[pn * 32 + lane] * prod;
        bn /= hsum32(bn);
        msb[pn * 32 + lane] = bn;
      }
      __syncthreads();
    }
  }
  // ---- switch R -> sC; mslb -> log rows (static slots) ----
  ((float4*)R)[tid] = sC0;
  ((float4*)R)[tid + 1024] = sC1;
  mslb[m0 * 32 + lane] = topL0;
  mslb[m1 * 32 + lane] = topL1;
  if (h2) mslb[m2 * 32 + lane] = topL2;
  __syncthreads();
  const float2* sC = (const float2*)R;

  // ---- own ancestor eps chain: root -> a1 -> a2 -> a3 (group-redundant) ----
  const int a3 = (r - 1) >> 2, a2 = (a3 - 1) >> 2, a1 = (a2 - 1) >> 2;
  float peps = msb[lane];  // eps[root] = final root beta
  {
    int pathN[3] = {a1, a2, a3};
#pragma unroll
    for (int s = 0; s < 3; s++) {
      int n = pathN[s], e = (n - 1) & 3;
      sq[grp * 32 + lane] = peps / mstb[n * 32 + lane];
      float an, aa;
      mv4p(&sC[e * 1024], &sq[grp * 32], lane, an, aa);
      float ratio = msb[n * 32 + lane] / msp[n * 32 + lane];
      float num = ratio * an;
      float den = hsum32(num);
      peps = num / den;
    }
  }

  float lh = 0.f;
  if (bid == 0) {  // full top-eps + top lh (levels 0..3)
    if (grp == 0) {
      float v = msb[lane];
      mseps[lane] = v;
      lh += v * (lPi + mslb[lane]);  // Pi_lh + root B_lh
    }
    __syncthreads();
    const int EST[3] = {1, 5, 21}, ECNT[3] = {4, 16, 64};
    for (int s = 0; s < 3; s++) {
      int st = EST[s], cnt = ECNT[s];
      for (int base = 0; base < cnt; base += 32) {
        int ix = base + grp;
        if (ix < cnt) {
          int n = st + ix, pa = (n - 1) >> 2, e = (n - 1) & 3;
          float ratio = msb[n * 32 + lane] / msp[n * 32 + lane];
          sq[grp * 32 + lane] = mseps[pa * 32 + lane] / mstb[n * 32 + lane];
          float an, aa;
          mv4p(&sC[e * 1024], &sq[grp * 32], lane, an, aa);
          float num = ratio * an;
          float den = hsum32(num);
          float epsi = num / den;
          mseps[n * 32 + lane] = epsi;
          lh += ratio * aa + epsi * mslb[n * 32 + lane];
        }
      }
      __syncthreads();
    }
  }
  __syncthreads();  // top arrays dead; repurpose U

  // ---- subtree phase: write early-loaded stash + log-B rows (static) ----
  if (tid < 680) {
    *(float4*)&stb[sm_ * 32 + sq_ * 4] = stT;
    *(float4*)&srt[sm_ * 32 + sq_ * 4] = stR;
  }
  slbL[m0 * 32 + lane] = subL0;
  slbL[m1 * 32 + lane] = subL1;
  if (h2) slbL[m2 * 32 + lane] = subL2;
  __syncthreads();

  // eps at level-4 root r
  if (grp == 0) {
    int e = (r - 1) & 3;
    float ratio = srt[lane];
    sq[lane] = peps / stb[lane];
    float an, aa;
    mv4p(&sC[e * 1024], &sq[0], lane, an, aa);
    float num = ratio * an;
    float den = hsum32(num);
    float epsi = num / den;
    seps[lane] = epsi;
    lh += ratio * aa + epsi * slbL[lane];
  }
  __syncthreads();
  // subtree eps levels 1..3 (global 5..7)
  for (int d = 1; d <= 3; d++) {
    int st = LOFF[d], cnt = LOFF[d + 1] - st;
    for (int base = 0; base < cnt; base += 32) {
      int ix = base + grp;
      if (ix < cnt) {
        int m = st + ix, pa = (m - 1) >> 2, e = (m - 1) & 3;
        float ratio = srt[m * 32 + lane];
        sq[grp * 32 + lane] = seps[pa * 32 + lane] / stb[m * 32 + lane];
        float an, aa;
        mv4p(&sC[e * 1024], &sq[grp * 32], lane, an, aa);
        float num = ratio * an;
        float den = hsum32(num);
        float epsi = num / den;
        seps[m * 32 + lane] = epsi;
        lh += ratio * aa + epsi * slbL[m * 32 + lane];
      }
    }
    __syncthreads();
  }

  // ---- block partial -> atomicAdd ----
#pragma unroll
  for (int m2_ = 32; m2_ >= 1; m2_ >>= 1) lh += __shfl_xor(lh, m2_, 64);
  if ((tid & 63) == 0) sred[tid >> 6] = lh;
  __syncthreads();
  if (tid == 0) {
    float t = 0.f;
#pragma unroll
    for (int w = 0; w < 16; w++) t += sred[w];
    atomicAdd(out, t);
  }
}

extern "C" void kernel_launch(void* const* d_in, const int* in_sizes, int n_in,
                              void* d_out, int out_size, void* d_ws, size_t ws_size,
                              hipStream_t stream) {
  const float* A  = (const float*)d_in[0];
  const float* Bm = (const float*)d_in[1];
  const float* Pi = (const float*)d_in[2];
  const int* labels = (const int*)d_in[5];
  float* W = (float*)d_ws;
  float* out = (float*)d_out;

  k_sub2<<<256, 1024, 0, stream>>>(A, Bm, Pi, labels, W, out);
  k_eps3<<<256, 1024, 0, stream>>>(A, Bm, Pi, labels, W, out);
}

// Round 12
// 55.001 us; speedup vs baseline: 5.9665x; 1.1800x over previous
//
#include <hip/hip_runtime.h>
#include <math.h>

// TopDownHTMM: C=32, 4-ary tree depth 7, N=21845, M=256. Output: scalar fp32.
// TWO kernels, 1024 threads, __launch_bounds__(1024, 4).
//
// Round-11 postmortem: kernels are LDS-ISSUE-THROUGHPUT bound (each matvec =
// ~40 DS ops/wave; ~4000 cy/phase on the CU LDS pipe). Fix: per-group
// REGISTER-RESIDENT table columns. Invariant: for st in {1,5,21,85} and base
// stepping by 32, e=(m-1)&3 == grp&3, so each group uses ONE e-class table.
// Matvec = 8 broadcast b128 reads + 32 reg-FMAs (~10 DS ops, 4x fewer).
//
// Subtree r in [85,341): local m in [0,85), depth d, global g = 4^d*r + m;
// parent=(m-1)>>2, pos=(m-1)&3 hold locally.

#define NF (21845 * 32)

enum : int {
  W_TBETA = 0,          // [N][32] rows 85..21844 (+ row r per subtree)
  W_RATIO = NF,         // [N][32] (beta_final/prior)
  W_TB4   = 2 * NF,     // [256][32] level-4 t_beta (index r-85)
};

__device__ inline float hsum32(float v) {
#pragma unroll
  for (int m = 16; m >= 1; m >>= 1) v += __shfl_xor(v, m, 32);
  return v;
}
__device__ inline float hmax32(float v) {
#pragma unroll
  for (int m = 16; m >= 1; m >>= 1) v = fmaxf(v, __shfl_xor(v, m, 32));
  return v;
}
__device__ inline int gmap(int r, int m) {
  return (m == 0) ? r : (m < 5 ? 4 * r + m : (m < 21 ? 16 * r + m : 64 * r + m));
}

// reg-table matvec: out[lane] = sum_j T[j] * vec[j]; vec via b128 broadcast.
__device__ inline float mvreg(const float (&T)[32], const float* __restrict__ vec) {
  const float4* v4 = (const float4*)vec;
  float a0 = 0.f, a1 = 0.f, a2 = 0.f, a3 = 0.f;
#pragma unroll
  for (int j4 = 0; j4 < 8; j4++) {
    float4 v = v4[j4];
    a0 += T[4 * j4 + 0] * v.x; a1 += T[4 * j4 + 1] * v.y;
    a2 += T[4 * j4 + 2] * v.z; a3 += T[4 * j4 + 3] * v.w;
  }
  return (a0 + a1) + (a2 + a3);
}
// dual version (num table + log table share the vector reads)
__device__ inline void mvreg2(const float (&Tn)[32], const float (&Tl)[32],
                              const float* __restrict__ vec, float& an, float& aa) {
  const float4* v4 = (const float4*)vec;
  float n0 = 0.f, n1 = 0.f, n2 = 0.f, n3 = 0.f;
  float l0 = 0.f, l1 = 0.f, l2 = 0.f, l3 = 0.f;
#pragma unroll
  for (int j4 = 0; j4 < 8; j4++) {
    float4 v = v4[j4];
    n0 += Tn[4 * j4 + 0] * v.x; n1 += Tn[4 * j4 + 1] * v.y;
    n2 += Tn[4 * j4 + 2] * v.z; n3 += Tn[4 * j4 + 3] * v.w;
    l0 += Tl[4 * j4 + 0] * v.x; l1 += Tl[4 * j4 + 1] * v.y;
    l2 += Tl[4 * j4 + 2] * v.z; l3 += Tl[4 * j4 + 3] * v.w;
  }
  an = (n0 + n1) + (n2 + n3);
  aa = (l0 + l1) + (l2 + l3);
}

// ---------------- K1: per-subtree down 5-7 + up 7-5 -------------------------
__global__ __launch_bounds__(1024, 4) void k_sub2(const float* __restrict__ A,
                                                  const float* __restrict__ Bm,
                                                  const float* __restrict__ Pi,
                                                  const int* __restrict__ labels,
                                                  float* __restrict__ W,
                                                  float* __restrict__ out) {
  __shared__ __align__(16) float sAT[4096], sA[4096];
  __shared__ __align__(16) float SH[10880];
  __shared__ float smx[128], sinv[128];
  __shared__ float sBmx[32], sBinv[32];
  __shared__ __align__(16) float spath[32];
  __shared__ float sp3v[32];
  float* sp  = SH;          float* sb  = SH + 2720;
  float* stb = SH + 5440;   float* slb = SH + 8160;
  float* S   = SH;          // staging 4224 floats, dead after build

  const int tid = threadIdx.x, bid = blockIdx.x;
  const int grp = tid >> 5, lane = tid & 31;
  const int ecl = grp & 3, slot = grp >> 2;
  const int r = 85 + bid;
  if (bid == 0 && tid == 0) out[0] = 0.f;

  // ---- B row stats ----
  {
    float xs[8], mx = -1e30f;
#pragma unroll
    for (int k = 0; k < 8; k++) { xs[k] = Bm[grp * 256 + k * 32 + lane]; mx = fmaxf(mx, xs[k]); }
    mx = hmax32(mx);
    float s = 0.f;
#pragma unroll
    for (int k = 0; k < 8; k++) s += expf(xs[k] - mx);
    s = hsum32(s);
    if (lane == 0) { sBmx[grp] = mx; sBinv[grp] = 1.f / s; }
  }
  // ---- stage raw A -> padded S ----
  {
    float4 raw = ((const float4*)A)[tid];
    int i = tid >> 5, j = tid & 31;
    S[(j * 4 + 0) * 33 + i] = raw.x;
    S[(j * 4 + 1) * 33 + i] = raw.y;
    S[(j * 4 + 2) * 33 + i] = raw.z;
    S[(j * 4 + 3) * 33 + i] = raw.w;
  }
  __syncthreads();
  if (tid < 128) {
    int c = tid;
    float mx = -1e30f;
    for (int i = 0; i < 32; i++) mx = fmaxf(mx, S[c * 33 + i]);
    float s = 0.f;
    for (int i = 0; i < 32; i++) s += expf(S[c * 33 + i] - mx);
    smx[c] = mx; sinv[c] = 1.f / s;
  }
  __syncthreads();
  {  // emit sAT [e][j][i]
    int v = 4 * tid, e = v >> 10, j = (v >> 5) & 31, i0 = v & 31, c = j * 4 + e;
    float mx = smx[c], iv = sinv[c];
    float4 o;
    o.x = expf(S[c * 33 + i0 + 0] - mx) * iv;
    o.y = expf(S[c * 33 + i0 + 1] - mx) * iv;
    o.z = expf(S[c * 33 + i0 + 2] - mx) * iv;
    o.w = expf(S[c * 33 + i0 + 3] - mx) * iv;
    ((float4*)sAT)[tid] = o;
  }
  {  // emit sA [e][i][j]
    int v = 4 * tid, e = v >> 10, i = (v >> 5) & 31, j0 = v & 31;
    float4 o;
    { int c = (j0 + 0) * 4 + e; o.x = expf(S[c * 33 + i] - smx[c]) * sinv[c]; }
    { int c = (j0 + 1) * 4 + e; o.y = expf(S[c * 33 + i] - smx[c]) * sinv[c]; }
    { int c = (j0 + 2) * 4 + e; o.z = expf(S[c * 33 + i] - smx[c]) * sinv[c]; }
    { int c = (j0 + 3) * 4 + e; o.w = expf(S[c * 33 + i] - smx[c]) * sinv[c]; }
    ((float4*)sA)[tid] = o;
  }
  __syncthreads();  // S dead

  // ---- smB label rows (static 3-slot, direct to LDS) ----
  {
    const int m0 = grp, m1 = grp + 32, m2 = grp + 64;
    float bmx = sBmx[lane], binv = sBinv[lane];
    float x0 = Bm[lane * 256 + labels[gmap(r, m0)]];
    float x1 = Bm[lane * 256 + labels[gmap(r, m1)]];
    slb[m0 * 32 + lane] = expf(x0 - bmx) * binv;
    slb[m1 * 32 + lane] = expf(x1 - bmx) * binv;
    if (m2 < 85) {
      float x2 = Bm[lane * 256 + labels[gmap(r, m2)]];
      slb[m2 * 32 + lane] = expf(x2 - bmx) * binv;
    }
  }
  // smPi + spath init
  {
    float x = Pi[lane];
    float mx = hmax32(x);
    float ex = expf(x - mx);
    float pPi = ex / hsum32(ex);
    if (tid < 32) spath[tid] = pPi;
  }
  // ---- down-table into registers (class = grp&3) ----
  float D[32];
#pragma unroll
  for (int j = 0; j < 32; j++) D[j] = sAT[(grp & 3) * 1024 + j * 32 + lane];
  __syncthreads();

  // ---- path prior chain root->a1->a2->a3->r (class-matching group) ----
  const int a3n = (r - 1) >> 2, a2n = (a3n - 1) >> 2, a1n = (a2n - 1) >> 2;
  const int pe0 = (a1n - 1) & 3, pe1 = (a2n - 1) & 3, pe2 = (a3n - 1) & 3, pe3 = (r - 1) & 3;
  if (ecl == pe0 && slot == 0) spath[lane] = mvreg(D, spath);
  __syncthreads();
  if (ecl == pe1 && slot == 0) spath[lane] = mvreg(D, spath);
  __syncthreads();
  if (ecl == pe2 && slot == 0) { float a = mvreg(D, spath); spath[lane] = a; sp3v[lane] = a; }
  __syncthreads();
  if (ecl == pe3 && slot == 0) spath[lane] = mvreg(D, spath);
  __syncthreads();
  if (tid < 32) { sp[tid] = spath[tid]; sb[tid] = spath[tid] * slb[tid]; }
  __syncthreads();

  const int LOFF[5] = {0, 1, 5, 21, 85};
  // ---- down local 1..3 (e == grp&3 by construction) ----
  for (int d = 1; d <= 3; d++) {
    int st = LOFF[d], cnt = LOFF[d + 1] - st;
    for (int base = 0; base < cnt; base += 32) {
      int ix = base + grp;
      if (ix < cnt) {
        int m = st + ix, pam = (m - 1) >> 2;
        float acc = mvreg(D, &sp[pam * 32]);
        sp[m * 32 + lane] = acc;
        float bv = acc * slb[m * 32 + lane];
        if (d == 3) bv /= hsum32(bv);  // leaves normalized
        sb[m * 32 + lane] = bv;
      }
    }
    __syncthreads();
  }
  // ---- up (class-split): children phase + combine phase per level ----
  float U[32];
#pragma unroll
  for (int i = 0; i < 32; i++) U[i] = sA[(grp & 3) * 1024 + i * 32 + lane];
  for (int d = 2; d >= 0; d--) {
    int pst = LOFF[d], pcnt = LOFF[d + 1] - pst;
    for (int base = 0; base < pcnt; base += 8) {
      int pidx = base + slot;
      if (pidx < pcnt) {
        int pn = pst + pidx;
        int mch = 4 * pn + 1 + ecl;   // child of class ecl
        stb[mch * 32 + lane] = mvreg(U, &sb[mch * 32]) / sp[pn * 32 + lane];
      }
    }
    __syncthreads();
    if (grp < pcnt) {
      int pn = pst + grp;
      float prod = stb[(4 * pn + 1) * 32 + lane] * stb[(4 * pn + 2) * 32 + lane]
                 * stb[(4 * pn + 3) * 32 + lane] * stb[(4 * pn + 4) * 32 + lane];
      float bn = sb[pn * 32 + lane] * prod;
      bn /= hsum32(bn);
      sb[pn * 32 + lane] = bn;
    }
    __syncthreads();
  }
  // ---- local-root t_beta + TB4 export ----
  if (ecl == pe3 && slot == 0) {
    float acc = mvreg(U, &sb[0]);   // U's class == pe3 for this group
    float tb = acc / sp3v[lane];
    stb[lane] = tb;
    W[W_TB4 + bid * 32 + lane] = tb;
  }
  __syncthreads();
  // ---- coalesced stash: t_beta + ratio for all 85 local rows ----
  if (tid < 680) {
    int m = tid >> 3, q = tid & 7, g = gmap(r, m);
    *(float4*)&W[W_TBETA + g * 32 + q * 4] = *(float4*)&stb[m * 32 + q * 4];
    float4 bb = *(float4*)&sb[m * 32 + q * 4], pp = *(float4*)&sp[m * 32 + q * 4];
    float4 rr;
    rr.x = bb.x / pp.x; rr.y = bb.y / pp.y; rr.z = bb.z / pp.z; rr.w = bb.w / pp.w;
    *(float4*)&W[W_RATIO + g * 32 + q * 4] = rr;
  }
}

// ---------------- K2: redundant top tree + eps (levels 1-7) + lh ------------
__global__ __launch_bounds__(1024, 4) void k_eps3(const float* __restrict__ A,
                                                  const float* __restrict__ Bm,
                                                  const float* __restrict__ Pi,
                                                  const int* __restrict__ labels,
                                                  float* __restrict__ W,
                                                  float* __restrict__ out) {
  __shared__ __align__(16) float sAT[4096], sA[4096], sLT[4096];  // sLT = sm*log
  __shared__ __align__(16) float R[8192];    // TB4
  __shared__ __align__(16) float U[13600];
  __shared__ __align__(16) float sq[1024];
  __shared__ __align__(16) float sqr[32];
  __shared__ float sPE[32];
  __shared__ float smx[128], sinv[128], sls[128];
  __shared__ float sBmx[32], sBinv[32], sBls[32];
  __shared__ float sred[16];
  float* msp   = U;            float* msb  = U + 2720;
  float* mstb  = U + 5440;     float* mslb = U + 8160;
  float* mseps = U + 10880;
  float* stb = U;              float* srt  = U + 2720;   // subtree-phase aliases
  float* seps = U + 5440;      float* slbL = U + 8160;
  float* S = U;                // staging, dead after build

  const int tid = threadIdx.x, bid = blockIdx.x;
  const int grp = tid >> 5, lane = tid & 31;
  const int ecl = grp & 3, slot = grp >> 2;
  const int r = 85 + bid;
  const int LOFF[5] = {0, 1, 5, 21, 85};

  // ---- early global issues ----
  float4 stT, stR;
  const int sm_ = tid >> 3, sq_ = tid & 7;
  if (tid < 680) {
    int g = gmap(r, sm_);
    stT = *(const float4*)&W[W_TBETA + g * 32 + sq_ * 4];
    stR = *(const float4*)&W[W_RATIO + g * 32 + sq_ * 4];
  }
  { ((float4*)R)[tid]        = ((const float4*)(W + W_TB4))[tid];
    ((float4*)R)[tid + 1024] = ((const float4*)(W + W_TB4))[tid + 1024]; }

  // ---- B row stats ----
  {
    float xs[8], mx = -1e30f;
#pragma unroll
    for (int k = 0; k < 8; k++) { xs[k] = Bm[grp * 256 + k * 32 + lane]; mx = fmaxf(mx, xs[k]); }
    mx = hmax32(mx);
    float s = 0.f;
#pragma unroll
    for (int k = 0; k < 8; k++) s += expf(xs[k] - mx);
    s = hsum32(s);
    if (lane == 0) { sBmx[grp] = mx; sBinv[grp] = 1.f / s; sBls[grp] = logf(s); }
  }
  // ---- stage raw A ----
  {
    float4 raw = ((const float4*)A)[tid];
    int i = tid >> 5, j = tid & 31;
    S[(j * 4 + 0) * 33 + i] = raw.x;
    S[(j * 4 + 1) * 33 + i] = raw.y;
    S[(j * 4 + 2) * 33 + i] = raw.z;
    S[(j * 4 + 3) * 33 + i] = raw.w;
  }
  __syncthreads();
  if (tid < 128) {
    int c = tid;
    float mx = -1e30f;
    for (int i = 0; i < 32; i++) mx = fmaxf(mx, S[c * 33 + i]);
    float s = 0.f;
    for (int i = 0; i < 32; i++) s += expf(S[c * 33 + i] - mx);
    smx[c] = mx; sinv[c] = 1.f / s; sls[c] = logf(s);
  }
  __syncthreads();
  {  // emit sAT + sLT (c-column)
    int v = 4 * tid, e = v >> 10, j = (v >> 5) & 31, i0 = v & 31, c = j * 4 + e;
    float mx = smx[c], iv = sinv[c], ls = sls[c];
    float x0 = S[c * 33 + i0 + 0], x1 = S[c * 33 + i0 + 1];
    float x2 = S[c * 33 + i0 + 2], x3 = S[c * 33 + i0 + 3];
    float s0 = expf(x0 - mx) * iv, s1 = expf(x1 - mx) * iv;
    float s2 = expf(x2 - mx) * iv, s3 = expf(x3 - mx) * iv;
    float4 o; o.x = s0; o.y = s1; o.z = s2; o.w = s3;
    ((float4*)sAT)[tid] = o;
    float4 ol;
    ol.x = s0 * ((x0 - mx) - ls); ol.y = s1 * ((x1 - mx) - ls);
    ol.z = s2 * ((x2 - mx) - ls); ol.w = s3 * ((x3 - mx) - ls);
    ((float4*)sLT)[tid] = ol;
  }
  {  // emit sA [e][i][j]
    int v = 4 * tid, e = v >> 10, i = (v >> 5) & 31, j0 = v & 31;
    float4 o;
    { int c = (j0 + 0) * 4 + e; o.x = expf(S[c * 33 + i] - smx[c]) * sinv[c]; }
    { int c = (j0 + 1) * 4 + e; o.y = expf(S[c * 33 + i] - smx[c]) * sinv[c]; }
    { int c = (j0 + 2) * 4 + e; o.z = expf(S[c * 33 + i] - smx[c]) * sinv[c]; }
    { int c = (j0 + 3) * 4 + e; o.w = expf(S[c * 33 + i] - smx[c]) * sinv[c]; }
    ((float4*)sA)[tid] = o;
  }
  __syncthreads();  // S dead; U usable

  // ---- label gathers: static 3-slot ----
  const int m0 = grp, m1 = grp + 32, m2 = grp + 64;
  const bool h2 = (m2 < 85);
  float topS0, topS1, topS2 = 0.f;
  float topL0, topL1, topL2 = 0.f;
  float subL0, subL1, subL2 = 0.f;
  {
    float bmx = sBmx[lane], binv = sBinv[lane], bls = sBls[lane];
    float xt0 = Bm[lane * 256 + labels[m0]];
    float xs0 = Bm[lane * 256 + labels[gmap(r, m0)]];
    float xt1 = Bm[lane * 256 + labels[m1]];
    float xs1 = Bm[lane * 256 + labels[gmap(r, m1)]];
    topS0 = expf(xt0 - bmx) * binv; topL0 = (xt0 - bmx) - bls; subL0 = (xs0 - bmx) - bls;
    topS1 = expf(xt1 - bmx) * binv; topL1 = (xt1 - bmx) - bls; subL1 = (xs1 - bmx) - bls;
    if (h2) {
      float xt2 = Bm[lane * 256 + labels[m2]];
      float xs2 = Bm[lane * 256 + labels[gmap(r, m2)]];
      topS2 = expf(xt2 - bmx) * binv; topL2 = (xt2 - bmx) - bls; subL2 = (xs2 - bmx) - bls;
    }
  }
  mslb[m0 * 32 + lane] = topS0;
  mslb[m1 * 32 + lane] = topS1;
  if (h2) mslb[m2 * 32 + lane] = topS2;
  float pPi, lPi;
  {
    float x = Pi[lane];
    float mx = hmax32(x);
    float ex = expf(x - mx);
    float s = hsum32(ex);
    pPi = ex / s;
    lPi = (x - mx) - logf(s);
  }
  if (grp == 0) msp[lane] = pPi;
  // ---- reg tables ----
  float D[32], L[32];
#pragma unroll
  for (int j = 0; j < 32; j++) D[j] = sAT[(grp & 3) * 1024 + j * 32 + lane];
#pragma unroll
  for (int j = 0; j < 32; j++) L[j] = sLT[(grp & 3) * 1024 + j * 32 + lane];
  __syncthreads();
  if (grp == 0) msb[lane] = msp[lane] * mslb[lane];
  __syncthreads();

  // ---- top-down levels 1..3 (e == grp&3) ----
  for (int l = 1; l <= 3; l++) {
    int st = LOFF[l], cnt = LOFF[l + 1] - st;
    for (int base = 0; base < cnt; base += 32) {
      int ix = base + grp;
      if (ix < cnt) {
        int n = st + ix, pa = (n - 1) >> 2;
        float acc = mvreg(D, &msp[pa * 32]);
        msp[n * 32 + lane] = acc;
        msb[n * 32 + lane] = acc * mslb[n * 32 + lane];
      }
    }
    __syncthreads();
  }
  // ---- top-up: level-3 parents from TB4, then 2,1,0 (LDS sA, small) ----
  {
    for (int base = 0; base < 64; base += 32) {
      int ix = base + grp;
      if (ix < 64) {
        int pn = 21 + ix;
        float prod = 1.f;
#pragma unroll
        for (int c = 0; c < 4; c++) prod *= R[(4 * pn + 1 + c - 85) * 32 + lane];
        float bn = msb[pn * 32 + lane] * prod;
        bn /= hsum32(bn);
        msb[pn * 32 + lane] = bn;
      }
    }
    __syncthreads();
    const int PST[3] = {5, 1, 0}, PCNT[3] = {16, 4, 1};
    for (int s = 0; s < 3; s++) {
      int st = PST[s], cnt = PCNT[s];
      if (grp < cnt) {
        int pn = st + grp;
        float ppj = msp[pn * 32 + lane];
        float ac[4] = {0.f, 0.f, 0.f, 0.f};
#pragma unroll
        for (int j4 = 0; j4 < 8; j4++) {
#pragma unroll
          for (int c = 0; c < 4; c++) {
            float4 v = ((const float4*)&msb[(4 * pn + 1 + c) * 32])[j4];
            const float* t = &sA[c * 1024 + j4 * 128 + lane];
            ac[c] += t[0] * v.x + t[32] * v.y + t[64] * v.z + t[96] * v.w;
          }
        }
        float prod = 1.f;
#pragma unroll
        for (int c = 0; c < 4; c++) {
          float buv = ac[c] / ppj;
          mstb[(4 * pn + 1 + c) * 32 + lane] = buv;
          prod *= buv;
        }
        float bn = msb[pn * 32 + lane] * prod;
        bn /= hsum32(bn);
        msb[pn * 32 + lane] = bn;
      }
      __syncthreads();
    }
  }
  // ---- mslb -> log rows; ancestor eps chain via class groups ----
  mslb[m0 * 32 + lane] = topL0;
  mslb[m1 * 32 + lane] = topL1;
  if (h2) mslb[m2 * 32 + lane] = topL2;
  if (tid < 32) sPE[tid] = msb[tid];  // eps[root] = final root beta
  __syncthreads();
  const int a3n = (r - 1) >> 2, a2n = (a3n - 1) >> 2, a1n = (a2n - 1) >> 2;
  {
    int n = a1n;
    if (ecl == ((n - 1) & 3) && slot == 0) {
      float qv = sPE[lane] / mstb[n * 32 + lane];
      sqr[lane] = qv;
      float num = mvreg(D, sqr) * (msb[n * 32 + lane] / msp[n * 32 + lane]);
      float den = hsum32(num);
      sPE[lane] = num / den;
    }
    __syncthreads();
  }
  {
    int n = a2n;
    if (ecl == ((n - 1) & 3) && slot == 0) {
      float qv = sPE[lane] / mstb[n * 32 + lane];
      sqr[lane] = qv;
      float num = mvreg(D, sqr) * (msb[n * 32 + lane] / msp[n * 32 + lane]);
      float den = hsum32(num);
      sPE[lane] = num / den;
    }
    __syncthreads();
  }
  {
    int n = a3n;
    if (ecl == ((n - 1) & 3) && slot == 0) {
      float qv = sPE[lane] / mstb[n * 32 + lane];
      sqr[lane] = qv;
      float num = mvreg(D, sqr) * (msb[n * 32 + lane] / msp[n * 32 + lane]);
      float den = hsum32(num);
      sPE[lane] = num / den;
    }
    __syncthreads();
  }

  float lh = 0.f;
  if (bid == 0) {  // full top-eps + top lh (levels 0..3); e == grp&3 at EST
    if (grp == 0) {
      float v = msb[lane];
      mseps[lane] = v;
      lh += v * (lPi + mslb[lane]);  // Pi_lh + root B_lh
    }
    __syncthreads();
    const int EST[3] = {1, 5, 21}, ECNT[3] = {4, 16, 64};
    for (int s = 0; s < 3; s++) {
      int st = EST[s], cnt = ECNT[s];
      for (int base = 0; base < cnt; base += 32) {
        int ix = base + grp;
        if (ix < cnt) {
          int n = st + ix, pa = (n - 1) >> 2;
          float ratio = msb[n * 32 + lane] / msp[n * 32 + lane];
          float qv = mseps[pa * 32 + lane] / mstb[n * 32 + lane];
          sq[grp * 32 + lane] = qv;
          float an, aa;
          mvreg2(D, L, &sq[grp * 32], an, aa);
          float num = ratio * an;
          float den = hsum32(num);
          float epsi = num / den;
          mseps[n * 32 + lane] = epsi;
          lh += ratio * aa + epsi * mslb[n * 32 + lane];
        }
      }
      __syncthreads();
    }
  }
  __syncthreads();  // top arrays dead (except sPE); repurpose U

  // ---- subtree phase: stash + log-B rows ----
  if (tid < 680) {
    *(float4*)&stb[sm_ * 32 + sq_ * 4] = stT;
    *(float4*)&srt[sm_ * 32 + sq_ * 4] = stR;
  }
  slbL[m0 * 32 + lane] = subL0;
  slbL[m1 * 32 + lane] = subL1;
  if (h2) slbL[m2 * 32 + lane] = subL2;
  __syncthreads();

  // eps at level-4 root r (class-matching group)
  {
    if (ecl == ((r - 1) & 3) && slot == 0) {
      float ratio = srt[lane];
      float qv = sPE[lane] / stb[lane];
      sqr[lane] = qv;
      float an, aa;
      mvreg2(D, L, sqr, an, aa);
      float num = ratio * an;
      float den = hsum32(num);
      float epsi = num / den;
      seps[lane] = epsi;
      lh += ratio * aa + epsi * slbL[lane];
    }
    __syncthreads();
  }
  // subtree eps levels 1..3 (global 5..7); e == grp&3
  for (int d = 1; d <= 3; d++) {
    int st = LOFF[d], cnt = LOFF[d + 1] - st;
    for (int base = 0; base < cnt; base += 32) {
      int ix = base + grp;
      if (ix < cnt) {
        int m = st + ix, pa = (m - 1) >> 2;
        float ratio = srt[m * 32 + lane];
        float qv = seps[pa * 32 + lane] / stb[m * 32 + lane];
        sq[grp * 32 + lane] = qv;
        float an, aa;
        mvreg2(D, L, &sq[grp * 32], an, aa);
        float num = ratio * an;
        float den = hsum32(num);
        float epsi = num / den;
        seps[m * 32 + lane] = epsi;
        lh += ratio * aa + epsi * slbL[m * 32 + lane];
      }
    }
    __syncthreads();
  }

  // ---- block partial -> atomicAdd ----
#pragma unroll
  for (int mm = 32; mm >= 1; mm >>= 1) lh += __shfl_xor(lh, mm, 64);
  if ((tid & 63) == 0) sred[tid >> 6] = lh;
  __syncthreads();
  if (tid == 0) {
    float t = 0.f;
#pragma unroll
    for (int w = 0; w < 16; w++) t += sred[w];
    atomicAdd(out, t);
  }
}

extern "C" void kernel_launch(void* const* d_in, const int* in_sizes, int n_in,
                              void* d_out, int out_size, void* d_ws, size_t ws_size,
                              hipStream_t stream) {
  const float* A  = (const float*)d_in[0];
  const float* Bm = (const float*)d_in[1];
  const float* Pi = (const float*)d_in[2];
  const int* labels = (const int*)d_in[5];
  float* W = (float*)d_ws;
  float* out = (float*)d_out;

  k_sub2<<<256, 1024, 0, stream>>>(A, Bm, Pi, labels, W, out);
  k_eps3<<<256, 1024, 0, stream>>>(A, Bm, Pi, labels, W, out);
}

// Round 13
// 51.507 us; speedup vs baseline: 6.3712x; 1.0678x over previous
//
#include <hip/hip_runtime.h>
#include <math.h>

// TopDownHTMM: C=32, 4-ary tree depth 7, N=21845, M=256. Output: scalar fp32.
// FOUR kernels (diagnostic de-entanglement of the 40us k_eps3 plateau):
//   k_sub2 (256x1024): [round-12 verified] in-block tables, path prior,
//                      down 5-7, up 7-5; exports TB4 + t_beta/ratio stash.
//   k_mid  (1x1024):   tables, top-down 0-3, top-up from TB4, FULL top-eps
//                      levels 0-3 + top lh; exports EPSM rows 0..84 +
//                      W_PART[256].
//   k_eps  (256x1024): tables (sAT/sLT only), stash->LDS, eps[a3(r)] read
//                      DIRECTLY from EPSM (no redundant top-tree, no
//                      ancestor chain), subtree eps 4-7 + lh -> W_PART[bid].
//   k_final(1x256):    sum 257 partials -> out[0].  NO float atomics.
//
// Subtree r in [85,341): local m in [0,85), depth d, global g = 4^d*r + m;
// parent=(m-1)>>2, pos=(m-1)&3 hold locally. Class invariant: for level
// starts {1,5,21,85} and base stepping by 32, e=(m-1)&3 == grp&3.

#define NF (21845 * 32)

enum : int {
  W_TBETA = 0,              // [N][32] rows 85..21844
  W_RATIO = NF,             // [N][32] (beta_final/prior)
  W_TB4   = 2 * NF,         // [256][32] level-4 t_beta (index r-85)
  W_EPSM  = 2 * NF + 8192,  // [85][32] top eps rows
  W_PART  = W_EPSM + 2720,  // 257 lh partials
};

__device__ inline float hsum32(float v) {
#pragma unroll
  for (int m = 16; m >= 1; m >>= 1) v += __shfl_xor(v, m, 32);
  return v;
}
__device__ inline float hmax32(float v) {
#pragma unroll
  for (int m = 16; m >= 1; m >>= 1) v = fmaxf(v, __shfl_xor(v, m, 32));
  return v;
}
__device__ inline int gmap(int r, int m) {
  return (m == 0) ? r : (m < 5 ? 4 * r + m : (m < 21 ? 16 * r + m : 64 * r + m));
}

// reg-table matvec: out[lane] = sum_j T[j] * vec[j]; vec via b128 broadcast.
__device__ inline float mvreg(const float (&T)[32], const float* __restrict__ vec) {
  const float4* v4 = (const float4*)vec;
  float a0 = 0.f, a1 = 0.f, a2 = 0.f, a3 = 0.f;
#pragma unroll
  for (int j4 = 0; j4 < 8; j4++) {
    float4 v = v4[j4];
    a0 += T[4 * j4 + 0] * v.x; a1 += T[4 * j4 + 1] * v.y;
    a2 += T[4 * j4 + 2] * v.z; a3 += T[4 * j4 + 3] * v.w;
  }
  return (a0 + a1) + (a2 + a3);
}
__device__ inline void mvreg2(const float (&Tn)[32], const float (&Tl)[32],
                              const float* __restrict__ vec, float& an, float& aa) {
  const float4* v4 = (const float4*)vec;
  float n0 = 0.f, n1 = 0.f, n2 = 0.f, n3 = 0.f;
  float l0 = 0.f, l1 = 0.f, l2 = 0.f, l3 = 0.f;
#pragma unroll
  for (int j4 = 0; j4 < 8; j4++) {
    float4 v = v4[j4];
    n0 += Tn[4 * j4 + 0] * v.x; n1 += Tn[4 * j4 + 1] * v.y;
    n2 += Tn[4 * j4 + 2] * v.z; n3 += Tn[4 * j4 + 3] * v.w;
    l0 += Tl[4 * j4 + 0] * v.x; l1 += Tl[4 * j4 + 1] * v.y;
    l2 += Tl[4 * j4 + 2] * v.z; l3 += Tl[4 * j4 + 3] * v.w;
  }
  an = (n0 + n1) + (n2 + n3);
  aa = (l0 + l1) + (l2 + l3);
}

// ---------------- K1: per-subtree down 5-7 + up 7-5 (round-12 verified) -----
__global__ __launch_bounds__(1024, 4) void k_sub2(const float* __restrict__ A,
                                                  const float* __restrict__ Bm,
                                                  const float* __restrict__ Pi,
                                                  const int* __restrict__ labels,
                                                  float* __restrict__ W) {
  __shared__ __align__(16) float sAT[4096], sA[4096];
  __shared__ __align__(16) float SH[10880];
  __shared__ float smx[128], sinv[128];
  __shared__ float sBmx[32], sBinv[32];
  __shared__ __align__(16) float spath[32];
  __shared__ float sp3v[32];
  float* sp  = SH;          float* sb  = SH + 2720;
  float* stb = SH + 5440;   float* slb = SH + 8160;
  float* S   = SH;          // staging 4224 floats, dead after build

  const int tid = threadIdx.x, bid = blockIdx.x;
  const int grp = tid >> 5, lane = tid & 31;
  const int ecl = grp & 3, slot = grp >> 2;
  const int r = 85 + bid;

  {  // B row stats
    float xs[8], mx = -1e30f;
#pragma unroll
    for (int k = 0; k < 8; k++) { xs[k] = Bm[grp * 256 + k * 32 + lane]; mx = fmaxf(mx, xs[k]); }
    mx = hmax32(mx);
    float s = 0.f;
#pragma unroll
    for (int k = 0; k < 8; k++) s += expf(xs[k] - mx);
    s = hsum32(s);
    if (lane == 0) { sBmx[grp] = mx; sBinv[grp] = 1.f / s; }
  }
  {  // stage raw A -> padded S
    float4 raw = ((const float4*)A)[tid];
    int i = tid >> 5, j = tid & 31;
    S[(j * 4 + 0) * 33 + i] = raw.x;
    S[(j * 4 + 1) * 33 + i] = raw.y;
    S[(j * 4 + 2) * 33 + i] = raw.z;
    S[(j * 4 + 3) * 33 + i] = raw.w;
  }
  __syncthreads();
  if (tid < 128) {
    int c = tid;
    float mx = -1e30f;
    for (int i = 0; i < 32; i++) mx = fmaxf(mx, S[c * 33 + i]);
    float s = 0.f;
    for (int i = 0; i < 32; i++) s += expf(S[c * 33 + i] - mx);
    smx[c] = mx; sinv[c] = 1.f / s;
  }
  __syncthreads();
  {  // emit sAT [e][j][i]
    int v = 4 * tid, e = v >> 10, j = (v >> 5) & 31, i0 = v & 31, c = j * 4 + e;
    float mx = smx[c], iv = sinv[c];
    float4 o;
    o.x = expf(S[c * 33 + i0 + 0] - mx) * iv;
    o.y = expf(S[c * 33 + i0 + 1] - mx) * iv;
    o.z = expf(S[c * 33 + i0 + 2] - mx) * iv;
    o.w = expf(S[c * 33 + i0 + 3] - mx) * iv;
    ((float4*)sAT)[tid] = o;
  }
  {  // emit sA [e][i][j]
    int v = 4 * tid, e = v >> 10, i = (v >> 5) & 31, j0 = v & 31;
    float4 o;
    { int c = (j0 + 0) * 4 + e; o.x = expf(S[c * 33 + i] - smx[c]) * sinv[c]; }
    { int c = (j0 + 1) * 4 + e; o.y = expf(S[c * 33 + i] - smx[c]) * sinv[c]; }
    { int c = (j0 + 2) * 4 + e; o.z = expf(S[c * 33 + i] - smx[c]) * sinv[c]; }
    { int c = (j0 + 3) * 4 + e; o.w = expf(S[c * 33 + i] - smx[c]) * sinv[c]; }
    ((float4*)sA)[tid] = o;
  }
  __syncthreads();  // S dead

  {  // smB label rows (static 3-slot)
    const int m0 = grp, m1 = grp + 32, m2 = grp + 64;
    float bmx = sBmx[lane], binv = sBinv[lane];
    float x0 = Bm[lane * 256 + labels[gmap(r, m0)]];
    float x1 = Bm[lane * 256 + labels[gmap(r, m1)]];
    slb[m0 * 32 + lane] = expf(x0 - bmx) * binv;
    slb[m1 * 32 + lane] = expf(x1 - bmx) * binv;
    if (m2 < 85) {
      float x2 = Bm[lane * 256 + labels[gmap(r, m2)]];
      slb[m2 * 32 + lane] = expf(x2 - bmx) * binv;
    }
  }
  {  // smPi -> spath
    float x = Pi[lane];
    float mx = hmax32(x);
    float ex = expf(x - mx);
    float pPi = ex / hsum32(ex);
    if (tid < 32) spath[tid] = pPi;
  }
  float D[32];
#pragma unroll
  for (int j = 0; j < 32; j++) D[j] = sAT[(grp & 3) * 1024 + j * 32 + lane];
  __syncthreads();

  const int a3n = (r - 1) >> 2, a2n = (a3n - 1) >> 2, a1n = (a2n - 1) >> 2;
  const int pe0 = (a1n - 1) & 3, pe1 = (a2n - 1) & 3, pe2 = (a3n - 1) & 3, pe3 = (r - 1) & 3;
  if (ecl == pe0 && slot == 0) spath[lane] = mvreg(D, spath);
  __syncthreads();
  if (ecl == pe1 && slot == 0) spath[lane] = mvreg(D, spath);
  __syncthreads();
  if (ecl == pe2 && slot == 0) { float a = mvreg(D, spath); spath[lane] = a; sp3v[lane] = a; }
  __syncthreads();
  if (ecl == pe3 && slot == 0) spath[lane] = mvreg(D, spath);
  __syncthreads();
  if (tid < 32) { sp[tid] = spath[tid]; sb[tid] = spath[tid] * slb[tid]; }
  __syncthreads();

  const int LOFF[5] = {0, 1, 5, 21, 85};
  for (int d = 1; d <= 3; d++) {
    int st = LOFF[d], cnt = LOFF[d + 1] - st;
    for (int base = 0; base < cnt; base += 32) {
      int ix = base + grp;
      if (ix < cnt) {
        int m = st + ix, pam = (m - 1) >> 2;
        float acc = mvreg(D, &sp[pam * 32]);
        sp[m * 32 + lane] = acc;
        float bv = acc * slb[m * 32 + lane];
        if (d == 3) bv /= hsum32(bv);
        sb[m * 32 + lane] = bv;
      }
    }
    __syncthreads();
  }
  float U[32];
#pragma unroll
  for (int i = 0; i < 32; i++) U[i] = sA[(grp & 3) * 1024 + i * 32 + lane];
  for (int d = 2; d >= 0; d--) {
    int pst = LOFF[d], pcnt = LOFF[d + 1] - pst;
    for (int base = 0; base < pcnt; base += 8) {
      int pidx = base + slot;
      if (pidx < pcnt) {
        int pn = pst + pidx;
        int mch = 4 * pn + 1 + ecl;
        stb[mch * 32 + lane] = mvreg(U, &sb[mch * 32]) / sp[pn * 32 + lane];
      }
    }
    __syncthreads();
    if (grp < pcnt) {
      int pn = pst + grp;
      float prod = stb[(4 * pn + 1) * 32 + lane] * stb[(4 * pn + 2) * 32 + lane]
                 * stb[(4 * pn + 3) * 32 + lane] * stb[(4 * pn + 4) * 32 + lane];
      float bn = sb[pn * 32 + lane] * prod;
      bn /= hsum32(bn);
      sb[pn * 32 + lane] = bn;
    }
    __syncthreads();
  }
  if (ecl == pe3 && slot == 0) {
    float acc = mvreg(U, &sb[0]);
    float tb = acc / sp3v[lane];
    stb[lane] = tb;
    W[W_TB4 + bid * 32 + lane] = tb;
  }
  __syncthreads();
  if (tid < 680) {
    int m = tid >> 3, q = tid & 7, g = gmap(r, m);
    *(float4*)&W[W_TBETA + g * 32 + q * 4] = *(float4*)&stb[m * 32 + q * 4];
    float4 bb = *(float4*)&sb[m * 32 + q * 4], pp = *(float4*)&sp[m * 32 + q * 4];
    float4 rr;
    rr.x = bb.x / pp.x; rr.y = bb.y / pp.y; rr.z = bb.z / pp.z; rr.w = bb.w / pp.w;
    *(float4*)&W[W_RATIO + g * 32 + q * 4] = rr;
  }
}

// ---------------- K2: top tree + full top-eps + top lh (1 block) ------------
__global__ __launch_bounds__(1024, 4) void k_mid(const float* __restrict__ A,
                                                 const float* __restrict__ Bm,
                                                 const float* __restrict__ Pi,
                                                 const int* __restrict__ labels,
                                                 float* __restrict__ W) {
  __shared__ __align__(16) float sAT[4096], sA[4096], sLT[4096];
  __shared__ __align__(16) float R[8192];    // TB4
  __shared__ __align__(16) float U[13600];
  __shared__ __align__(16) float sq[1024];
  __shared__ float smx[128], sinv[128], sls[128];
  __shared__ float sBmx[32], sBinv[32], sBls[32];
  __shared__ float sred[16];
  float* msp   = U;            float* msb  = U + 2720;
  float* mstb  = U + 5440;     float* mslb = U + 8160;
  float* mseps = U + 10880;
  float* S = U;                // staging, dead after build

  const int tid = threadIdx.x;
  const int grp = tid >> 5, lane = tid & 31;
  const int LOFF[5] = {0, 1, 5, 21, 85};

  { ((float4*)R)[tid]        = ((const float4*)(W + W_TB4))[tid];
    ((float4*)R)[tid + 1024] = ((const float4*)(W + W_TB4))[tid + 1024]; }
  {  // B row stats
    float xs[8], mx = -1e30f;
#pragma unroll
    for (int k = 0; k < 8; k++) { xs[k] = Bm[grp * 256 + k * 32 + lane]; mx = fmaxf(mx, xs[k]); }
    mx = hmax32(mx);
    float s = 0.f;
#pragma unroll
    for (int k = 0; k < 8; k++) s += expf(xs[k] - mx);
    s = hsum32(s);
    if (lane == 0) { sBmx[grp] = mx; sBinv[grp] = 1.f / s; sBls[grp] = logf(s); }
  }
  {  // stage raw A
    float4 raw = ((const float4*)A)[tid];
    int i = tid >> 5, j = tid & 31;
    S[(j * 4 + 0) * 33 + i] = raw.x;
    S[(j * 4 + 1) * 33 + i] = raw.y;
    S[(j * 4 + 2) * 33 + i] = raw.z;
    S[(j * 4 + 3) * 33 + i] = raw.w;
  }
  __syncthreads();
  if (tid < 128) {
    int c = tid;
    float mx = -1e30f;
    for (int i = 0; i < 32; i++) mx = fmaxf(mx, S[c * 33 + i]);
    float s = 0.f;
    for (int i = 0; i < 32; i++) s += expf(S[c * 33 + i] - mx);
    smx[c] = mx; sinv[c] = 1.f / s; sls[c] = logf(s);
  }
  __syncthreads();
  {  // emit sAT + sLT
    int v = 4 * tid, e = v >> 10, j = (v >> 5) & 31, i0 = v & 31, c = j * 4 + e;
    float mx = smx[c], iv = sinv[c], ls = sls[c];
    float x0 = S[c * 33 + i0 + 0], x1 = S[c * 33 + i0 + 1];
    float x2 = S[c * 33 + i0 + 2], x3 = S[c * 33 + i0 + 3];
    float s0 = expf(x0 - mx) * iv, s1 = expf(x1 - mx) * iv;
    float s2 = expf(x2 - mx) * iv, s3 = expf(x3 - mx) * iv;
    float4 o; o.x = s0; o.y = s1; o.z = s2; o.w = s3;
    ((float4*)sAT)[tid] = o;
    float4 ol;
    ol.x = s0 * ((x0 - mx) - ls); ol.y = s1 * ((x1 - mx) - ls);
    ol.z = s2 * ((x2 - mx) - ls); ol.w = s3 * ((x3 - mx) - ls);
    ((float4*)sLT)[tid] = ol;
  }
  {  // emit sA [e][i][j]
    int v = 4 * tid, e = v >> 10, i = (v >> 5) & 31, j0 = v & 31;
    float4 o;
    { int c = (j0 + 0) * 4 + e; o.x = expf(S[c * 33 + i] - smx[c]) * sinv[c]; }
    { int c = (j0 + 1) * 4 + e; o.y = expf(S[c * 33 + i] - smx[c]) * sinv[c]; }
    { int c = (j0 + 2) * 4 + e; o.z = expf(S[c * 33 + i] - smx[c]) * sinv[c]; }
    { int c = (j0 + 3) * 4 + e; o.w = expf(S[c * 33 + i] - smx[c]) * sinv[c]; }
    ((float4*)sA)[tid] = o;
  }
  __syncthreads();  // S dead; U usable

  const int m0 = grp, m1 = grp + 32, m2 = grp + 64;
  const bool h2 = (m2 < 85);
  float topL0, topL1, topL2 = 0.f;
  {
    float bmx = sBmx[lane], binv = sBinv[lane], bls = sBls[lane];
    float xt0 = Bm[lane * 256 + labels[m0]];
    float xt1 = Bm[lane * 256 + labels[m1]];
    mslb[m0 * 32 + lane] = expf(xt0 - bmx) * binv;
    mslb[m1 * 32 + lane] = expf(xt1 - bmx) * binv;
    topL0 = (xt0 - bmx) - bls;
    topL1 = (xt1 - bmx) - bls;
    if (h2) {
      float xt2 = Bm[lane * 256 + labels[m2]];
      mslb[m2 * 32 + lane] = expf(xt2 - bmx) * binv;
      topL2 = (xt2 - bmx) - bls;
    }
  }
  float pPi, lPi;
  {
    float x = Pi[lane];
    float mx = hmax32(x);
    float ex = expf(x - mx);
    float s = hsum32(ex);
    pPi = ex / s;
    lPi = (x - mx) - logf(s);
  }
  if (grp == 0) msp[lane] = pPi;
  float D[32], L[32];
#pragma unroll
  for (int j = 0; j < 32; j++) D[j] = sAT[(grp & 3) * 1024 + j * 32 + lane];
#pragma unroll
  for (int j = 0; j < 32; j++) L[j] = sLT[(grp & 3) * 1024 + j * 32 + lane];
  __syncthreads();
  if (grp == 0) msb[lane] = msp[lane] * mslb[lane];
  __syncthreads();

  // top-down levels 1..3
  for (int l = 1; l <= 3; l++) {
    int st = LOFF[l], cnt = LOFF[l + 1] - st;
    for (int base = 0; base < cnt; base += 32) {
      int ix = base + grp;
      if (ix < cnt) {
        int n = st + ix, pa = (n - 1) >> 2;
        float acc = mvreg(D, &msp[pa * 32]);
        msp[n * 32 + lane] = acc;
        msb[n * 32 + lane] = acc * mslb[n * 32 + lane];
      }
    }
    __syncthreads();
  }
  // top-up: level-3 parents from TB4, then 2,1,0
  {
    for (int base = 0; base < 64; base += 32) {
      int ix = base + grp;
      if (ix < 64) {
        int pn = 21 + ix;
        float prod = 1.f;
#pragma unroll
        for (int c = 0; c < 4; c++) prod *= R[(4 * pn + 1 + c - 85) * 32 + lane];
        float bn = msb[pn * 32 + lane] * prod;
        bn /= hsum32(bn);
        msb[pn * 32 + lane] = bn;
      }
    }
    __syncthreads();
    const int PST[3] = {5, 1, 0}, PCNT[3] = {16, 4, 1};
    for (int s = 0; s < 3; s++) {
      int st = PST[s], cnt = PCNT[s];
      if (grp < cnt) {
        int pn = st + grp;
        float ppj = msp[pn * 32 + lane];
        float ac[4] = {0.f, 0.f, 0.f, 0.f};
#pragma unroll
        for (int j4 = 0; j4 < 8; j4++) {
#pragma unroll
          for (int c = 0; c < 4; c++) {
            float4 v = ((const float4*)&msb[(4 * pn + 1 + c) * 32])[j4];
            const float* t = &sA[c * 1024 + j4 * 128 + lane];
            ac[c] += t[0] * v.x + t[32] * v.y + t[64] * v.z + t[96] * v.w;
          }
        }
        float prod = 1.f;
#pragma unroll
        for (int c = 0; c < 4; c++) {
          float buv = ac[c] / ppj;
          mstb[(4 * pn + 1 + c) * 32 + lane] = buv;
          prod *= buv;
        }
        float bn = msb[pn * 32 + lane] * prod;
        bn /= hsum32(bn);
        msb[pn * 32 + lane] = bn;
      }
      __syncthreads();
    }
  }
  // mslb -> log rows
  mslb[m0 * 32 + lane] = topL0;
  mslb[m1 * 32 + lane] = topL1;
  if (h2) mslb[m2 * 32 + lane] = topL2;
  __syncthreads();

  float lh = 0.f;
  if (grp == 0) {
    float v = msb[lane];
    mseps[lane] = v;
    lh += v * (lPi + mslb[lane]);  // Pi_lh + root B_lh
  }
  __syncthreads();
  const int EST[3] = {1, 5, 21}, ECNT[3] = {4, 16, 64};
  for (int s = 0; s < 3; s++) {
    int st = EST[s], cnt = ECNT[s];
    for (int base = 0; base < cnt; base += 32) {
      int ix = base + grp;
      if (ix < cnt) {
        int n = st + ix, pa = (n - 1) >> 2;
        float ratio = msb[n * 32 + lane] / msp[n * 32 + lane];
        float qv = mseps[pa * 32 + lane] / mstb[n * 32 + lane];
        sq[grp * 32 + lane] = qv;
        float an, aa;
        mvreg2(D, L, &sq[grp * 32], an, aa);
        float num = ratio * an;
        float den = hsum32(num);
        float epsi = num / den;
        mseps[n * 32 + lane] = epsi;
        lh += ratio * aa + epsi * mslb[n * 32 + lane];
      }
    }
    __syncthreads();
  }
  if (tid < 680) {  // export eps rows 0..84
    int m = tid >> 3, q = tid & 7;
    *(float4*)&W[W_EPSM + m * 32 + q * 4] = *(float4*)&mseps[m * 32 + q * 4];
  }
#pragma unroll
  for (int mm = 32; mm >= 1; mm >>= 1) lh += __shfl_xor(lh, mm, 64);
  if ((tid & 63) == 0) sred[tid >> 6] = lh;
  __syncthreads();
  if (tid == 0) {
    float t = 0.f;
#pragma unroll
    for (int w = 0; w < 16; w++) t += sred[w];
    W[W_PART + 256] = t;
  }
}

// ---------------- K3: per-subtree eps 4-7 + lh -> W_PART[bid] ---------------
__global__ __launch_bounds__(1024, 4) void k_eps(const float* __restrict__ A,
                                                 const float* __restrict__ Bm,
                                                 const int* __restrict__ labels,
                                                 float* __restrict__ W) {
  __shared__ __align__(16) float sAT[4096], sLT[4096];
  __shared__ __align__(16) float V[10880];
  __shared__ __align__(16) float sq[1024];
  __shared__ __align__(16) float sqr[32];
  __shared__ float spe[32];
  __shared__ float smx[128], sinv[128], sls[128];
  __shared__ float sBmx[32], sBls[32];
  __shared__ float sred[16];
  float* stb  = V;            float* srt  = V + 2720;
  float* seps = V + 5440;     float* slbL = V + 8160;
  float* S = V;               // staging 4224 floats, dead before stb/srt written

  const int tid = threadIdx.x, bid = blockIdx.x;
  const int grp = tid >> 5, lane = tid & 31;
  const int ecl = grp & 3, slot = grp >> 2;
  const int r = 85 + bid;
  const int LOFF[5] = {0, 1, 5, 21, 85};

  // early stash loads (regs until S dead)
  float4 stT, stR;
  const int sm_ = tid >> 3, sq_ = tid & 7;
  if (tid < 680) {
    int g = gmap(r, sm_);
    stT = *(const float4*)&W[W_TBETA + g * 32 + sq_ * 4];
    stR = *(const float4*)&W[W_RATIO + g * 32 + sq_ * 4];
  }
  {  // B row stats (max + log sum only)
    float xs[8], mx = -1e30f;
#pragma unroll
    for (int k = 0; k < 8; k++) { xs[k] = Bm[grp * 256 + k * 32 + lane]; mx = fmaxf(mx, xs[k]); }
    mx = hmax32(mx);
    float s = 0.f;
#pragma unroll
    for (int k = 0; k < 8; k++) s += expf(xs[k] - mx);
    s = hsum32(s);
    if (lane == 0) { sBmx[grp] = mx; sBls[grp] = logf(s); }
  }
  {  // stage raw A
    float4 raw = ((const float4*)A)[tid];
    int i = tid >> 5, j = tid & 31;
    S[(j * 4 + 0) * 33 + i] = raw.x;
    S[(j * 4 + 1) * 33 + i] = raw.y;
    S[(j * 4 + 2) * 33 + i] = raw.z;
    S[(j * 4 + 3) * 33 + i] = raw.w;
  }
  __syncthreads();
  if (tid < 128) {
    int c = tid;
    float mx = -1e30f;
    for (int i = 0; i < 32; i++) mx = fmaxf(mx, S[c * 33 + i]);
    float s = 0.f;
    for (int i = 0; i < 32; i++) s += expf(S[c * 33 + i] - mx);
    smx[c] = mx; sinv[c] = 1.f / s; sls[c] = logf(s);
  }
  __syncthreads();
  {  // emit sAT + sLT
    int v = 4 * tid, e = v >> 10, j = (v >> 5) & 31, i0 = v & 31, c = j * 4 + e;
    float mx = smx[c], iv = sinv[c], ls = sls[c];
    float x0 = S[c * 33 + i0 + 0], x1 = S[c * 33 + i0 + 1];
    float x2 = S[c * 33 + i0 + 2], x3 = S[c * 33 + i0 + 3];
    float s0 = expf(x0 - mx) * iv, s1 = expf(x1 - mx) * iv;
    float s2 = expf(x2 - mx) * iv, s3 = expf(x3 - mx) * iv;
    float4 o; o.x = s0; o.y = s1; o.z = s2; o.w = s3;
    ((float4*)sAT)[tid] = o;
    float4 ol;
    ol.x = s0 * ((x0 - mx) - ls); ol.y = s1 * ((x1 - mx) - ls);
    ol.z = s2 * ((x2 - mx) - ls); ol.w = s3 * ((x3 - mx) - ls);
    ((float4*)sLT)[tid] = ol;
  }
  __syncthreads();  // S dead

  // stash -> LDS; log-B rows; spe; reg tables
  if (tid < 680) {
    *(float4*)&stb[sm_ * 32 + sq_ * 4] = stT;
    *(float4*)&srt[sm_ * 32 + sq_ * 4] = stR;
  }
  {
    const int m0 = grp, m1 = grp + 32, m2 = grp + 64;
    float bmx = sBmx[lane], bls = sBls[lane];
    float xs0 = Bm[lane * 256 + labels[gmap(r, m0)]];
    float xs1 = Bm[lane * 256 + labels[gmap(r, m1)]];
    slbL[m0 * 32 + lane] = (xs0 - bmx) - bls;
    slbL[m1 * 32 + lane] = (xs1 - bmx) - bls;
    if (m2 < 85) {
      float xs2 = Bm[lane * 256 + labels[gmap(r, m2)]];
      slbL[m2 * 32 + lane] = (xs2 - bmx) - bls;
    }
  }
  if (tid < 32) spe[tid] = W[W_EPSM + ((r - 1) >> 2) * 32 + tid];
  float D[32], L[32];
#pragma unroll
  for (int j = 0; j < 32; j++) D[j] = sAT[(grp & 3) * 1024 + j * 32 + lane];
#pragma unroll
  for (int j = 0; j < 32; j++) L[j] = sLT[(grp & 3) * 1024 + j * 32 + lane];
  __syncthreads();

  float lh = 0.f;
  // eps at level-4 root r (class-matching group)
  if (ecl == ((r - 1) & 3) && slot == 0) {
    float ratio = srt[lane];
    sqr[lane] = spe[lane] / stb[lane];
    float an, aa;
    mvreg2(D, L, sqr, an, aa);
    float num = ratio * an;
    float den = hsum32(num);
    float epsi = num / den;
    seps[lane] = epsi;
    lh += ratio * aa + epsi * slbL[lane];
  }
  __syncthreads();
  // subtree eps levels 1..3 (global 5..7); e == grp&3
  for (int d = 1; d <= 3; d++) {
    int st = LOFF[d], cnt = LOFF[d + 1] - st;
    for (int base = 0; base < cnt; base += 32) {
      int ix = base + grp;
      if (ix < cnt) {
        int m = st + ix, pa = (m - 1) >> 2;
        float ratio = srt[m * 32 + lane];
        sq[grp * 32 + lane] = seps[pa * 32 + lane] / stb[m * 32 + lane];
        float an, aa;
        mvreg2(D, L, &sq[grp * 32], an, aa);
        float num = ratio * an;
        float den = hsum32(num);
        float epsi = num / den;
        seps[m * 32 + lane] = epsi;
        lh += ratio * aa + epsi * slbL[m * 32 + lane];
      }
    }
    __syncthreads();
  }

#pragma unroll
  for (int mm = 32; mm >= 1; mm >>= 1) lh += __shfl_xor(lh, mm, 64);
  if ((tid & 63) == 0) sred[tid >> 6] = lh;
  __syncthreads();
  if (tid == 0) {
    float t = 0.f;
#pragma unroll
    for (int w = 0; w < 16; w++) t += sred[w];
    W[W_PART + bid] = t;
  }
}

// ---------------- K4: final reduce (no atomics) ------------------------------
__global__ void k_final(const float* __restrict__ W, float* __restrict__ out) {
  __shared__ float sh[256];
  int tid = threadIdx.x;
  float a = 0.f;
  for (int k = tid; k < 257; k += 256) a += W[W_PART + k];
  sh[tid] = a; __syncthreads();
  for (int off = 128; off >= 1; off >>= 1) {
    if (tid < off) sh[tid] += sh[tid + off];
    __syncthreads();
  }
  if (tid == 0) out[0] = sh[0];
}

extern "C" void kernel_launch(void* const* d_in, const int* in_sizes, int n_in,
                              void* d_out, int out_size, void* d_ws, size_t ws_size,
                              hipStream_t stream) {
  const float* A  = (const float*)d_in[0];
  const float* Bm = (const float*)d_in[1];
  const float* Pi = (const float*)d_in[2];
  const int* labels = (const int*)d_in[5];
  float* W = (float*)d_ws;
  float* out = (float*)d_out;

  k_sub2<<<256, 1024, 0, stream>>>(A, Bm, Pi, labels, W);
  k_mid<<<1, 1024, 0, stream>>>(A, Bm, Pi, labels, W);
  k_eps<<<256, 1024, 0, stream>>>(A, Bm, labels, W);
  k_final<<<1, 256, 0, stream>>>(W, out);
}

// Round 14
// 43.879 us; speedup vs baseline: 7.4789x; 1.1739x over previous
//
#include <hip/hip_runtime.h>
#include <math.h>

// TopDownHTMM: C=32, 4-ary tree depth 7, N=21845, M=256. Output: scalar fp32.
// FOUR kernels. Round-13 postmortem: the 1-block k_mid was paying table build
// + serial gathers + cold loads on one CU (~15us). Fix: k_sub2 (256 parallel
// blocks) exports tables/stats/top-label-rows; k_mid and k_eps import them
// coalesced and do no table building.
//
//   k_sub2 (256x1024): tables in-block (block 0 exports sAT/sA/sLT, B-stats,
//                      Pi; blocks 0..84 export top label rows), path prior,
//                      down 5-7, up 7-5; exports TB4 + t_beta/ratio stash.
//   k_mid  (1x1024):   pure-import; top-down 0-3, top-up from TB4, full
//                      top-eps + top lh; exports EPSM + W_PART[256].
//   k_eps  (256x1024): import tables/stats; stash->LDS; subtree eps 4-7 + lh.
//   k_final(1x256):    sum 257 partials -> out[0]. No float atomics.
//
// Subtree r in [85,341): local m in [0,85), depth d, global g = 4^d*r + m;
// parent=(m-1)>>2, pos=(m-1)&3 hold locally. Class invariant: for level
// starts {1,5,21,85} and base stepping by 32, e=(m-1)&3 == grp&3.

#define NF (21845 * 32)

enum : int {
  W_TBETA = 0,              // [N][32] rows 85..21844
  W_RATIO = NF,             // [N][32] (beta_final/prior)
  W_TB4   = 2 * NF,         // [256][32] level-4 t_beta (index r-85)
  W_EPSM  = 2 * NF + 8192,  // [85][32] top eps rows
  W_PART  = W_EPSM + 2720,  // 257 lh partials
  W_TABA  = W_PART + 260,   // sAT  [e][j][i] sm            (4096)
  W_TABU  = W_TABA + 4096,  // sA   [e][i][j] sm            (4096)
  W_TABL  = W_TABU + 4096,  // sLT  [e][j][i] sm*log        (4096)
  W_BST   = W_TABL + 4096,  // bmx[32], binv[32], bls[32]   (96)
  W_PIV   = W_BST + 96,     // sPi[32], lPi[32]             (64)
  W_TOPS  = W_PIV + 64,     // top smB label rows [85][32]  (2720)
  W_TOPL  = W_TOPS + 2720,  // top logB label rows [85][32] (2720)
};

__device__ inline float hsum32(float v) {
#pragma unroll
  for (int m = 16; m >= 1; m >>= 1) v += __shfl_xor(v, m, 32);
  return v;
}
__device__ inline float hmax32(float v) {
#pragma unroll
  for (int m = 16; m >= 1; m >>= 1) v = fmaxf(v, __shfl_xor(v, m, 32));
  return v;
}
__device__ inline int gmap(int r, int m) {
  return (m == 0) ? r : (m < 5 ? 4 * r + m : (m < 21 ? 16 * r + m : 64 * r + m));
}

// reg-table matvec: out[lane] = sum_j T[j] * vec[j]; vec via b128 broadcast.
__device__ inline float mvreg(const float (&T)[32], const float* __restrict__ vec) {
  const float4* v4 = (const float4*)vec;
  float a0 = 0.f, a1 = 0.f, a2 = 0.f, a3 = 0.f;
#pragma unroll
  for (int j4 = 0; j4 < 8; j4++) {
    float4 v = v4[j4];
    a0 += T[4 * j4 + 0] * v.x; a1 += T[4 * j4 + 1] * v.y;
    a2 += T[4 * j4 + 2] * v.z; a3 += T[4 * j4 + 3] * v.w;
  }
  return (a0 + a1) + (a2 + a3);
}
__device__ inline void mvreg2(const float (&Tn)[32], const float (&Tl)[32],
                              const float* __restrict__ vec, float& an, float& aa) {
  const float4* v4 = (const float4*)vec;
  float n0 = 0.f, n1 = 0.f, n2 = 0.f, n3 = 0.f;
  float l0 = 0.f, l1 = 0.f, l2 = 0.f, l3 = 0.f;
#pragma unroll
  for (int j4 = 0; j4 < 8; j4++) {
    float4 v = v4[j4];
    n0 += Tn[4 * j4 + 0] * v.x; n1 += Tn[4 * j4 + 1] * v.y;
    n2 += Tn[4 * j4 + 2] * v.z; n3 += Tn[4 * j4 + 3] * v.w;
    l0 += Tl[4 * j4 + 0] * v.x; l1 += Tl[4 * j4 + 1] * v.y;
    l2 += Tl[4 * j4 + 2] * v.z; l3 += Tl[4 * j4 + 3] * v.w;
  }
  an = (n0 + n1) + (n2 + n3);
  aa = (l0 + l1) + (l2 + l3);
}

// ---------------- K1: per-subtree down 5-7 + up 7-5 + exports ---------------
__global__ __launch_bounds__(1024, 4) void k_sub2(const float* __restrict__ A,
                                                  const float* __restrict__ Bm,
                                                  const float* __restrict__ Pi,
                                                  const int* __restrict__ labels,
                                                  float* __restrict__ W) {
  __shared__ __align__(16) float sAT[4096], sA[4096];
  __shared__ __align__(16) float SH[10880];
  __shared__ float smx[128], sinv[128], sls[128];
  __shared__ float sBmx[32], sBinv[32], sBls[32];
  __shared__ __align__(16) float spath[32];
  __shared__ float sp3v[32];
  float* sp  = SH;          float* sb  = SH + 2720;
  float* stb = SH + 5440;   float* slb = SH + 8160;
  float* S   = SH;          // staging 4224 floats, dead after build

  const int tid = threadIdx.x, bid = blockIdx.x;
  const int grp = tid >> 5, lane = tid & 31;
  const int ecl = grp & 3, slot = grp >> 2;
  const int r = 85 + bid;

  {  // B row stats (+ export by block 0)
    float xs[8], mx = -1e30f;
#pragma unroll
    for (int k = 0; k < 8; k++) { xs[k] = Bm[grp * 256 + k * 32 + lane]; mx = fmaxf(mx, xs[k]); }
    mx = hmax32(mx);
    float s = 0.f;
#pragma unroll
    for (int k = 0; k < 8; k++) s += expf(xs[k] - mx);
    s = hsum32(s);
    if (lane == 0) {
      float ls = logf(s);
      sBmx[grp] = mx; sBinv[grp] = 1.f / s; sBls[grp] = ls;
      if (bid == 0) { W[W_BST + grp] = mx; W[W_BST + 32 + grp] = 1.f / s; W[W_BST + 64 + grp] = ls; }
    }
  }
  {  // stage raw A -> padded S
    float4 raw = ((const float4*)A)[tid];
    int i = tid >> 5, j = tid & 31;
    S[(j * 4 + 0) * 33 + i] = raw.x;
    S[(j * 4 + 1) * 33 + i] = raw.y;
    S[(j * 4 + 2) * 33 + i] = raw.z;
    S[(j * 4 + 3) * 33 + i] = raw.w;
  }
  __syncthreads();
  if (tid < 128) {
    int c = tid;
    float mx = -1e30f;
    for (int i = 0; i < 32; i++) mx = fmaxf(mx, S[c * 33 + i]);
    float s = 0.f;
    for (int i = 0; i < 32; i++) s += expf(S[c * 33 + i] - mx);
    smx[c] = mx; sinv[c] = 1.f / s; sls[c] = logf(s);
  }
  __syncthreads();
  {  // emit sAT [e][j][i]; block 0 also exports sAT + sLT (sm*log)
    int v = 4 * tid, e = v >> 10, j = (v >> 5) & 31, i0 = v & 31, c = j * 4 + e;
    float mx = smx[c], iv = sinv[c], ls = sls[c];
    float x0 = S[c * 33 + i0 + 0], x1 = S[c * 33 + i0 + 1];
    float x2 = S[c * 33 + i0 + 2], x3 = S[c * 33 + i0 + 3];
    float s0 = expf(x0 - mx) * iv, s1 = expf(x1 - mx) * iv;
    float s2 = expf(x2 - mx) * iv, s3 = expf(x3 - mx) * iv;
    float4 o; o.x = s0; o.y = s1; o.z = s2; o.w = s3;
    ((float4*)sAT)[tid] = o;
    if (bid == 0) {
      ((float4*)(W + W_TABA))[tid] = o;
      float4 ol;
      ol.x = s0 * ((x0 - mx) - ls); ol.y = s1 * ((x1 - mx) - ls);
      ol.z = s2 * ((x2 - mx) - ls); ol.w = s3 * ((x3 - mx) - ls);
      ((float4*)(W + W_TABL))[tid] = ol;
    }
  }
  {  // emit sA [e][i][j]; block 0 exports
    int v = 4 * tid, e = v >> 10, i = (v >> 5) & 31, j0 = v & 31;
    float4 o;
    { int c = (j0 + 0) * 4 + e; o.x = expf(S[c * 33 + i] - smx[c]) * sinv[c]; }
    { int c = (j0 + 1) * 4 + e; o.y = expf(S[c * 33 + i] - smx[c]) * sinv[c]; }
    { int c = (j0 + 2) * 4 + e; o.z = expf(S[c * 33 + i] - smx[c]) * sinv[c]; }
    { int c = (j0 + 3) * 4 + e; o.w = expf(S[c * 33 + i] - smx[c]) * sinv[c]; }
    ((float4*)sA)[tid] = o;
    if (bid == 0) ((float4*)(W + W_TABU))[tid] = o;
  }
  __syncthreads();  // S dead

  {  // smB label rows (static 3-slot)
    const int m0 = grp, m1 = grp + 32, m2 = grp + 64;
    float bmx = sBmx[lane], binv = sBinv[lane];
    float x0 = Bm[lane * 256 + labels[gmap(r, m0)]];
    float x1 = Bm[lane * 256 + labels[gmap(r, m1)]];
    slb[m0 * 32 + lane] = expf(x0 - bmx) * binv;
    slb[m1 * 32 + lane] = expf(x1 - bmx) * binv;
    if (m2 < 85) {
      float x2 = Bm[lane * 256 + labels[gmap(r, m2)]];
      slb[m2 * 32 + lane] = expf(x2 - bmx) * binv;
    }
  }
  // top label row export: block b (<85) exports top node b's row (sm + log)
  if (bid < 85 && tid < 32) {
    float x = Bm[tid * 256 + labels[bid]];
    W[W_TOPS + bid * 32 + tid] = expf(x - sBmx[tid]) * sBinv[tid];
    W[W_TOPL + bid * 32 + tid] = (x - sBmx[tid]) - sBls[tid];
  }
  {  // smPi -> spath (+ export by block 0)
    float x = Pi[lane];
    float mx = hmax32(x);
    float ex = expf(x - mx);
    float s = hsum32(ex);
    float pPi = ex / s;
    if (tid < 32) {
      spath[tid] = pPi;
      if (bid == 0) { W[W_PIV + tid] = pPi; W[W_PIV + 32 + tid] = (x - mx) - logf(s); }
    }
  }
  float D[32];
#pragma unroll
  for (int j = 0; j < 32; j++) D[j] = sAT[(grp & 3) * 1024 + j * 32 + lane];
  __syncthreads();

  const int a3n = (r - 1) >> 2, a2n = (a3n - 1) >> 2, a1n = (a2n - 1) >> 2;
  const int pe0 = (a1n - 1) & 3, pe1 = (a2n - 1) & 3, pe2 = (a3n - 1) & 3, pe3 = (r - 1) & 3;
  if (ecl == pe0 && slot == 0) spath[lane] = mvreg(D, spath);
  __syncthreads();
  if (ecl == pe1 && slot == 0) spath[lane] = mvreg(D, spath);
  __syncthreads();
  if (ecl == pe2 && slot == 0) { float a = mvreg(D, spath); spath[lane] = a; sp3v[lane] = a; }
  __syncthreads();
  if (ecl == pe3 && slot == 0) spath[lane] = mvreg(D, spath);
  __syncthreads();
  if (tid < 32) { sp[tid] = spath[tid]; sb[tid] = spath[tid] * slb[tid]; }
  __syncthreads();

  const int LOFF[5] = {0, 1, 5, 21, 85};
  for (int d = 1; d <= 3; d++) {
    int st = LOFF[d], cnt = LOFF[d + 1] - st;
    for (int base = 0; base < cnt; base += 32) {
      int ix = base + grp;
      if (ix < cnt) {
        int m = st + ix, pam = (m - 1) >> 2;
        float acc = mvreg(D, &sp[pam * 32]);
        sp[m * 32 + lane] = acc;
        float bv = acc * slb[m * 32 + lane];
        if (d == 3) bv /= hsum32(bv);
        sb[m * 32 + lane] = bv;
      }
    }
    __syncthreads();
  }
  float U[32];
#pragma unroll
  for (int i = 0; i < 32; i++) U[i] = sA[(grp & 3) * 1024 + i * 32 + lane];
  for (int d = 2; d >= 0; d--) {
    int pst = LOFF[d], pcnt = LOFF[d + 1] - pst;
    for (int base = 0; base < pcnt; base += 8) {
      int pidx = base + slot;
      if (pidx < pcnt) {
        int pn = pst + pidx;
        int mch = 4 * pn + 1 + ecl;
        stb[mch * 32 + lane] = mvreg(U, &sb[mch * 32]) / sp[pn * 32 + lane];
      }
    }
    __syncthreads();
    if (grp < pcnt) {
      int pn = pst + grp;
      float prod = stb[(4 * pn + 1) * 32 + lane] * stb[(4 * pn + 2) * 32 + lane]
                 * stb[(4 * pn + 3) * 32 + lane] * stb[(4 * pn + 4) * 32 + lane];
      float bn = sb[pn * 32 + lane] * prod;
      bn /= hsum32(bn);
      sb[pn * 32 + lane] = bn;
    }
    __syncthreads();
  }
  if (ecl == pe3 && slot == 0) {
    float acc = mvreg(U, &sb[0]);
    float tb = acc / sp3v[lane];
    stb[lane] = tb;
    W[W_TB4 + bid * 32 + lane] = tb;
  }
  __syncthreads();
  if (tid < 680) {
    int m = tid >> 3, q = tid & 7, g = gmap(r, m);
    *(float4*)&W[W_TBETA + g * 32 + q * 4] = *(float4*)&stb[m * 32 + q * 4];
    float4 bb = *(float4*)&sb[m * 32 + q * 4], pp = *(float4*)&sp[m * 32 + q * 4];
    float4 rr;
    rr.x = bb.x / pp.x; rr.y = bb.y / pp.y; rr.z = bb.z / pp.z; rr.w = bb.w / pp.w;
    *(float4*)&W[W_RATIO + g * 32 + q * 4] = rr;
  }
}

// ---------------- K2: top tree + full top-eps + top lh (pure import) --------
__global__ __launch_bounds__(1024, 4) void k_mid(float* __restrict__ W) {
  __shared__ __align__(16) float sAT[4096], sA[4096], sLT[4096];
  __shared__ __align__(16) float R[8192];    // TB4
  __shared__ __align__(16) float U[16320];
  __shared__ __align__(16) float sq[1024];
  __shared__ float sred[16];
  float* msp   = U;            float* msb   = U + 2720;
  float* mstb  = U + 5440;     float* mslbS = U + 8160;
  float* mseps = U + 10880;    float* mslbL = U + 13600;

  const int tid = threadIdx.x;
  const int grp = tid >> 5, lane = tid & 31;
  const int LOFF[5] = {0, 1, 5, 21, 85};

  // ---- issue ALL imports up front ----
  float4 tA = ((const float4*)(W + W_TABA))[tid];
  float4 tU = ((const float4*)(W + W_TABU))[tid];
  float4 tL = ((const float4*)(W + W_TABL))[tid];
  float4 r0 = ((const float4*)(W + W_TB4))[tid];
  float4 r1 = ((const float4*)(W + W_TB4))[tid + 1024];
  float4 tS, tLg;
  if (tid < 680) {
    tS  = ((const float4*)(W + W_TOPS))[tid];
    tLg = ((const float4*)(W + W_TOPL))[tid];
  }
  float pv = 0.f, lv = 0.f;
  if (tid < 32) { pv = W[W_PIV + tid]; lv = W[W_PIV + 32 + tid]; }

  ((float4*)sAT)[tid] = tA;
  ((float4*)sA)[tid]  = tU;
  ((float4*)sLT)[tid] = tL;
  ((float4*)R)[tid] = r0; ((float4*)R)[tid + 1024] = r1;
  if (tid < 680) { ((float4*)mslbS)[tid] = tS; ((float4*)mslbL)[tid] = tLg; }
  if (tid < 32) msp[tid] = pv;
  __syncthreads();

  float D[32], L[32];
#pragma unroll
  for (int j = 0; j < 32; j++) D[j] = sAT[(grp & 3) * 1024 + j * 32 + lane];
#pragma unroll
  for (int j = 0; j < 32; j++) L[j] = sLT[(grp & 3) * 1024 + j * 32 + lane];
  if (grp == 0) msb[lane] = msp[lane] * mslbS[lane];
  __syncthreads();

  // top-down levels 1..3
  for (int l = 1; l <= 3; l++) {
    int st = LOFF[l], cnt = LOFF[l + 1] - st;
    for (int base = 0; base < cnt; base += 32) {
      int ix = base + grp;
      if (ix < cnt) {
        int n = st + ix, pa = (n - 1) >> 2;
        float acc = mvreg(D, &msp[pa * 32]);
        msp[n * 32 + lane] = acc;
        msb[n * 32 + lane] = acc * mslbS[n * 32 + lane];
      }
    }
    __syncthreads();
  }
  // top-up: level-3 parents from TB4, then 2,1,0
  {
    for (int base = 0; base < 64; base += 32) {
      int ix = base + grp;
      if (ix < 64) {
        int pn = 21 + ix;
        float prod = 1.f;
#pragma unroll
        for (int c = 0; c < 4; c++) prod *= R[(4 * pn + 1 + c - 85) * 32 + lane];
        float bn = msb[pn * 32 + lane] * prod;
        bn /= hsum32(bn);
        msb[pn * 32 + lane] = bn;
      }
    }
    __syncthreads();
    const int PST[3] = {5, 1, 0}, PCNT[3] = {16, 4, 1};
    for (int s = 0; s < 3; s++) {
      int st = PST[s], cnt = PCNT[s];
      if (grp < cnt) {
        int pn = st + grp;
        float ppj = msp[pn * 32 + lane];
        float ac[4] = {0.f, 0.f, 0.f, 0.f};
#pragma unroll
        for (int j4 = 0; j4 < 8; j4++) {
#pragma unroll
          for (int c = 0; c < 4; c++) {
            float4 v = ((const float4*)&msb[(4 * pn + 1 + c) * 32])[j4];
            const float* t = &sA[c * 1024 + j4 * 128 + lane];
            ac[c] += t[0] * v.x + t[32] * v.y + t[64] * v.z + t[96] * v.w;
          }
        }
        float prod = 1.f;
#pragma unroll
        for (int c = 0; c < 4; c++) {
          float buv = ac[c] / ppj;
          mstb[(4 * pn + 1 + c) * 32 + lane] = buv;
          prod *= buv;
        }
        float bn = msb[pn * 32 + lane] * prod;
        bn /= hsum32(bn);
        msb[pn * 32 + lane] = bn;
      }
      __syncthreads();
    }
  }

  float lh = 0.f;
  if (grp == 0) {
    float v = msb[lane];
    mseps[lane] = v;
    lh += v * (lv + mslbL[lane]);  // Pi_lh + root B_lh
  }
  __syncthreads();
  const int EST[3] = {1, 5, 21}, ECNT[3] = {4, 16, 64};
  for (int s = 0; s < 3; s++) {
    int st = EST[s], cnt = ECNT[s];
    for (int base = 0; base < cnt; base += 32) {
      int ix = base + grp;
      if (ix < cnt) {
        int n = st + ix, pa = (n - 1) >> 2;
        float ratio = msb[n * 32 + lane] / msp[n * 32 + lane];
        float qv = mseps[pa * 32 + lane] / mstb[n * 32 + lane];
        sq[grp * 32 + lane] = qv;
        float an, aa;
        mvreg2(D, L, &sq[grp * 32], an, aa);
        float num = ratio * an;
        float den = hsum32(num);
        float epsi = num / den;
        mseps[n * 32 + lane] = epsi;
        lh += ratio * aa + epsi * mslbL[n * 32 + lane];
      }
    }
    __syncthreads();
  }
  if (tid < 680) {  // export eps rows 0..84
    int m = tid >> 3, q = tid & 7;
    *(float4*)&W[W_EPSM + m * 32 + q * 4] = *(float4*)&mseps[m * 32 + q * 4];
  }
#pragma unroll
  for (int mm = 32; mm >= 1; mm >>= 1) lh += __shfl_xor(lh, mm, 64);
  if ((tid & 63) == 0) sred[tid >> 6] = lh;
  __syncthreads();
  if (tid == 0) {
    float t = 0.f;
#pragma unroll
    for (int w = 0; w < 16; w++) t += sred[w];
    W[W_PART + 256] = t;
  }
}

// ---------------- K3: per-subtree eps 4-7 + lh (imports tables) -------------
__global__ __launch_bounds__(1024, 4) void k_eps(const float* __restrict__ Bm,
                                                 const int* __restrict__ labels,
                                                 float* __restrict__ W) {
  __shared__ __align__(16) float sAT[4096], sLT[4096];
  __shared__ __align__(16) float V[10880];
  __shared__ __align__(16) float sq[1024];
  __shared__ __align__(16) float sqr[32];
  __shared__ float spe[32];
  __shared__ float sbst[96];
  __shared__ float sred[16];
  float* stb  = V;            float* srt  = V + 2720;
  float* seps = V + 5440;     float* slbL = V + 8160;

  const int tid = threadIdx.x, bid = blockIdx.x;
  const int grp = tid >> 5, lane = tid & 31;
  const int ecl = grp & 3, slot = grp >> 2;
  const int r = 85 + bid;
  const int LOFF[5] = {0, 1, 5, 21, 85};

  // ---- issue ALL global loads up front ----
  float4 stT, stR;
  const int sm_ = tid >> 3, sq_ = tid & 7;
  if (tid < 680) {
    int g = gmap(r, sm_);
    stT = *(const float4*)&W[W_TBETA + g * 32 + sq_ * 4];
    stR = *(const float4*)&W[W_RATIO + g * 32 + sq_ * 4];
  }
  float4 tA = ((const float4*)(W + W_TABA))[tid];
  float4 tL = ((const float4*)(W + W_TABL))[tid];
  float pe = 0.f;
  if (tid < 32) pe = W[W_EPSM + ((r - 1) >> 2) * 32 + tid];
  float bv = 0.f;
  if (tid < 96) bv = W[W_BST + tid];
  const int m0 = grp, m1 = grp + 32, m2 = grp + 64;
  const bool h2 = (m2 < 85);
  int lb0 = labels[gmap(r, m0)];
  int lb1 = labels[gmap(r, m1)];
  int lb2 = h2 ? labels[gmap(r, m2)] : 0;
  float xs0 = Bm[lane * 256 + lb0];
  float xs1 = Bm[lane * 256 + lb1];
  float xs2 = h2 ? Bm[lane * 256 + lb2] : 0.f;

  ((float4*)sAT)[tid] = tA;
  ((float4*)sLT)[tid] = tL;
  if (tid < 32) spe[tid] = pe;
  if (tid < 96) sbst[tid] = bv;
  if (tid < 680) {
    *(float4*)&stb[sm_ * 32 + sq_ * 4] = stT;
    *(float4*)&srt[sm_ * 32 + sq_ * 4] = stR;
  }
  __syncthreads();

  {  // log-B label rows (bmx = sbst[lane], bls = sbst[64+lane])
    float bmx = sbst[lane], bls = sbst[64 + lane];
    slbL[m0 * 32 + lane] = (xs0 - bmx) - bls;
    slbL[m1 * 32 + lane] = (xs1 - bmx) - bls;
    if (h2) slbL[m2 * 32 + lane] = (xs2 - bmx) - bls;
  }
  float D[32], L[32];
#pragma unroll
  for (int j = 0; j < 32; j++) D[j] = sAT[(grp & 3) * 1024 + j * 32 + lane];
#pragma unroll
  for (int j = 0; j < 32; j++) L[j] = sLT[(grp & 3) * 1024 + j * 32 + lane];
  __syncthreads();

  float lh = 0.f;
  // eps at level-4 root r (class-matching group)
  if (ecl == ((r - 1) & 3) && slot == 0) {
    float ratio = srt[lane];
    sqr[lane] = spe[lane] / stb[lane];
    float an, aa;
    mvreg2(D, L, sqr, an, aa);
    float num = ratio * an;
    float den = hsum32(num);
    float epsi = num / den;
    seps[lane] = epsi;
    lh += ratio * aa + epsi * slbL[lane];
  }
  __syncthreads();
  // subtree eps levels 1..3 (global 5..7); e == grp&3
  for (int d = 1; d <= 3; d++) {
    int st = LOFF[d], cnt = LOFF[d + 1] - st;
    for (int base = 0; base < cnt; base += 32) {
      int ix = base + grp;
      if (ix < cnt) {
        int m = st + ix, pa = (m - 1) >> 2;
        float ratio = srt[m * 32 + lane];
        sq[grp * 32 + lane] = seps[pa * 32 + lane] / stb[m * 32 + lane];
        float an, aa;
        mvreg2(D, L, &sq[grp * 32], an, aa);
        float num = ratio * an;
        float den = hsum32(num);
        float epsi = num / den;
        seps[m * 32 + lane] = epsi;
        lh += ratio * aa + epsi * slbL[m * 32 + lane];
      }
    }
    __syncthreads();
  }

#pragma unroll
  for (int mm = 32; mm >= 1; mm >>= 1) lh += __shfl_xor(lh, mm, 64);
  if ((tid & 63) == 0) sred[tid >> 6] = lh;
  __syncthreads();
  if (tid == 0) {
    float t = 0.f;
#pragma unroll
    for (int w = 0; w < 16; w++) t += sred[w];
    W[W_PART + bid] = t;
  }
}

// ---------------- K4: final reduce (no atomics) ------------------------------
__global__ void k_final(const float* __restrict__ W, float* __restrict__ out) {
  __shared__ float sh[256];
  int tid = threadIdx.x;
  float a = 0.f;
  for (int k = tid; k < 257; k += 256) a += W[W_PART + k];
  sh[tid] = a; __syncthreads();
  for (int off = 128; off >= 1; off >>= 1) {
    if (tid < off) sh[tid] += sh[tid + off];
    __syncthreads();
  }
  if (tid == 0) out[0] = sh[0];
}

extern "C" void kernel_launch(void* const* d_in, const int* in_sizes, int n_in,
                              void* d_out, int out_size, void* d_ws, size_t ws_size,
                              hipStream_t stream) {
  const float* A  = (const float*)d_in[0];
  const float* Bm = (const float*)d_in[1];
  const float* Pi = (const float*)d_in[2];
  const int* labels = (const int*)d_in[5];
  float* W = (float*)d_ws;
  float* out = (float*)d_out;

  k_sub2<<<256, 1024, 0, stream>>>(A, Bm, Pi, labels, W);
  k_mid<<<1, 1024, 0, stream>>>(W);
  k_eps<<<256, 1024, 0, stream>>>(Bm, labels, W);
  k_final<<<1, 256, 0, stream>>>(W, out);
}